// Round 1
// baseline (1506.351 us; speedup 1.0000x reference)
//
#include <hip/hip_runtime.h>
#include <cmath>
#include <cstdio>

#ifndef M_PI
#define M_PI 3.14159265358979323846
#endif

// ---------------- constant table offsets (in floats) ----------------
#define OFF_D1F 0        // [15][60][29]
#define OFF_D1I 26100    // [15][30][29][29]
#define OFF_Y1  404550   // [15][29][24] complex
#define OFF_D2F 425430   // [10][30][19][19]
#define OFF_D2I 533730   // [10][20][19][19]
#define OFF_Y2  605930   // [10][19][19][192] complex
#define OFF_WI  1992170  // [20]
#define OFF_E1  1992190  // [29][60] complex
#define OFF_I1  1995670  // [30][29] complex
#define OFF_E2  1997410  // [19][30] complex
#define OFF_I2  1998550  // [20][19] complex
#define NCONST  1999310

// ---------------- workspace byte offsets ----------------
#define WOFF_CONST 0ul
#define WOFF_X2A   7997440ul                       // [10][608][380] cplx = 18,483,200 B
#define WOFF_P2    (7997440ul + 18483200ul)        // [10][380][760] cplx = 23,104,000 B
#define WOFF_H2    7997440ul                       // overlays X2A+P2: 40,960,000 B
#define WOFF_H1    49584640ul                      // [32][20][30^3] f32 = 69,120,000 B
#define WOFF_Z     49584640ul                      // overlays h1: [10][608][760] cplx = 36,966,400 B
#define WOFF_XF1   118704640ul                     // [32][60][29] cplx
#define WOFF_X1    (118704640ul + 445440ul)        // [32][15][29] cplx
#define WOFF_PSI1C (118704640ul + 445440ul + 111360ul)   // [15][29][20] cplx
#define WOFF_G     (118704640ul + 445440ul + 111360ul + 69600ul) // [32][40] f32
#define WS_NEED    (WOFF_G + 5120ul)

// ================= device helpers for constant generation =================
__device__ inline double dfact(int n){ double r=1.0; for(int i=2;i<=n;i++) r*=(double)i; return r; }
__device__ inline double dpowi(double x,int e){ double r=1.0; for(int i=0;i<e;i++) r*=x; return r; }
__device__ double wig(int l,int m,int n,double beta){
  if(m < -l || m > l || n < -l || n > l) return 0.0;
  double cb=cos(0.5*beta), sb=sin(0.5*beta);
  double pref=sqrt(dfact(l+m)*dfact(l-m)*dfact(l+n)*dfact(l-n));
  int k0 = (m-n)>0 ? (m-n) : 0;
  int k1 = (l+m) < (l-n) ? (l+m) : (l-n);
  double s=0.0;
  for(int k=k0;k<=k1;k++){
    double c=((k&1)?-1.0:1.0)/(dfact(k)*dfact(l+m-k)*dfact(l-n-k)*dfact(n-m+k));
    s += c*dpowi(cb,2*l+m-n-2*k)*dpowi(sb,n-m+2*k);
  }
  return pref*s;
}
__device__ inline double dh_w(int b,int j){
  double s=0.0;
  for(int k=0;k<b;k++) s += sin((2.0*j+1.0)*(2.0*k+1.0)*M_PI/(4.0*b))/(2.0*k+1.0);
  return (2.0/b)*sin(M_PI*(2.0*j+1.0)/(4.0*b))*s;
}
__device__ inline double soft_beta(int b,int j){ return M_PI*(2.0*j+1.0)/(4.0*b); }

// one flat kernel generating every constant table
__global__ __launch_bounds__(256) void kconst(float* __restrict__ C){
  for(long idx = (long)blockIdx.x*blockDim.x + threadIdx.x; idx < 1292190L;
      idx += (long)gridDim.x*blockDim.x){
    if(idx < 26100L){                       // D1F [15][60][29]
      int m=(int)(idx%29); int j=(int)((idx/29)%60); int l=(int)(idx/(29*60));
      C[OFF_D1F+idx] = (float)( wig(l, m-14, 0, soft_beta(30,j)) * dh_w(30,j) );
    } else if(idx < 404550L){ long q=idx-26100L;   // D1I [15][30][29][29]
      int n=(int)(q%29); int m=(int)((q/29)%29); int j=(int)((q/841)%30); int l=(int)(q/(841*30));
      C[OFF_D1I+q] = (float)wig(l, m-14, n-14, soft_beta(15,j));
    } else if(idx < 414990L){ long q=idx-404550L;  // Y1 [15][29][24] complex
      int g=(int)(q%24); int m=(int)((q/24)%29); int l=(int)(q/(24*29));
      double gb=((g>>3)+1)*(M_PI/8.0)/3.0;
      double ga=(double)(g&7)*(M_PI/4.0);
      double mag=(2*l+1)*wig(l, m-14, 0, gb);
      double ph = -(double)(m-14)*ga;
      C[OFF_Y1+2*q]  =(float)(mag*cos(ph));
      C[OFF_Y1+2*q+1]=(float)(mag*sin(ph));
    } else if(idx < 523290L){ long q=idx-414990L;  // D2F [10][30][19][19]
      int n=(int)(q%19); int m=(int)((q/19)%19); int j=(int)((q/361)%30); int l=(int)(q/(361*30));
      C[OFF_D2F+q]=(float)( wig(l,m-9,n-9,soft_beta(15,j))*dh_w(15,j) );
    } else if(idx < 595490L){ long q=idx-523290L;  // D2I [10][20][19][19]
      int n=(int)(q%19); int m=(int)((q/19)%19); int j=(int)((q/361)%20); int l=(int)(q/(361*20));
      C[OFF_D2I+q]=(float)wig(l,m-9,n-9,soft_beta(10,j));
    } else if(idx < 1288610L){ long q=idx-595490L; // Y2 [10][19][19][192] complex
      int g=(int)(q%192); int n=(int)((q/192)%19); int m=(int)((q/(192*19))%19); int l=(int)(q/(192*361));
      double gb=((g>>6)+1)*(M_PI/8.0)/3.0;
      double ga=(double)((g>>3)&7)*(M_PI/4.0);
      double gg=(double)(g&7)*(M_PI/4.0);
      double mag=(2*l+1)*wig(l,m-9,n-9,gb);
      double ph=-((double)(m-9)*ga + (double)(n-9)*gg);
      C[OFF_Y2+2*q]  =(float)(mag*cos(ph));
      C[OFF_Y2+2*q+1]=(float)(mag*sin(ph));
    } else if(idx < 1288630L){ int j=(int)(idx-1288610L); C[OFF_WI+j]=(float)dh_w(10,j); }
    else if(idx < 1290370L){ long q=idx-1288630L;  // E1 [29][60]
      int a=(int)(q%60); int m=(int)(q/60); double ph=-2.0*M_PI*(double)(m-14)*a/60.0;
      C[OFF_E1+2*q]=(float)cos(ph); C[OFF_E1+2*q+1]=(float)sin(ph);
    } else if(idx < 1291240L){ long q=idx-1290370L; // I1 [30][29]
      int m=(int)(q%29); int p=(int)(q/29); double ph=2.0*M_PI*(double)p*(double)(m-14)/30.0;
      C[OFF_I1+2*q]=(float)cos(ph); C[OFF_I1+2*q+1]=(float)sin(ph);
    } else if(idx < 1291810L){ long q=idx-1291240L; // E2 [19][30]
      int a=(int)(q%30); int m=(int)(q/30); double ph=-2.0*M_PI*(double)(m-9)*a/30.0;
      C[OFF_E2+2*q]=(float)cos(ph); C[OFF_E2+2*q+1]=(float)sin(ph);
    } else { long q=idx-1291810L;                   // I2 [20][19]
      int m=(int)(q%19); int p=(int)(q/19); double ph=2.0*M_PI*(double)p*(double)(m-9)/20.0;
      C[OFF_I2+2*q]=(float)cos(ph); C[OFF_I2+2*q+1]=(float)sin(ph);
    }
  }
}

// ================= forward-pass kernels =================

// xf1[b,j,m] = sum_a x[b,0,j,a] * E1[m,a]
__global__ __launch_bounds__(256) void k1a(const float* __restrict__ x,
                                           const float2* __restrict__ E1,
                                           float2* __restrict__ xf1){
  int idx = blockIdx.x*256 + threadIdx.x;
  if(idx >= 32*60*29) return;
  int m = idx % 29; int bj = idx / 29;
  const float* row = x + bj*60;
  float sr=0.f, si=0.f;
  for(int a=0;a<60;a++){ float2 e=E1[m*60+a]; float v=row[a]; sr+=v*e.x; si+=v*e.y; }
  xf1[idx] = make_float2(sr,si);
}

// X1[b,l,m] = sum_j D1F[l,j,m] * xf1[b,j,m]
__global__ __launch_bounds__(256) void k1b(const float2* __restrict__ xf1,
                                           const float* __restrict__ D1F,
                                           float2* __restrict__ X1){
  int idx = blockIdx.x*256 + threadIdx.x;
  if(idx >= 32*15*29) return;
  int m = idx % 29; int lb = idx / 29; int l = lb % 15; int b = lb / 15;
  float sr=0.f, si=0.f;
  for(int j=0;j<60;j++){
    float d = D1F[(l*60+j)*29+m]; float2 v = xf1[(b*60+j)*29+m];
    sr += d*v.x; si += d*v.y;
  }
  X1[(b*15+l)*29+m] = make_float2(sr,si);
}

// psi1c[l,n,o] = conj( sum_g w1[0,o,g] * Y1[l,n,g] )
__global__ __launch_bounds__(256) void kpsi1(const float* __restrict__ w1,
                                             const float2* __restrict__ Y1,
                                             float2* __restrict__ psi1c){
  int idx = blockIdx.x*256 + threadIdx.x;
  if(idx >= 15*29*20) return;
  int o = idx % 20; int ln = idx / 20;
  float sr=0.f, si=0.f;
  for(int g=0;g<24;g++){ float w=w1[o*24+g]; float2 y=Y1[ln*24+g]; sr+=w*y.x; si+=w*y.y; }
  psi1c[idx] = make_float2(sr,-si);
}

// per (b,o,j): A[m,n]=sum_l X1*psi1c*D1I  ->  y=Re(I1 A I1^T) + b1, ReLU -> h1
__global__ __launch_bounds__(256) void k2(const float2* __restrict__ X1,
                                          const float2* __restrict__ psi1c,
                                          const float* __restrict__ D1I,
                                          const float2* __restrict__ I1g,
                                          const float* __restrict__ b1,
                                          float* __restrict__ h1){
  int j=blockIdx.x, o=blockIdx.y, b=blockIdx.z;
  __shared__ float2 sX[15][29];
  __shared__ float2 sP[15][29];
  __shared__ float2 sA[29][29];
  __shared__ float2 sT[30][29];
  __shared__ float2 sI[30][29];
  int t=threadIdx.x;
  for(int q=t;q<435;q+=256){ sX[q/29][q%29]=X1[b*435+q]; sP[q/29][q%29]=psi1c[q*20+o]; }
  for(int q=t;q<870;q+=256){ sI[q/29][q%29]=I1g[q]; }
  __syncthreads();
  for(int q=t;q<841;q+=256){
    int m=q/29, n=q%29; float sr=0.f, si=0.f;
    for(int l=0;l<15;l++){
      float d=D1I[((l*30+j)*29+m)*29+n];
      float2 xx=sX[l][m], pp=sP[l][n];
      float zr=xx.x*pp.x - xx.y*pp.y, zi=xx.x*pp.y + xx.y*pp.x;
      sr += d*zr; si += d*zi;
    }
    sA[m][n]=make_float2(sr,si);
  }
  __syncthreads();
  for(int q=t;q<870;q+=256){
    int p=q/29, n=q%29; float sr=0.f, si=0.f;
    for(int m=0;m<29;m++){
      float2 e=sI[p][m], a=sA[m][n];
      sr += e.x*a.x - e.y*a.y; si += e.x*a.y + e.y*a.x;
    }
    sT[p][n]=make_float2(sr,si);
  }
  __syncthreads();
  float bias=b1[o];
  for(int q=t;q<900;q+=256){
    int p=q/30, qq=q%30; float s=0.f;
    for(int n=0;n<29;n++){ float2 tt=sT[p][n], e=sI[qq][n]; s += tt.x*e.x - tt.y*e.y; }
    s += bias; s = fmaxf(s,0.f);
    h1[((((size_t)b*20+o)*30+j)*30+p)*30+qq]=s;
  }
}

// P2[l][(i,n)][(o,k)] = conj( sum_g w2[i,o,g] * Y2[l,k,n,g] )
__global__ __launch_bounds__(256) void k3(const float* __restrict__ w2,
                                          const float2* __restrict__ Y2,
                                          float2* __restrict__ P2){
  int blk=blockIdx.x;               // (l,k,n): l*361 + k*19 + n
  int n=blk%19; int kk=(blk/19)%19; int l=blk/361;
  __shared__ float2 sY[192];
  int t=threadIdx.x;
  for(int q=t;q<192;q+=256) sY[q]=Y2[((size_t)(l*19+kk)*19+n)*192+q];
  __syncthreads();
  for(int q=t;q<800;q+=256){
    int i=q/40, o=q%40; float sr=0.f, si=0.f;
    const float* wr = w2 + (size_t)(i*40+o)*192;
    for(int g=0;g<192;g++){ float w=wr[g]; float2 y=sY[g]; sr+=w*y.x; si+=w*y.y; }
    P2[(size_t)(l*380 + i*19+n)*760 + (o*19+kk)] = make_float2(sr,-si);
  }
}

// per (b,i): fft2 of each beta-slice of h1 (30x30 -> 19x19) * D2F, summed over j
// -> X2A[l][(b,m)][(i,n)]
__global__ __launch_bounds__(256) void k4(const float* __restrict__ h1,
                                          const float* __restrict__ D2F,
                                          const float2* __restrict__ E2g,
                                          float2* __restrict__ X2A){
  int i=blockIdx.x, b=blockIdx.y;
  __shared__ float2 acc[10][19][19];
  __shared__ float  tile[30][30];
  __shared__ float2 t1[30][19];
  __shared__ float2 xf[19][19];
  __shared__ float2 sE2[19][30];
  int t=threadIdx.x;
  for(int q=t;q<19*30;q+=256) sE2[q/30][q%30]=E2g[q];
  for(int q=t;q<3610;q+=256){ int l=q/361, r=q%361; acc[l][r/19][r%19]=make_float2(0.f,0.f); }
  __syncthreads();
  for(int j=0;j<30;j++){
    for(int q=t;q<900;q+=256) tile[q/30][q%30]=h1[(((size_t)(b*20+i)*30+j))*900 + q];
    __syncthreads();
    for(int q=t;q<570;q+=256){
      int a=q/19, n=q%19; float sr=0.f, si=0.f;
      for(int g=0;g<30;g++){ float v=tile[a][g]; float2 e=sE2[n][g]; sr+=v*e.x; si+=v*e.y; }
      t1[a][n]=make_float2(sr,si);
    }
    __syncthreads();
    for(int q=t;q<361;q+=256){
      int m=q/19, n=q%19; float sr=0.f, si=0.f;
      for(int a=0;a<30;a++){
        float2 e=sE2[m][a], v=t1[a][n];
        sr += e.x*v.x - e.y*v.y; si += e.x*v.y + e.y*v.x;
      }
      xf[m][n]=make_float2(sr,si);
    }
    __syncthreads();
    for(int q=t;q<3610;q+=256){
      int l=q/361, r=q%361, m=r/19, n=r%19;
      float d=D2F[((l*30+j)*19+m)*19+n];
      float2 v=xf[m][n];
      acc[l][m][n].x += d*v.x; acc[l][m][n].y += d*v.y;
    }
    __syncthreads();
  }
  for(int q=t;q<3610;q+=256){
    int l=q/361, r=q%361, m=r/19, n=r%19;
    X2A[(size_t)(l*608 + b*19+m)*380 + i*19+n]=acc[l][m][n];
  }
}

// complex GEMM per l: C[l] = A[l](608x380) * B[l](380x760)
__global__ __launch_bounds__(256) void k5(const float2* __restrict__ A,
                                          const float2* __restrict__ B,
                                          float2* __restrict__ Cm){
  int l=blockIdx.z;
  int m0=blockIdx.y*32, n0=blockIdx.x*40;
  __shared__ float2 As[32][19];
  __shared__ float2 Bs[19][40];
  const float2* Al=A + (size_t)l*608*380;
  const float2* Bl=B + (size_t)l*380*760;
  int t=threadIdx.x; int tr=t>>3, tc=t&7;
  float2 acc[5];
  #pragma unroll
  for(int u=0;u<5;u++) acc[u]=make_float2(0.f,0.f);
  for(int kt=0;kt<380;kt+=19){
    for(int q=t;q<32*19;q+=256){ int r=q/19,k=q%19; As[r][k]=Al[(size_t)(m0+r)*380+kt+k]; }
    for(int q=t;q<19*40;q+=256){ int k=q/40,c=q%40; Bs[k][c]=Bl[(size_t)(kt+k)*760+n0+c]; }
    __syncthreads();
    #pragma unroll
    for(int kk=0;kk<19;kk++){
      float2 a=As[tr][kk];
      #pragma unroll
      for(int u=0;u<5;u++){
        float2 bb=Bs[kk][tc+8*u];
        acc[u].x += a.x*bb.x - a.y*bb.y;
        acc[u].y += a.x*bb.y + a.y*bb.x;
      }
    }
    __syncthreads();
  }
  #pragma unroll
  for(int u=0;u<5;u++) Cm[(size_t)(l*608+m0+tr)*760 + n0+tc+8*u]=acc[u];
}

// per (b,o,j): A[m,k]=sum_l Z*D2I -> y=Re(I2 A I2^T) + b2, ReLU -> h2
__global__ __launch_bounds__(128) void k6(const float2* __restrict__ Z,
                                          const float* __restrict__ D2I,
                                          const float2* __restrict__ I2g,
                                          const float* __restrict__ b2,
                                          float* __restrict__ h2){
  int j=blockIdx.x, o=blockIdx.y, b=blockIdx.z;
  __shared__ float2 sA[19][19];
  __shared__ float2 sT[20][19];
  __shared__ float2 sI2[20][19];
  int t=threadIdx.x;
  for(int q=t;q<380;q+=128) sI2[q/19][q%19]=I2g[q];
  __syncthreads();
  for(int q=t;q<361;q+=128){
    int m=q/19, k=q%19; float sr=0.f, si=0.f;
    for(int l=0;l<10;l++){
      float2 z=Z[(size_t)(l*608 + b*19+m)*760 + o*19+k];
      float d=D2I[((l*20+j)*19+m)*19+k];
      sr += z.x*d; si += z.y*d;
    }
    sA[m][k]=make_float2(sr,si);
  }
  __syncthreads();
  for(int q=t;q<380;q+=128){
    int p=q/19, k=q%19; float sr=0.f, si=0.f;
    for(int m=0;m<19;m++){
      float2 e=sI2[p][m], a=sA[m][k];
      sr += e.x*a.x - e.y*a.y; si += e.x*a.y + e.y*a.x;
    }
    sT[p][k]=make_float2(sr,si);
  }
  __syncthreads();
  float bias=b2[o];
  for(int q=t;q<400;q+=128){
    int p=q/20, qq=q%20; float s=0.f;
    for(int k=0;k<19;k++){ float2 tt=sT[p][k], e=sI2[qq][k]; s += tt.x*e.x - tt.y*e.y; }
    s += bias; s = fmaxf(s,0.f);
    h2[((((size_t)b*40+o)*20+j)*20+p)*20+qq]=s;
  }
}

// g[b,f] = (2pi/20)^2 * sum_{j,p,q} h2 * W_INT[j]
__global__ __launch_bounds__(256) void k7a(const float* __restrict__ h2,
                                           const float* __restrict__ WI,
                                           float* __restrict__ g){
  int bf=blockIdx.x;
  const float* base=h2 + (size_t)bf*8000;
  int t=threadIdx.x; float s=0.f;
  for(int q=t;q<8000;q+=256) s += base[q]*WI[q/400];
  __shared__ float red[256];
  red[t]=s; __syncthreads();
  for(int off=128;off>0;off>>=1){ if(t<off) red[t]+=red[t+off]; __syncthreads(); }
  if(t==0){
    const float c=(float)((2.0*M_PI/20.0)*(2.0*M_PI/20.0));
    g[bf]=red[0]*c;
  }
}

// out[b,c] = sum_f g[b,f]*w_lin[c,f] + bl[c]
__global__ __launch_bounds__(64) void k7b(const float* __restrict__ g,
                                          const float* __restrict__ wlin,
                                          const float* __restrict__ bl,
                                          float* __restrict__ out){
  int idx=blockIdx.x*64+threadIdx.x;
  if(idx>=320) return;
  int b=idx/10, c=idx%10;
  float s=bl[c];
  for(int f=0;f<40;f++) s += g[b*40+f]*wlin[c*40+f];
  out[b*10+c]=s;
}

extern "C" void kernel_launch(void* const* d_in, const int* in_sizes, int n_in,
                              void* d_out, int out_size, void* d_ws, size_t ws_size,
                              hipStream_t stream){
  (void)in_sizes; (void)n_in; (void)out_size;
  const float* x    = (const float*)d_in[0];
  const float* w1   = (const float*)d_in[1];
  const float* b1   = (const float*)d_in[2];
  const float* w2   = (const float*)d_in[3];
  const float* b2   = (const float*)d_in[4];
  const float* wlin = (const float*)d_in[5];
  const float* bl   = (const float*)d_in[6];
  float* out = (float*)d_out;
  char*  ws  = (char*)d_ws;

  if(ws_size < WS_NEED){
    fprintf(stderr, "kernel_launch: ws too small: have %zu need %lu\n", ws_size, WS_NEED);
  }

  float* C = (float*)(ws + WOFF_CONST);
  const float*  D1F = C + OFF_D1F;
  const float*  D1I = C + OFF_D1I;
  const float2* Y1  = (const float2*)(C + OFF_Y1);
  const float*  D2F = C + OFF_D2F;
  const float*  D2I = C + OFF_D2I;
  const float2* Y2  = (const float2*)(C + OFF_Y2);
  const float*  WI  = C + OFF_WI;
  const float2* E1  = (const float2*)(C + OFF_E1);
  const float2* I1  = (const float2*)(C + OFF_I1);
  const float2* E2  = (const float2*)(C + OFF_E2);
  const float2* I2  = (const float2*)(C + OFF_I2);

  float2* xf1   = (float2*)(ws + WOFF_XF1);
  float2* X1    = (float2*)(ws + WOFF_X1);
  float2* psi1c = (float2*)(ws + WOFF_PSI1C);
  float*  h1    = (float*)(ws + WOFF_H1);
  float2* X2A   = (float2*)(ws + WOFF_X2A);
  float2* P2    = (float2*)(ws + WOFF_P2);
  float2* Z     = (float2*)(ws + WOFF_Z);
  float*  h2    = (float*)(ws + WOFF_H2);
  float*  g     = (float*)(ws + WOFF_G);

  // constants (ws is re-poisoned before every timed call -> regenerate every call)
  hipLaunchKernelGGL(kconst, dim3(2048), dim3(256), 0, stream, C);

  hipLaunchKernelGGL(k1a, dim3((32*60*29+255)/256), dim3(256), 0, stream, x, E1, xf1);
  hipLaunchKernelGGL(k1b, dim3((32*15*29+255)/256), dim3(256), 0, stream, xf1, D1F, X1);
  hipLaunchKernelGGL(kpsi1, dim3((15*29*20+255)/256), dim3(256), 0, stream, w1, Y1, psi1c);
  hipLaunchKernelGGL(k2, dim3(30,20,32), dim3(256), 0, stream, X1, psi1c, D1I, I1, b1, h1);
  hipLaunchKernelGGL(k3, dim3(3610), dim3(256), 0, stream, w2, Y2, P2);
  hipLaunchKernelGGL(k4, dim3(20,32), dim3(256), 0, stream, h1, D2F, E2, X2A);
  hipLaunchKernelGGL(k5, dim3(19,19,10), dim3(256), 0, stream, X2A, P2, Z);
  hipLaunchKernelGGL(k6, dim3(20,40,32), dim3(128), 0, stream, Z, D2I, I2, b2, h2);
  hipLaunchKernelGGL(k7a, dim3(1280), dim3(256), 0, stream, h2, WI, g);
  hipLaunchKernelGGL(k7b, dim3(5), dim3(64), 0, stream, g, wlin, bl, out);
}

// Round 2
// 1381.828 us; speedup vs baseline: 1.0901x; 1.0901x over previous
//
#include <hip/hip_runtime.h>
#include <cmath>
#include <cstdio>

#ifndef M_PI
#define M_PI 3.14159265358979323846
#endif

// ---------------- constant table offsets (in floats) ----------------
#define OFF_D1F 0        // [15][60][29]
#define OFF_D1I 26100    // [15][30][29][29]
#define OFF_Y1  404550   // [15][29][24] complex
#define OFF_D2F 425430   // [10][30][19][19]
#define OFF_D2I 533730   // [10][20][19][19]
#define OFF_Y2  605930   // [10][19][19][192] complex
#define OFF_WI  1992170  // [20]
#define OFF_E1  1992190  // [29][60] complex
#define OFF_I1  1995670  // [30][29] complex
#define OFF_E2  1997410  // [19][30] complex
#define OFF_I2  1998550  // [20][19] complex
#define NCONST  1999310

// ---------------- workspace byte offsets ----------------
// CONST  [0, 7,997,440)
// A_aug  [7,997,440, 17,827,840)   bf16 [10][640][768]
// B_augT [17,827,840, 41,420,800)  bf16 [10][1536][768]
// h1     [41,420,800, 110,540,800) f32  [32][20][30^3]
//   P2 overlays h1 head [41,420,800, 64,524,800)  (written after k4)
//   Z  overlays h1 tail [73,574,400, 110,540,800)
// h2     [7,997,440, 48,957,440)   f32 (overlays A,B,P2 head - all dead by k6)
// smalls [110,540,800, ...)
#define WOFF_CONST 0ul
#define WOFF_AAUG  7997440ul
#define WOFF_BT    17827840ul
#define WOFF_H1    41420800ul
#define WOFF_P2    41420800ul
#define WOFF_Z     73574400ul
#define WOFF_H2    7997440ul
#define WOFF_XF1   110540800ul
#define WOFF_X1    (110540800ul + 445440ul)
#define WOFF_PSI1  (110540800ul + 445440ul + 111360ul)
#define WOFF_G     (110540800ul + 445440ul + 111360ul + 69600ul)
#define WS_NEED    (WOFF_G + 5120ul)

typedef __attribute__((ext_vector_type(8))) short short8v;
typedef __attribute__((ext_vector_type(4))) float f32x4;

__device__ inline unsigned short f2bf(float x){
  unsigned int u = __float_as_uint(x);
  u += 0x7FFFu + ((u >> 16) & 1u);
  return (unsigned short)(u >> 16);
}

// ================= device helpers for constant generation =================
__device__ inline double dfact(int n){ double r=1.0; for(int i=2;i<=n;i++) r*=(double)i; return r; }
__device__ inline double dpowi(double x,int e){ double r=1.0; for(int i=0;i<e;i++) r*=x; return r; }
__device__ double wig(int l,int m,int n,double beta){
  if(m < -l || m > l || n < -l || n > l) return 0.0;
  double cb=cos(0.5*beta), sb=sin(0.5*beta);
  double pref=sqrt(dfact(l+m)*dfact(l-m)*dfact(l+n)*dfact(l-n));
  int k0 = (m-n)>0 ? (m-n) : 0;
  int k1 = (l+m) < (l-n) ? (l+m) : (l-n);
  double s=0.0;
  for(int k=k0;k<=k1;k++){
    double c=((k&1)?-1.0:1.0)/(dfact(k)*dfact(l+m-k)*dfact(l-n-k)*dfact(n-m+k));
    s += c*dpowi(cb,2*l+m-n-2*k)*dpowi(sb,n-m+2*k);
  }
  return pref*s;
}
__device__ inline double dh_w(int b,int j){
  double s=0.0;
  for(int k=0;k<b;k++) s += sin((2.0*j+1.0)*(2.0*k+1.0)*M_PI/(4.0*b))/(2.0*k+1.0);
  return (2.0/b)*sin(M_PI*(2.0*j+1.0)/(4.0*b))*s;
}
__device__ inline double soft_beta(int b,int j){ return M_PI*(2.0*j+1.0)/(4.0*b); }

__global__ __launch_bounds__(256) void kconst(float* __restrict__ C){
  for(long idx = (long)blockIdx.x*blockDim.x + threadIdx.x; idx < 1292190L;
      idx += (long)gridDim.x*blockDim.x){
    if(idx < 26100L){                       // D1F [15][60][29]
      int m=(int)(idx%29); int j=(int)((idx/29)%60); int l=(int)(idx/(29*60));
      C[OFF_D1F+idx] = (float)( wig(l, m-14, 0, soft_beta(30,j)) * dh_w(30,j) );
    } else if(idx < 404550L){ long q=idx-26100L;   // D1I [15][30][29][29]
      int n=(int)(q%29); int m=(int)((q/29)%29); int j=(int)((q/841)%30); int l=(int)(q/(841*30));
      C[OFF_D1I+q] = (float)wig(l, m-14, n-14, soft_beta(15,j));
    } else if(idx < 414990L){ long q=idx-404550L;  // Y1 [15][29][24] complex
      int g=(int)(q%24); int m=(int)((q/24)%29); int l=(int)(q/(24*29));
      double gb=((g>>3)+1)*(M_PI/8.0)/3.0;
      double ga=(double)(g&7)*(M_PI/4.0);
      double mag=(2*l+1)*wig(l, m-14, 0, gb);
      double ph = -(double)(m-14)*ga;
      C[OFF_Y1+2*q]  =(float)(mag*cos(ph));
      C[OFF_Y1+2*q+1]=(float)(mag*sin(ph));
    } else if(idx < 523290L){ long q=idx-414990L;  // D2F [10][30][19][19]
      int n=(int)(q%19); int m=(int)((q/19)%19); int j=(int)((q/361)%30); int l=(int)(q/(361*30));
      C[OFF_D2F+q]=(float)( wig(l,m-9,n-9,soft_beta(15,j))*dh_w(15,j) );
    } else if(idx < 595490L){ long q=idx-523290L;  // D2I [10][20][19][19]
      int n=(int)(q%19); int m=(int)((q/19)%19); int j=(int)((q/361)%20); int l=(int)(q/(361*20));
      C[OFF_D2I+q]=(float)wig(l,m-9,n-9,soft_beta(10,j));
    } else if(idx < 1288610L){ long q=idx-595490L; // Y2 [10][19][19][192] complex
      int g=(int)(q%192); int n=(int)((q/192)%19); int m=(int)((q/(192*19))%19); int l=(int)(q/(192*361));
      double gb=((g>>6)+1)*(M_PI/8.0)/3.0;
      double ga=(double)((g>>3)&7)*(M_PI/4.0);
      double gg=(double)(g&7)*(M_PI/4.0);
      double mag=(2*l+1)*wig(l,m-9,n-9,gb);
      double ph=-((double)(m-9)*ga + (double)(n-9)*gg);
      C[OFF_Y2+2*q]  =(float)(mag*cos(ph));
      C[OFF_Y2+2*q+1]=(float)(mag*sin(ph));
    } else if(idx < 1288630L){ int j=(int)(idx-1288610L); C[OFF_WI+j]=(float)dh_w(10,j); }
    else if(idx < 1290370L){ long q=idx-1288630L;  // E1 [29][60]
      int a=(int)(q%60); int m=(int)(q/60); double ph=-2.0*M_PI*(double)(m-14)*a/60.0;
      C[OFF_E1+2*q]=(float)cos(ph); C[OFF_E1+2*q+1]=(float)sin(ph);
    } else if(idx < 1291240L){ long q=idx-1290370L; // I1 [30][29]
      int m=(int)(q%29); int p=(int)(q/29); double ph=2.0*M_PI*(double)p*(double)(m-14)/30.0;
      C[OFF_I1+2*q]=(float)cos(ph); C[OFF_I1+2*q+1]=(float)sin(ph);
    } else if(idx < 1291810L){ long q=idx-1291240L; // E2 [19][30]
      int a=(int)(q%30); int m=(int)(q/30); double ph=-2.0*M_PI*(double)(m-9)*a/30.0;
      C[OFF_E2+2*q]=(float)cos(ph); C[OFF_E2+2*q+1]=(float)sin(ph);
    } else { long q=idx-1291810L;                   // I2 [20][19]
      int m=(int)(q%19); int p=(int)(q/19); double ph=2.0*M_PI*(double)p*(double)(m-9)/20.0;
      C[OFF_I2+2*q]=(float)cos(ph); C[OFF_I2+2*q+1]=(float)sin(ph);
    }
  }
}

// zero A_aug + B_augT (contiguous region)
__global__ __launch_bounds__(256) void kfill(uint4* __restrict__ p, long n16){
  uint4 z; z.x=0u; z.y=0u; z.z=0u; z.w=0u;
  for(long i=(long)blockIdx.x*256+threadIdx.x; i<n16; i+=(long)gridDim.x*256) p[i]=z;
}

// ================= forward-pass kernels =================

// xf1[b,j,m] = sum_a x[b,0,j,a] * E1[m,a]
__global__ __launch_bounds__(256) void k1a(const float* __restrict__ x,
                                           const float2* __restrict__ E1,
                                           float2* __restrict__ xf1){
  int idx = blockIdx.x*256 + threadIdx.x;
  if(idx >= 32*60*29) return;
  int m = idx % 29; int bj = idx / 29;
  const float* row = x + bj*60;
  float sr=0.f, si=0.f;
  for(int a=0;a<60;a++){ float2 e=E1[m*60+a]; float v=row[a]; sr+=v*e.x; si+=v*e.y; }
  xf1[idx] = make_float2(sr,si);
}

// X1[b,l,m] = sum_j D1F[l,j,m] * xf1[b,j,m]
__global__ __launch_bounds__(256) void k1b(const float2* __restrict__ xf1,
                                           const float* __restrict__ D1F,
                                           float2* __restrict__ X1){
  int idx = blockIdx.x*256 + threadIdx.x;
  if(idx >= 32*15*29) return;
  int m = idx % 29; int lb = idx / 29; int l = lb % 15; int b = lb / 15;
  float sr=0.f, si=0.f;
  for(int j=0;j<60;j++){
    float d = D1F[(l*60+j)*29+m]; float2 v = xf1[(b*60+j)*29+m];
    sr += d*v.x; si += d*v.y;
  }
  X1[(b*15+l)*29+m] = make_float2(sr,si);
}

// psi1cO[o][l][n] = conj( sum_g w1[0,o,g] * Y1[l,n,g] )
__global__ __launch_bounds__(256) void kpsi1(const float* __restrict__ w1,
                                             const float2* __restrict__ Y1,
                                             float2* __restrict__ psi1cO){
  int idx = blockIdx.x*256 + threadIdx.x;
  if(idx >= 15*29*20) return;
  int o = idx % 20; int ln = idx / 20;
  float sr=0.f, si=0.f;
  for(int g=0;g<24;g++){ float w=w1[o*24+g]; float2 y=Y1[ln*24+g]; sr+=w*y.x; si+=w*y.y; }
  psi1cO[o*435 + ln] = make_float2(sr,-si);
}

// conv1 fused: block=(j,b), loop o. D1I from L2 (coalesced), X1/psi/I1 in LDS.
__global__ __launch_bounds__(256) void k2(const float2* __restrict__ X1,
                                          const float2* __restrict__ psi1cO,
                                          const float* __restrict__ D1I,
                                          const float2* __restrict__ I1g,
                                          const float* __restrict__ b1,
                                          float* __restrict__ h1){
  int j=blockIdx.x, b=blockIdx.y;
  __shared__ float2 sX[15][29];
  __shared__ float  sI1r[30][31], sI1i[30][31];
  __shared__ float2 sPo[15][29];
  __shared__ float2 sA[29][29];
  __shared__ float2 sT[30][29];
  int t=threadIdx.x;
  for(int q=t;q<435;q+=256) ((float2*)sX)[q]=X1[b*435+q];
  for(int q=t;q<870;q+=256){ float2 e=I1g[q]; sI1r[q/29][q%29]=e.x; sI1i[q/29][q%29]=e.y; }
  const float* Dj = D1I + j*841;
  __syncthreads();
  for(int o=0;o<20;o++){
    for(int q=t;q<435;q+=256) ((float2*)sPo)[q]=psi1cO[o*435+q];
    __syncthreads();
    for(int q=t;q<841;q+=256){
      int m=q/29, n=q%29; float sr=0.f, si=0.f;
      #pragma unroll
      for(int l=0;l<15;l++){
        float d=Dj[l*25230 + q];
        float2 xx=sX[l][m], pp=sPo[l][n];
        sr += d*(xx.x*pp.x - xx.y*pp.y);
        si += d*(xx.x*pp.y + xx.y*pp.x);
      }
      sA[m][n]=make_float2(sr,si);
    }
    __syncthreads();
    for(int q=t;q<870;q+=256){
      int p=q/29, n=q%29; float sr=0.f, si=0.f;
      #pragma unroll
      for(int m=0;m<29;m++){
        float er=sI1r[p][m], ei=sI1i[p][m]; float2 a=sA[m][n];
        sr += er*a.x - ei*a.y; si += er*a.y + ei*a.x;
      }
      sT[p][n]=make_float2(sr,si);
    }
    __syncthreads();
    float bias=b1[o];
    for(int q=t;q<900;q+=256){
      int p=q/30, qq=q%30; float s=0.f;
      #pragma unroll
      for(int n=0;n<29;n++){ float2 tt=sT[p][n]; s += tt.x*sI1r[qq][n] - tt.y*sI1i[qq][n]; }
      s += bias; s = fmaxf(s,0.f);
      h1[((((size_t)b*20+o)*30+j)*30+p)*30+qq]=s;
    }
    __syncthreads();
  }
}

// P2[l][(i,n)][(o,k)] = conj( sum_g w2[i,o,g] * Y2[l,k,n,g] )   (f32 complex)
__global__ __launch_bounds__(256) void k3(const float* __restrict__ w2,
                                          const float2* __restrict__ Y2,
                                          float2* __restrict__ P2){
  int blk=blockIdx.x;               // (l,k,n): l*361 + k*19 + n
  int n=blk%19; int kk=(blk/19)%19; int l=blk/361;
  __shared__ float2 sY[192];
  int t=threadIdx.x;
  for(int q=t;q<192;q+=256) sY[q]=Y2[((size_t)(l*19+kk)*19+n)*192+q];
  __syncthreads();
  for(int q=t;q<800;q+=256){
    int i=q/40, o=q%40; float sr=0.f, si=0.f;
    const float* wr = w2 + (size_t)(i*40+o)*192;
    for(int g=0;g<192;g++){ float w=wr[g]; float2 y=sY[g]; sr+=w*y.x; si+=w*y.y; }
    P2[(size_t)(l*380 + i*19+n)*760 + (o*19+kk)] = make_float2(sr,-si);
  }
}

// transpose P2 -> B_augT bf16: Bt[l][2c+ri][k_aug]
__global__ __launch_bounds__(128) void kB(const float2* __restrict__ P2,
                                          unsigned short* __restrict__ Bt){
  int c = blockIdx.x;      // 0..759
  int l = blockIdx.y;
  unsigned short* base = Bt + (size_t)l*1536*768;
  size_t r0 = (size_t)(2*c)*768, r1 = (size_t)(2*c+1)*768;
  for(int k=threadIdx.x; k<380; k+=128){
    float2 z = P2[((size_t)(l*380) + k)*760 + c];
    unsigned short zr=f2bf(z.x), zi=f2bf(z.y), nzi=f2bf(-z.y);
    base[r0 + k]       = zr;
    base[r0 + 384 + k] = nzi;
    base[r1 + k]       = zi;
    base[r1 + 384 + k] = zr;
  }
}

// per (b,i): fft2(30x30 -> 19x19) * D2F summed over j -> A_aug bf16
__global__ __launch_bounds__(256) void k4(const float* __restrict__ h1,
                                          const float* __restrict__ D2F,
                                          const float2* __restrict__ E2g,
                                          unsigned short* __restrict__ Aaug){
  int i=blockIdx.x, b=blockIdx.y;
  __shared__ float2 acc[10][19][19];
  __shared__ float  tile[30][30];
  __shared__ float2 t1[30][19];
  __shared__ float2 xf[19][19];
  __shared__ float2 sE2[19][30];
  int t=threadIdx.x;
  for(int q=t;q<19*30;q+=256) sE2[q/30][q%30]=E2g[q];
  for(int q=t;q<3610;q+=256){ int l=q/361, r=q%361; acc[l][r/19][r%19]=make_float2(0.f,0.f); }
  __syncthreads();
  for(int j=0;j<30;j++){
    for(int q=t;q<900;q+=256) tile[q/30][q%30]=h1[(((size_t)(b*20+i)*30+j))*900 + q];
    __syncthreads();
    for(int q=t;q<570;q+=256){
      int a=q/19, n=q%19; float sr=0.f, si=0.f;
      for(int g=0;g<30;g++){ float v=tile[a][g]; float2 e=sE2[n][g]; sr+=v*e.x; si+=v*e.y; }
      t1[a][n]=make_float2(sr,si);
    }
    __syncthreads();
    for(int q=t;q<361;q+=256){
      int m=q/19, n=q%19; float sr=0.f, si=0.f;
      for(int a=0;a<30;a++){
        float2 e=sE2[m][a], v=t1[a][n];
        sr += e.x*v.x - e.y*v.y; si += e.x*v.y + e.y*v.x;
      }
      xf[m][n]=make_float2(sr,si);
    }
    __syncthreads();
    for(int q=t;q<3610;q+=256){
      int l=q/361, r=q%361, m=r/19, n=r%19;
      float d=D2F[((l*30+j)*19+m)*19+n];
      float2 v=xf[m][n];
      acc[l][m][n].x += d*v.x; acc[l][m][n].y += d*v.y;
    }
    __syncthreads();
  }
  for(int q=t;q<3610;q+=256){
    int l=q/361, r=q%361, m=r/19, n=r%19;
    float2 v=acc[l][m][n];
    size_t base=((size_t)(l*640) + b*19+m)*768 + (size_t)(i*19+n);
    Aaug[base]     = f2bf(v.x);
    Aaug[base+384] = f2bf(v.y);
  }
}

// bf16 MFMA GEMM per l: Cf[l](608x1520 f32) = A_aug[l](640x768) x B_augT[l]^T(768x1536)
__global__ __launch_bounds__(256) void k5(const unsigned short* __restrict__ A,
                                          const unsigned short* __restrict__ B,
                                          float* __restrict__ Cf){
  int l = blockIdx.z;
  int m0 = blockIdx.y*128, n0 = blockIdx.x*128;
  __shared__ unsigned short As[128][40];   // padded: 40 elems = 20 words -> conflict-free frag reads
  __shared__ unsigned short Bs[128][40];   // Bs[n][k]
  int t = threadIdx.x;
  int wid = t>>6, lane = t&63;
  int wr = wid>>1, wc = wid&1;
  f32x4 acc[4][4];
  #pragma unroll
  for(int a=0;a<4;a++)
    #pragma unroll
    for(int c=0;c<4;c++) acc[a][c]=(f32x4){0.f,0.f,0.f,0.f};
  const unsigned short* Ag = A + (size_t)l*640*768;
  const unsigned short* Bg = B + (size_t)l*1536*768;
  int row_a = wr*64 + (lane&15);
  int row_b = wc*64 + (lane&15);
  int ko = (lane>>4)*8;
  for(int kt=0; kt<768; kt+=32){
    #pragma unroll
    for(int it=0; it<2; it++){
      int q = t + 256*it;
      int r = q>>2, c8 = (q&3)*8;
      *(uint4*)&As[r][c8] = *(const uint4*)&Ag[(size_t)(m0+r)*768 + kt + c8];
      *(uint4*)&Bs[r][c8] = *(const uint4*)&Bg[(size_t)(n0+r)*768 + kt + c8];
    }
    __syncthreads();
    short8v af[4], bfv[4];
    #pragma unroll
    for(int f=0; f<4; f++){
      af[f]  = *(const short8v*)&As[row_a + f*16][ko];
      bfv[f] = *(const short8v*)&Bs[row_b + f*16][ko];
    }
    #pragma unroll
    for(int fm=0;fm<4;fm++)
      #pragma unroll
      for(int fn=0;fn<4;fn++)
        acc[fm][fn] = __builtin_amdgcn_mfma_f32_16x16x32_bf16(af[fm], bfv[fn], acc[fm][fn], 0,0,0);
    __syncthreads();
  }
  #pragma unroll
  for(int fm=0;fm<4;fm++){
    int mb = m0 + wr*64 + fm*16 + ((lane>>4)*4);
    #pragma unroll
    for(int fn=0;fn<4;fn++){
      int n = n0 + wc*64 + fn*16 + (lane&15);
      if(n<1520){
        #pragma unroll
        for(int r=0;r<4;r++){
          int m = mb + r;
          if(m<608) Cf[((size_t)(l*608)+m)*1520 + n] = acc[fm][fn][r];
        }
      }
    }
  }
}

// conv2 inverse: block=(o,b), loop j. Z slice staged in LDS once.
__global__ __launch_bounds__(256) void k6(const float2* __restrict__ Z,
                                          const float* __restrict__ D2I,
                                          const float2* __restrict__ I2g,
                                          const float* __restrict__ b2,
                                          float* __restrict__ h2){
  int o=blockIdx.x, b=blockIdx.y;
  __shared__ float2 sZ[10][19][19];
  __shared__ float  sI2r[20][21], sI2i[20][21];
  __shared__ float2 sA[19][19];
  __shared__ float2 sT[20][19];
  int t=threadIdx.x;
  for(int q=t;q<380;q+=256){ float2 e=I2g[q]; sI2r[q/19][q%19]=e.x; sI2i[q/19][q%19]=e.y; }
  for(int q=t;q<3610;q+=256){
    int l=q/361, r=q%361, m=r/19, k=r%19;
    sZ[l][m][k]=Z[(size_t)(l*608 + b*19+m)*760 + o*19+k];
  }
  __syncthreads();
  float bias=b2[o];
  for(int j=0;j<20;j++){
    for(int q=t;q<361;q+=256){
      int m=q/19, k=q%19; float sr=0.f, si=0.f;
      #pragma unroll
      for(int l=0;l<10;l++){
        float d=D2I[((l*20+j)*19+m)*19+k];
        float2 z=sZ[l][m][k];
        sr += z.x*d; si += z.y*d;
      }
      sA[m][k]=make_float2(sr,si);
    }
    __syncthreads();
    for(int q=t;q<380;q+=256){
      int p=q/19, k=q%19; float sr=0.f, si=0.f;
      #pragma unroll
      for(int m=0;m<19;m++){
        float er=sI2r[p][m], ei=sI2i[p][m]; float2 a=sA[m][k];
        sr += er*a.x - ei*a.y; si += er*a.y + ei*a.x;
      }
      sT[p][k]=make_float2(sr,si);
    }
    __syncthreads();
    for(int q=t;q<400;q+=256){
      int p=q/20, qq=q%20; float s=0.f;
      #pragma unroll
      for(int k=0;k<19;k++){ float2 tt=sT[p][k]; s += tt.x*sI2r[qq][k] - tt.y*sI2i[qq][k]; }
      s += bias; s = fmaxf(s,0.f);
      h2[((((size_t)b*40+o)*20+j)*20+p)*20+qq]=s;
    }
    __syncthreads();
  }
}

// g[b,f] = (2pi/20)^2 * sum_{j,p,q} h2 * W_INT[j]
__global__ __launch_bounds__(256) void k7a(const float* __restrict__ h2,
                                           const float* __restrict__ WI,
                                           float* __restrict__ g){
  int bf=blockIdx.x;
  const float* base=h2 + (size_t)bf*8000;
  int t=threadIdx.x; float s=0.f;
  for(int q=t;q<8000;q+=256) s += base[q]*WI[q/400];
  __shared__ float red[256];
  red[t]=s; __syncthreads();
  for(int off=128;off>0;off>>=1){ if(t<off) red[t]+=red[t+off]; __syncthreads(); }
  if(t==0){
    const float c=(float)((2.0*M_PI/20.0)*(2.0*M_PI/20.0));
    g[bf]=red[0]*c;
  }
}

// out[b,c] = sum_f g[b,f]*w_lin[c,f] + bl[c]
__global__ __launch_bounds__(64) void k7b(const float* __restrict__ g,
                                          const float* __restrict__ wlin,
                                          const float* __restrict__ bl,
                                          float* __restrict__ out){
  int idx=blockIdx.x*64+threadIdx.x;
  if(idx>=320) return;
  int b=idx/10, c=idx%10;
  float s=bl[c];
  for(int f=0;f<40;f++) s += g[b*40+f]*wlin[c*40+f];
  out[b*10+c]=s;
}

extern "C" void kernel_launch(void* const* d_in, const int* in_sizes, int n_in,
                              void* d_out, int out_size, void* d_ws, size_t ws_size,
                              hipStream_t stream){
  (void)in_sizes; (void)n_in; (void)out_size;
  const float* x    = (const float*)d_in[0];
  const float* w1   = (const float*)d_in[1];
  const float* b1   = (const float*)d_in[2];
  const float* w2   = (const float*)d_in[3];
  const float* b2   = (const float*)d_in[4];
  const float* wlin = (const float*)d_in[5];
  const float* bl   = (const float*)d_in[6];
  float* out = (float*)d_out;
  char*  ws  = (char*)d_ws;

  if(ws_size < WS_NEED){
    fprintf(stderr, "kernel_launch: ws too small: have %zu need %lu\n", ws_size, WS_NEED);
  }

  float* C = (float*)(ws + WOFF_CONST);
  const float*  D1F = C + OFF_D1F;
  const float*  D1I = C + OFF_D1I;
  const float2* Y1  = (const float2*)(C + OFF_Y1);
  const float*  D2F = C + OFF_D2F;
  const float*  D2I = C + OFF_D2I;
  const float2* Y2  = (const float2*)(C + OFF_Y2);
  const float*  WI  = C + OFF_WI;
  const float2* E1  = (const float2*)(C + OFF_E1);
  const float2* I1  = (const float2*)(C + OFF_I1);
  const float2* E2  = (const float2*)(C + OFF_E2);
  const float2* I2  = (const float2*)(C + OFF_I2);

  float2* xf1   = (float2*)(ws + WOFF_XF1);
  float2* X1    = (float2*)(ws + WOFF_X1);
  float2* psi1c = (float2*)(ws + WOFF_PSI1);
  float*  h1    = (float*)(ws + WOFF_H1);
  float2* P2    = (float2*)(ws + WOFF_P2);
  unsigned short* Aaug = (unsigned short*)(ws + WOFF_AAUG);
  unsigned short* Bt   = (unsigned short*)(ws + WOFF_BT);
  float*  Zf    = (float*)(ws + WOFF_Z);
  float*  h2    = (float*)(ws + WOFF_H2);
  float*  g     = (float*)(ws + WOFF_G);

  hipLaunchKernelGGL(kconst, dim3(2048), dim3(256), 0, stream, C);
  hipLaunchKernelGGL(kfill, dim3(2048), dim3(256), 0, stream,
                     (uint4*)(ws + WOFF_AAUG), (long)((9830400ul+23592960ul)/16ul));

  hipLaunchKernelGGL(k1a, dim3((32*60*29+255)/256), dim3(256), 0, stream, x, E1, xf1);
  hipLaunchKernelGGL(k1b, dim3((32*15*29+255)/256), dim3(256), 0, stream, xf1, D1F, X1);
  hipLaunchKernelGGL(kpsi1, dim3((15*29*20+255)/256), dim3(256), 0, stream, w1, Y1, psi1c);
  hipLaunchKernelGGL(k2, dim3(30,32), dim3(256), 0, stream, X1, psi1c, D1I, I1, b1, h1);
  hipLaunchKernelGGL(k4, dim3(20,32), dim3(256), 0, stream, h1, D2F, E2, Aaug);
  hipLaunchKernelGGL(k3, dim3(3610), dim3(256), 0, stream, w2, Y2, P2);
  hipLaunchKernelGGL(kB, dim3(760,10), dim3(128), 0, stream, P2, Bt);
  hipLaunchKernelGGL(k5, dim3(12,5,10), dim3(256), 0, stream, Aaug, Bt, Zf);
  hipLaunchKernelGGL(k6, dim3(40,32), dim3(256), 0, stream, (const float2*)Zf, D2I, I2, b2, h2);
  hipLaunchKernelGGL(k7a, dim3(1280), dim3(256), 0, stream, h2, WI, g);
  hipLaunchKernelGGL(k7b, dim3(5), dim3(64), 0, stream, g, wlin, bl, out);
}

// Round 3
// 904.328 us; speedup vs baseline: 1.6657x; 1.5280x over previous
//
#include <hip/hip_runtime.h>
#include <cmath>
#include <cstdio>

#ifndef M_PI
#define M_PI 3.14159265358979323846
#endif

// ---------------- constant table offsets (in floats) ----------------
#define OFF_D1F 0        // [15][60][29]
#define OFF_D1I 26100    // [15][30][29][29]
#define OFF_Y1  404550   // [15][29][24] complex
#define OFF_D2F 425430   // [10][30][19][19]
#define OFF_D2I 533730   // [10][20][19][19]
#define OFF_Y2  605930   // [10][19][19][192] complex
#define OFF_WI  1992170  // [20]
#define OFF_E1  1992190  // [29][60] complex
#define OFF_I1  1995670  // [30][29] complex
#define OFF_E2  1997410  // [19][30] complex
#define OFF_I2  1998550  // [20][19] complex
#define OFF_DHW30 1999310 // [60]
#define OFF_DHW15 1999370 // [30]
#define NCONST  1999400

// ---------------- workspace byte offsets ----------------
// CONST  [0, 8,000,000)
// A_aug  [8,000,000, 17,830,400)    bf16 [10][640][768]
// B_augT [17,830,400, 41,423,360)   bf16 [10][1536][768]
// h1     [41,423,360, 75,983,360)   bf16 [32][20][30^3]
//   P2 overlays h1 head [41,423,360, 64,527,360)  (written by k3 AFTER k4)
// Z      [75,983,360, 112,949,760)  f32 [10][608][1520]
// h2     [8,000,000, 48,960,000)    f32 (overlays A,B,P2 - all dead by k6)
#define WOFF_CONST 0ul
#define WOFF_AAUG  8000000ul
#define WOFF_BT    17830400ul
#define WOFF_H1    41423360ul
#define WOFF_P2    41423360ul
#define WOFF_Z     75983360ul
#define WOFF_H2    8000000ul
#define WOFF_XF1   112949760ul
#define WOFF_X1    (112949760ul + 445440ul)
#define WOFF_PSI1  (112949760ul + 445440ul + 111360ul)
#define WOFF_G     (112949760ul + 445440ul + 111360ul + 69600ul)
#define WS_NEED    (WOFF_G + 5120ul)

typedef __attribute__((ext_vector_type(8))) short short8v;
typedef __attribute__((ext_vector_type(4))) float f32x4;

__device__ inline unsigned short f2bf(float x){
  unsigned int u = __float_as_uint(x);
  u += 0x7FFFu + ((u >> 16) & 1u);
  return (unsigned short)(u >> 16);
}
__device__ inline float bf2f(unsigned short u){
  return __uint_as_float(((unsigned int)u) << 16);
}

// ================= device helpers for constant generation =================
__device__ inline double dfact(int n){ double r=1.0; for(int i=2;i<=n;i++) r*=(double)i; return r; }
__device__ inline double dpowi(double x,int e){ double r=1.0; for(int i=0;i<e;i++) r*=x; return r; }
// Wigner small-d via k-recurrence (no per-k factorials)
__device__ double wig(int l,int m,int n,double beta){
  if(m < -l || m > l || n < -l || n > l) return 0.0;
  double cb=cos(0.5*beta), sb=sin(0.5*beta);
  double pref=sqrt(dfact(l+m)*dfact(l-m)*dfact(l+n)*dfact(l-n));
  int k0 = (m-n)>0 ? (m-n) : 0;
  int k1 = (l+m) < (l-n) ? (l+m) : (l-n);
  double c0 = ((k0&1)?-1.0:1.0)/(dfact(k0)*dfact(l+m-k0)*dfact(l-n-k0)*dfact(n-m+k0));
  double t = c0 * dpowi(cb, 2*l+m-n-2*k0) * dpowi(sb, n-m+2*k0);
  double ratio = (sb*sb)/(cb*cb);
  double s = t;
  for(int k=k0;k<k1;k++){
    t *= -((double)(l+m-k)*(double)(l-n-k)) / ((double)(k+1)*(double)(n-m+k+1)) * ratio;
    s += t;
  }
  return pref*s;
}
__device__ inline double dh_w(int b,int j){
  double s=0.0;
  for(int k=0;k<b;k++) s += sin((2.0*j+1.0)*(2.0*k+1.0)*M_PI/(4.0*b))/(2.0*k+1.0);
  return (2.0/b)*sin(M_PI*(2.0*j+1.0)/(4.0*b))*s;
}
__device__ inline double soft_beta(int b,int j){ return M_PI*(2.0*j+1.0)/(4.0*b); }
// cos/sin of q*pi/4
__device__ inline void octcs(int q, double* c, double* s){
  const double r = 0.70710678118654752440;
  int i = q & 7;
  const double C[8]={1.0,r,0.0,-r,-1.0,-r,0.0,r};
  const double S[8]={0.0,r,1.0,r,0.0,-r,-1.0,-r};
  *c=C[i]; *s=S[i];
}

// small tables: quadrature weights + DFT twiddles
__global__ __launch_bounds__(256) void kconst0(float* __restrict__ C){
  for(int idx = blockIdx.x*256 + threadIdx.x; idx < 3670; idx += gridDim.x*256){
    if(idx < 20){ C[OFF_WI+idx]=(float)dh_w(10,idx); }
    else if(idx < 80){ int j=idx-20; C[OFF_DHW30+j]=(float)dh_w(30,j); }
    else if(idx < 110){ int j=idx-80; C[OFF_DHW15+j]=(float)dh_w(15,j); }
    else if(idx < 1850){ int q=idx-110; // E1 [29][60]
      int a=q%60; int m=q/60; double ph=-2.0*M_PI*(double)(m-14)*a/60.0;
      C[OFF_E1+2*q]=(float)cos(ph); C[OFF_E1+2*q+1]=(float)sin(ph);
    } else if(idx < 2720){ int q=idx-1850; // I1 [30][29]
      int m=q%29; int p=q/29; double ph=2.0*M_PI*(double)p*(double)(m-14)/30.0;
      C[OFF_I1+2*q]=(float)cos(ph); C[OFF_I1+2*q+1]=(float)sin(ph);
    } else if(idx < 3290){ int q=idx-2720; // E2 [19][30]
      int a=q%30; int m=q/30; double ph=-2.0*M_PI*(double)(m-9)*a/30.0;
      C[OFF_E2+2*q]=(float)cos(ph); C[OFF_E2+2*q+1]=(float)sin(ph);
    } else { int q=idx-3290; // I2 [20][19]
      int m=q%19; int p=q/19; double ph=2.0*M_PI*(double)p*(double)(m-9)/20.0;
      C[OFF_I2+2*q]=(float)cos(ph); C[OFF_I2+2*q+1]=(float)sin(ph);
    }
  }
}

// big tables (reads DHW tables written by kconst0)
__global__ __launch_bounds__(256) void kconst(float* __restrict__ C){
  for(long idx = (long)blockIdx.x*blockDim.x + threadIdx.x; idx < 1288610L;
      idx += (long)gridDim.x*blockDim.x){
    if(idx < 26100L){                       // D1F [15][60][29]
      int m=(int)(idx%29); int j=(int)((idx/29)%60); int l=(int)(idx/(29*60));
      C[OFF_D1F+idx] = (float)( wig(l, m-14, 0, soft_beta(30,j)) * (double)C[OFF_DHW30+j] );
    } else if(idx < 404550L){ long q=idx-26100L;   // D1I [15][30][29][29]
      int n=(int)(q%29); int m=(int)((q/29)%29); int j=(int)((q/841)%30); int l=(int)(q/(841*30));
      C[OFF_D1I+q] = (float)wig(l, m-14, n-14, soft_beta(15,j));
    } else if(idx < 414990L){ long q=idx-404550L;  // Y1 [15][29][24] complex
      int g=(int)(q%24); int m=(int)((q/24)%29); int l=(int)(q/(24*29));
      double gb=((g>>3)+1)*(M_PI/8.0)/3.0;
      int ka = g&7;
      double mag=(2*l+1)*wig(l, m-14, 0, gb);
      double cc,ss; octcs((m-14)*ka, &cc, &ss);
      C[OFF_Y1+2*q]  =(float)(mag*cc);
      C[OFF_Y1+2*q+1]=(float)(-mag*ss);
    } else if(idx < 523290L){ long q=idx-414990L;  // D2F [10][30][19][19]
      int n=(int)(q%19); int m=(int)((q/19)%19); int j=(int)((q/361)%30); int l=(int)(q/(361*30));
      C[OFF_D2F+q]=(float)( wig(l,m-9,n-9,soft_beta(15,j)) * (double)C[OFF_DHW15+j] );
    } else if(idx < 595490L){ long q=idx-523290L;  // D2I [10][20][19][19]
      int n=(int)(q%19); int m=(int)((q/19)%19); int j=(int)((q/361)%20); int l=(int)(q/(361*20));
      C[OFF_D2I+q]=(float)wig(l,m-9,n-9,soft_beta(10,j));
    } else { long q=idx-595490L;                   // Y2 [10][19][19][192] complex
      int g=(int)(q%192); int n=(int)((q/192)%19); int m=(int)((q/(192*19))%19); int l=(int)(q/(192*361));
      double gb=((g>>6)+1)*(M_PI/8.0)/3.0;
      int ka=(g>>3)&7, kg=g&7;
      double mag=(2*l+1)*wig(l,m-9,n-9,gb);
      double cc,ss; octcs((m-9)*ka + (n-9)*kg, &cc, &ss);
      C[OFF_Y2+2*q]  =(float)(mag*cc);
      C[OFF_Y2+2*q+1]=(float)(-mag*ss);
    }
  }
}

// zero A_aug + B_augT (contiguous region)
__global__ __launch_bounds__(256) void kfill(uint4* __restrict__ p, long n16){
  uint4 z; z.x=0u; z.y=0u; z.z=0u; z.w=0u;
  for(long i=(long)blockIdx.x*256+threadIdx.x; i<n16; i+=(long)gridDim.x*256) p[i]=z;
}

// ================= forward-pass kernels =================

__global__ __launch_bounds__(256) void k1a(const float* __restrict__ x,
                                           const float2* __restrict__ E1,
                                           float2* __restrict__ xf1){
  int idx = blockIdx.x*256 + threadIdx.x;
  if(idx >= 32*60*29) return;
  int m = idx % 29; int bj = idx / 29;
  const float* row = x + bj*60;
  float sr=0.f, si=0.f;
  for(int a=0;a<60;a++){ float2 e=E1[m*60+a]; float v=row[a]; sr+=v*e.x; si+=v*e.y; }
  xf1[idx] = make_float2(sr,si);
}

__global__ __launch_bounds__(256) void k1b(const float2* __restrict__ xf1,
                                           const float* __restrict__ D1F,
                                           float2* __restrict__ X1){
  int idx = blockIdx.x*256 + threadIdx.x;
  if(idx >= 32*15*29) return;
  int m = idx % 29; int lb = idx / 29; int l = lb % 15; int b = lb / 15;
  float sr=0.f, si=0.f;
  for(int j=0;j<60;j++){
    float d = D1F[(l*60+j)*29+m]; float2 v = xf1[(b*60+j)*29+m];
    sr += d*v.x; si += d*v.y;
  }
  X1[(b*15+l)*29+m] = make_float2(sr,si);
}

// psi1cO[o][l*29+n] = conj( sum_g w1[0,o,g] * Y1[l,n,g] )
__global__ __launch_bounds__(256) void kpsi1(const float* __restrict__ w1,
                                             const float2* __restrict__ Y1,
                                             float2* __restrict__ psi1cO){
  int idx = blockIdx.x*256 + threadIdx.x;
  if(idx >= 15*29*20) return;
  int o = idx % 20; int ln = idx / 20;
  float sr=0.f, si=0.f;
  for(int g=0;g<24;g++){ float w=w1[o*24+g]; float2 y=Y1[ln*24+g]; sr+=w*y.x; si+=w*y.y; }
  psi1cO[o*435 + ln] = make_float2(sr,-si);
}

// conv1 fused, MFMA for both inverse DFTs.
// block=(o,b), 512 thr (8 waves). Per j: stage A (VALU, P cached in regs) ->
// An (bf16 LDS, augmented) -> stage B MFMA T=I1aug@An -> stage C MFMA y=Tflat@I1C
__global__ __launch_bounds__(512) void k2(const float2* __restrict__ X1,
                                          const float2* __restrict__ psi1cO,
                                          const float* __restrict__ D1I,
                                          const float2* __restrict__ I1g,
                                          const float* __restrict__ b1,
                                          unsigned short* __restrict__ h1){
  int o=blockIdx.x, b=blockIdx.y;
  __shared__ float2 sX[15][29];
  __shared__ float2 sP[15][29];
  __shared__ __align__(16) unsigned short I1A[64][72];
  __shared__ __align__(16) unsigned short I1C[32][72];
  __shared__ __align__(16) unsigned short An[32][72];
  __shared__ __align__(16) unsigned short Tl[32][72];
  int t=threadIdx.x;
  for(int q=t;q<435;q+=512){ ((float2*)sX)[q]=X1[b*435+q]; ((float2*)sP)[q]=psi1cO[o*435+q]; }
  // I1A rows 0..29: [I1r | -I1i]; rows 32..61: [I1i | I1r]; zero elsewhere
  for(int q=t;q<64*72;q+=512){
    int R=q/72, k=q%72; float v=0.f;
    if(k<64){ int kk=k&31, kh=k>>5;
      if(kk<29){
        if(R<30){ float2 e=I1g[R*29+kk]; v = kh ? -e.y : e.x; }
        else if(R>=32 && R<62){ float2 e=I1g[(R-32)*29+kk]; v = kh ? e.x : e.y; }
      }
    }
    I1A[R][k]=f2bf(v);
  }
  // I1C rows q<30: [I1r | -I1i]
  for(int q=t;q<32*72;q+=512){
    int Qr=q/72, k=q%72; float v=0.f;
    if(Qr<30 && k<64){ int kk=k&31, kh=k>>5;
      if(kk<29){ float2 e=I1g[Qr*29+kk]; v = kh ? -e.y : e.x; }
    }
    I1C[Qr][k]=f2bf(v);
  }
  // zero An pad rows 29..31 (avoid NaN garbage entering T)
  for(int q=t;q<3*72;q+=512) An[29+q/72][q%72]=0;
  __syncthreads();
  // cache P = X1 * conj(psi) per (m,n) pair
  float Pr[2][15], Pi[2][15];
  #pragma unroll
  for(int s=0;s<2;s++){
    int id=t+512*s;
    if(id<841){
      int m=id/29, n=id%29;
      #pragma unroll
      for(int l=0;l<15;l++){
        float2 xx=sX[l][m], pp=sP[l][n];
        Pr[s][l]=xx.x*pp.x-xx.y*pp.y;
        Pi[s][l]=xx.x*pp.y+xx.y*pp.x;
      }
    }
  }
  int wid=t>>6, lane=t&63;
  int fr=lane&15, ko=(lane>>4)*8;
  int mwB=wid>>1, nwB=wid&1;
  short8v aB0 = *(const short8v*)&I1A[16*mwB+fr][ko];
  short8v aB1 = *(const short8v*)&I1A[16*mwB+fr][32+ko];
  int mwC=(wid>>1)&1, nwC=wid&1;
  short8v bC0 = *(const short8v*)&I1C[16*nwC+fr][ko];
  short8v bC1 = *(const short8v*)&I1C[16*nwC+fr][32+ko];
  float bias=b1[o];
  for(int j=0;j<30;j++){
    // stage A
    #pragma unroll
    for(int s=0;s<2;s++){
      int id=t+512*s;
      if(id<841){
        const float* dp = D1I + j*841 + id;
        float ar=0.f, ai=0.f;
        #pragma unroll
        for(int l=0;l<15;l++){ float d=dp[l*25230]; ar+=Pr[s][l]*d; ai+=Pi[s][l]*d; }
        int m=id/29, n=id%29;
        An[n][m]   =f2bf(ar);
        An[n][32+m]=f2bf(ai);
      }
    }
    __syncthreads();
    // stage B: T(64x32) = I1A(64x64) @ stacked-A(64x32); B-operand from An[n][k]
    f32x4 accB={0.f,0.f,0.f,0.f};
    short8v b0 = *(const short8v*)&An[16*nwB+fr][ko];
    short8v b1v= *(const short8v*)&An[16*nwB+fr][32+ko];
    accB=__builtin_amdgcn_mfma_f32_16x16x32_bf16(aB0,b0,accB,0,0,0);
    accB=__builtin_amdgcn_mfma_f32_16x16x32_bf16(aB1,b1v,accB,0,0,0);
    #pragma unroll
    for(int r=0;r<4;r++){
      int R=16*mwB+(lane>>4)*4+r;
      int cc=16*nwB+fr;
      Tl[R&31][(R>>5)*32+cc]=f2bf(accB[r]);
    }
    __syncthreads();
    // stage C: y(32x32) = Tflat(32x64) @ I1C^T ; waves 0..3
    if(wid<4){
      f32x4 accC={0.f,0.f,0.f,0.f};
      short8v a0 = *(const short8v*)&Tl[16*mwC+fr][ko];
      short8v a1 = *(const short8v*)&Tl[16*mwC+fr][32+ko];
      accC=__builtin_amdgcn_mfma_f32_16x16x32_bf16(a0,bC0,accC,0,0,0);
      accC=__builtin_amdgcn_mfma_f32_16x16x32_bf16(a1,bC1,accC,0,0,0);
      size_t base=((size_t)(b*20+o)*30+j)*900;
      #pragma unroll
      for(int r=0;r<4;r++){
        int p=16*mwC+(lane>>4)*4+r, qq=16*nwC+fr;
        if(p<30 && qq<30){
          float v=fmaxf(accC[r]+bias,0.f);
          h1[base+p*30+qq]=f2bf(v);
        }
      }
    }
    // no third sync needed: next stage A writes An (read only by stage B, done);
    // next stage B (after next sync) is the earliest Tl overwrite.
  }
}

// P2[l][(i,n)][(o,k)] = conj( sum_g w2[i,o,g] * Y2[l,k,n,g] )   (f32 complex)
__global__ __launch_bounds__(256) void k3(const float* __restrict__ w2,
                                          const float2* __restrict__ Y2,
                                          float2* __restrict__ P2){
  int blk=blockIdx.x;               // (l,k,n): l*361 + k*19 + n
  int n=blk%19; int kk=(blk/19)%19; int l=blk/361;
  __shared__ float2 sY[192];
  int t=threadIdx.x;
  for(int q=t;q<192;q+=256) sY[q]=Y2[((size_t)(l*19+kk)*19+n)*192+q];
  __syncthreads();
  for(int q=t;q<800;q+=256){
    int i=q/40, o=q%40; float sr=0.f, si=0.f;
    const float* wr = w2 + (size_t)(i*40+o)*192;
    for(int g=0;g<192;g++){ float w=wr[g]; float2 y=sY[g]; sr+=w*y.x; si+=w*y.y; }
    P2[(size_t)(l*380 + i*19+n)*760 + (o*19+kk)] = make_float2(sr,-si);
  }
}

// transpose P2 -> B_augT bf16: Bt[l][2c+ri][k_aug]
__global__ __launch_bounds__(128) void kB(const float2* __restrict__ P2,
                                          unsigned short* __restrict__ Bt){
  int c = blockIdx.x;      // 0..759
  int l = blockIdx.y;
  unsigned short* base = Bt + (size_t)l*1536*768;
  size_t r0 = (size_t)(2*c)*768, r1 = (size_t)(2*c+1)*768;
  for(int k=threadIdx.x; k<380; k+=128){
    float2 z = P2[((size_t)(l*380) + k)*760 + c];
    unsigned short zr=f2bf(z.x), zi=f2bf(z.y), nzi=f2bf(-z.y);
    base[r0 + k]       = zr;
    base[r0 + 384 + k] = nzi;
    base[r1 + k]       = zi;
    base[r1 + 384 + k] = zr;
  }
}

// per (b,i): fft2(30x30 -> 19x19) * D2F summed over j -> A_aug bf16
// 384 threads; acc in registers (thread = (m,n), acc[10] complex)
__global__ __launch_bounds__(384) void k4(const unsigned short* __restrict__ h1,
                                          const float* __restrict__ D2F,
                                          const float2* __restrict__ E2g,
                                          unsigned short* __restrict__ Aaug){
  int i=blockIdx.x, b=blockIdx.y;
  __shared__ float  tile[30][31];
  __shared__ float2 t1[30][19];
  __shared__ float2 sE2[19][30];
  int t=threadIdx.x;
  for(int q=t;q<570;q+=384) ((float2*)sE2)[q]=E2g[q];
  float accr[10], acci[10];
  #pragma unroll
  for(int l=0;l<10;l++){ accr[l]=0.f; acci[l]=0.f; }
  int m=t/19, n=t%19;   // valid for t<361
  __syncthreads();
  for(int j=0;j<30;j++){
    const uint2* src=(const uint2*)(h1 + ((size_t)(b*20+i)*30+j)*900);
    if(t<225){
      uint2 v=src[t];
      int base4=t*4;
      float f0=bf2f((unsigned short)(v.x&0xFFFF)), f1=bf2f((unsigned short)(v.x>>16));
      float f2=bf2f((unsigned short)(v.y&0xFFFF)), f3=bf2f((unsigned short)(v.y>>16));
      tile[(base4)/30][(base4)%30]=f0;
      tile[(base4+1)/30][(base4+1)%30]=f1;
      tile[(base4+2)/30][(base4+2)%30]=f2;
      tile[(base4+3)/30][(base4+3)%30]=f3;
    }
    __syncthreads();
    for(int q=t;q<570;q+=384){
      int a=q/19, nn=q%19; float sr=0.f, si=0.f;
      #pragma unroll
      for(int g=0;g<30;g++){ float vv=tile[a][g]; float2 e=sE2[nn][g]; sr+=vv*e.x; si+=vv*e.y; }
      t1[a][nn]=make_float2(sr,si);
    }
    __syncthreads();
    if(t<361){
      float xr=0.f, xi=0.f;
      #pragma unroll
      for(int a=0;a<30;a++){
        float2 e=sE2[m][a], v2=t1[a][n];
        xr += e.x*v2.x - e.y*v2.y;
        xi += e.x*v2.y + e.y*v2.x;
      }
      const float* dp = D2F + j*361 + t;
      #pragma unroll
      for(int l=0;l<10;l++){ float d=dp[l*10830]; accr[l]+=d*xr; acci[l]+=d*xi; }
    }
    // next tile write only races with stage1 (done before 2nd sync); stage2
    // reads t1 which is only overwritten after the next first sync.
  }
  if(t<361){
    #pragma unroll
    for(int l=0;l<10;l++){
      size_t row=((size_t)(l*640) + b*19+m)*768;
      Aaug[row + i*19+n]       = f2bf(accr[l]);
      Aaug[row + 384 + i*19+n] = f2bf(acci[l]);
    }
  }
}

// bf16 MFMA GEMM per l: Cf[l](608x1520 f32) = A_aug[l](640x768) x B_augT[l]^T(768x1536)
__global__ __launch_bounds__(256) void k5(const unsigned short* __restrict__ A,
                                          const unsigned short* __restrict__ B,
                                          float* __restrict__ Cf){
  int l = blockIdx.z;
  int m0 = blockIdx.y*128, n0 = blockIdx.x*128;
  __shared__ unsigned short As[128][40];
  __shared__ unsigned short Bs[128][40];
  int t = threadIdx.x;
  int wid = t>>6, lane = t&63;
  int wr = wid>>1, wc = wid&1;
  f32x4 acc[4][4];
  #pragma unroll
  for(int a=0;a<4;a++)
    #pragma unroll
    for(int c=0;c<4;c++) acc[a][c]=(f32x4){0.f,0.f,0.f,0.f};
  const unsigned short* Ag = A + (size_t)l*640*768;
  const unsigned short* Bg = B + (size_t)l*1536*768;
  int row_a = wr*64 + (lane&15);
  int row_b = wc*64 + (lane&15);
  int ko = (lane>>4)*8;
  for(int kt=0; kt<768; kt+=32){
    #pragma unroll
    for(int it=0; it<2; it++){
      int q = t + 256*it;
      int r = q>>2, c8 = (q&3)*8;
      *(uint4*)&As[r][c8] = *(const uint4*)&Ag[(size_t)(m0+r)*768 + kt + c8];
      *(uint4*)&Bs[r][c8] = *(const uint4*)&Bg[(size_t)(n0+r)*768 + kt + c8];
    }
    __syncthreads();
    short8v af[4], bfv[4];
    #pragma unroll
    for(int f=0; f<4; f++){
      af[f]  = *(const short8v*)&As[row_a + f*16][ko];
      bfv[f] = *(const short8v*)&Bs[row_b + f*16][ko];
    }
    #pragma unroll
    for(int fm=0;fm<4;fm++)
      #pragma unroll
      for(int fn=0;fn<4;fn++)
        acc[fm][fn] = __builtin_amdgcn_mfma_f32_16x16x32_bf16(af[fm], bfv[fn], acc[fm][fn], 0,0,0);
    __syncthreads();
  }
  #pragma unroll
  for(int fm=0;fm<4;fm++){
    int mb = m0 + wr*64 + fm*16 + ((lane>>4)*4);
    #pragma unroll
    for(int fn=0;fn<4;fn++){
      int n = n0 + wc*64 + fn*16 + (lane&15);
      if(n<1520){
        #pragma unroll
        for(int r=0;r<4;r++){
          int m = mb + r;
          if(m<608) Cf[((size_t)(l*608)+m)*1520 + n] = acc[fm][fn][r];
        }
      }
    }
  }
}

// conv2 inverse: block=(o,b), loop j. Z slice staged in LDS once.
__global__ __launch_bounds__(256) void k6(const float2* __restrict__ Z,
                                          const float* __restrict__ D2I,
                                          const float2* __restrict__ I2g,
                                          const float* __restrict__ b2,
                                          float* __restrict__ h2){
  int o=blockIdx.x, b=blockIdx.y;
  __shared__ float2 sZ[10][19][19];
  __shared__ float  sI2r[20][21], sI2i[20][21];
  __shared__ float2 sA[19][19];
  __shared__ float2 sT[20][19];
  int t=threadIdx.x;
  for(int q=t;q<380;q+=256){ float2 e=I2g[q]; sI2r[q/19][q%19]=e.x; sI2i[q/19][q%19]=e.y; }
  for(int q=t;q<3610;q+=256){
    int l=q/361, r=q%361, m=r/19, k=r%19;
    sZ[l][m][k]=Z[(size_t)(l*608 + b*19+m)*760 + o*19+k];
  }
  __syncthreads();
  float bias=b2[o];
  for(int j=0;j<20;j++){
    for(int q=t;q<361;q+=256){
      int m=q/19, k=q%19; float sr=0.f, si=0.f;
      #pragma unroll
      for(int l=0;l<10;l++){
        float d=D2I[((l*20+j)*19+m)*19+k];
        float2 z=sZ[l][m][k];
        sr += z.x*d; si += z.y*d;
      }
      sA[m][k]=make_float2(sr,si);
    }
    __syncthreads();
    for(int q=t;q<380;q+=256){
      int p=q/19, k=q%19; float sr=0.f, si=0.f;
      #pragma unroll
      for(int m2=0;m2<19;m2++){
        float er=sI2r[p][m2], ei=sI2i[p][m2]; float2 a=sA[m2][k];
        sr += er*a.x - ei*a.y; si += er*a.y + ei*a.x;
      }
      sT[p][k]=make_float2(sr,si);
    }
    __syncthreads();
    for(int q=t;q<400;q+=256){
      int p=q/20, qq=q%20; float s=0.f;
      #pragma unroll
      for(int k=0;k<19;k++){ float2 tt=sT[p][k]; s += tt.x*sI2r[qq][k] - tt.y*sI2i[qq][k]; }
      s += bias; s = fmaxf(s,0.f);
      h2[((((size_t)b*40+o)*20+j)*20+p)*20+qq]=s;
    }
    __syncthreads();
  }
}

// g[b,f] = (2pi/20)^2 * sum_{j,p,q} h2 * W_INT[j]
__global__ __launch_bounds__(256) void k7a(const float* __restrict__ h2,
                                           const float* __restrict__ WI,
                                           float* __restrict__ g){
  int bf=blockIdx.x;
  const float* base=h2 + (size_t)bf*8000;
  int t=threadIdx.x; float s=0.f;
  for(int q=t;q<8000;q+=256) s += base[q]*WI[q/400];
  __shared__ float red[256];
  red[t]=s; __syncthreads();
  for(int off=128;off>0;off>>=1){ if(t<off) red[t]+=red[t+off]; __syncthreads(); }
  if(t==0){
    const float c=(float)((2.0*M_PI/20.0)*(2.0*M_PI/20.0));
    g[bf]=red[0]*c;
  }
}

__global__ __launch_bounds__(64) void k7b(const float* __restrict__ g,
                                          const float* __restrict__ wlin,
                                          const float* __restrict__ bl,
                                          float* __restrict__ out){
  int idx=blockIdx.x*64+threadIdx.x;
  if(idx>=320) return;
  int b=idx/10, c=idx%10;
  float s=bl[c];
  for(int f=0;f<40;f++) s += g[b*40+f]*wlin[c*40+f];
  out[b*10+c]=s;
}

extern "C" void kernel_launch(void* const* d_in, const int* in_sizes, int n_in,
                              void* d_out, int out_size, void* d_ws, size_t ws_size,
                              hipStream_t stream){
  (void)in_sizes; (void)n_in; (void)out_size;
  const float* x    = (const float*)d_in[0];
  const float* w1   = (const float*)d_in[1];
  const float* b1   = (const float*)d_in[2];
  const float* w2   = (const float*)d_in[3];
  const float* b2   = (const float*)d_in[4];
  const float* wlin = (const float*)d_in[5];
  const float* bl   = (const float*)d_in[6];
  float* out = (float*)d_out;
  char*  ws  = (char*)d_ws;

  if(ws_size < WS_NEED){
    fprintf(stderr, "kernel_launch: ws too small: have %zu need %lu\n", ws_size, WS_NEED);
  }

  float* C = (float*)(ws + WOFF_CONST);
  const float*  D1F = C + OFF_D1F;
  const float*  D1I = C + OFF_D1I;
  const float2* Y1  = (const float2*)(C + OFF_Y1);
  const float*  D2F = C + OFF_D2F;
  const float*  D2I = C + OFF_D2I;
  const float2* Y2  = (const float2*)(C + OFF_Y2);
  const float*  WI  = C + OFF_WI;
  const float2* E1  = (const float2*)(C + OFF_E1);
  const float2* I1  = (const float2*)(C + OFF_I1);
  const float2* E2  = (const float2*)(C + OFF_E2);
  const float2* I2  = (const float2*)(C + OFF_I2);

  float2* xf1   = (float2*)(ws + WOFF_XF1);
  float2* X1    = (float2*)(ws + WOFF_X1);
  float2* psi1c = (float2*)(ws + WOFF_PSI1);
  unsigned short* h1 = (unsigned short*)(ws + WOFF_H1);
  float2* P2    = (float2*)(ws + WOFF_P2);
  unsigned short* Aaug = (unsigned short*)(ws + WOFF_AAUG);
  unsigned short* Bt   = (unsigned short*)(ws + WOFF_BT);
  float*  Zf    = (float*)(ws + WOFF_Z);
  float*  h2    = (float*)(ws + WOFF_H2);
  float*  g     = (float*)(ws + WOFF_G);

  hipLaunchKernelGGL(kconst0, dim3(16), dim3(256), 0, stream, C);
  hipLaunchKernelGGL(kconst, dim3(2048), dim3(256), 0, stream, C);
  hipLaunchKernelGGL(kfill, dim3(2048), dim3(256), 0, stream,
                     (uint4*)(ws + WOFF_AAUG), (long)(33423360ul/16ul));

  hipLaunchKernelGGL(k1a, dim3((32*60*29+255)/256), dim3(256), 0, stream, x, E1, xf1);
  hipLaunchKernelGGL(k1b, dim3((32*15*29+255)/256), dim3(256), 0, stream, xf1, D1F, X1);
  hipLaunchKernelGGL(kpsi1, dim3((15*29*20+255)/256), dim3(256), 0, stream, w1, Y1, psi1c);
  hipLaunchKernelGGL(k2, dim3(20,32), dim3(512), 0, stream, X1, psi1c, D1I, I1, b1, h1);
  hipLaunchKernelGGL(k4, dim3(20,32), dim3(384), 0, stream, h1, D2F, E2, Aaug);
  hipLaunchKernelGGL(k3, dim3(3610), dim3(256), 0, stream, w2, Y2, P2);
  hipLaunchKernelGGL(kB, dim3(760,10), dim3(128), 0, stream, P2, Bt);
  hipLaunchKernelGGL(k5, dim3(12,5,10), dim3(256), 0, stream, Aaug, Bt, Zf);
  hipLaunchKernelGGL(k6, dim3(40,32), dim3(256), 0, stream, (const float2*)Zf, D2I, I2, b2, h2);
  hipLaunchKernelGGL(k7a, dim3(1280), dim3(256), 0, stream, h2, WI, g);
  hipLaunchKernelGGL(k7b, dim3(5), dim3(64), 0, stream, g, wlin, bl, out);
}

// Round 5
// 651.731 us; speedup vs baseline: 2.3113x; 1.3876x over previous
//
#include <hip/hip_runtime.h>
#include <cmath>
#include <cstdio>

#ifndef M_PI
#define M_PI 3.14159265358979323846
#endif

// ---------------- constant table offsets (in floats) ----------------
#define OFF_D1F 0        // [15][60][29]
#define OFF_D1I 26100    // [15][30][29][29]
#define OFF_Y1  404550   // [15][29][24] complex
#define OFF_D2F 425430   // [10][30][19][19]
#define OFF_D2I 533730   // [10][20][19][19]
#define OFF_WI  605930   // [20]
#define OFF_E1  605950   // [29][60] complex
#define OFF_I1  609430   // [30][29] complex
#define OFF_E2  611170   // [19][30] complex
#define OFF_I2  612310   // [20][19] complex
#define OFF_DHW30 613070 // [60]
#define OFF_DHW15 613130 // [30]
#define NCONST  613160

// ---------------- workspace byte offsets ----------------
// lifetimes: CONST permanent; Y2bf/w2bf until k3g; h1 k2->k4; Cpsi k3g->kBt
// (overlays h1); Aaug k4->k5; Bt kBt->k5; Z k5->k6 (overlays h1/Cpsi);
// h2 k6->k7a (overlays Y2bf/w2bf/Aaug head).
#define WOFF_CONST 0ul
#define WOFF_Y2BF  2457600ul                 // bf16 [10][768][192] = 2,949,120
#define WOFF_W2BF  5406720ul                 // bf16 [896][192]     =   344,064
#define WOFF_AAUG  5750784ul                 // bf16 [10][640][768] = 9,830,400
#define WOFF_BT    15581184ul                // bf16 [10][1536][768]= 23,592,960
#define WOFF_H1    39174144ul                // bf16 [32][20][27000]= 34,560,000
#define WOFF_CPSI  39174144ul                // f32 [10][896][768]  = 27,525,120 (h1 dead)
#define WOFF_Z     39174144ul                // f32 [10][608][1520] = 36,966,400 (Cpsi dead)
#define WOFF_H2    2457600ul                 // bf16 [32][40][8000] = 20,480,000
#define WOFF_XF1   76140544ul
#define WOFF_X1    (76140544ul + 445440ul)
#define WOFF_PSI1  (76140544ul + 445440ul + 111360ul)
#define WOFF_G     (76140544ul + 445440ul + 111360ul + 69600ul)
#define WS_NEED    (WOFF_G + 5120ul)

typedef __attribute__((ext_vector_type(8))) short short8v;
typedef __attribute__((ext_vector_type(4))) float f32x4;

__device__ inline unsigned short f2bf(float x){
  unsigned int u = __float_as_uint(x);
  u += 0x7FFFu + ((u >> 16) & 1u);
  return (unsigned short)(u >> 16);
}
__device__ inline float bf2f(unsigned short u){
  return __uint_as_float(((unsigned int)u) << 16);
}

// ================= device helpers for constant generation =================
__device__ inline double dfact(int n){ double r=1.0; for(int i=2;i<=n;i++) r*=(double)i; return r; }
__device__ inline double dpowi(double x,int e){ double r=1.0; for(int i=0;i<e;i++) r*=x; return r; }
// Wigner small-d via k-recurrence (no per-k factorials)
__device__ double wig(int l,int m,int n,double beta){
  if(m < -l || m > l || n < -l || n > l) return 0.0;
  double cb=cos(0.5*beta), sb=sin(0.5*beta);
  double pref=sqrt(dfact(l+m)*dfact(l-m)*dfact(l+n)*dfact(l-n));
  int k0 = (m-n)>0 ? (m-n) : 0;
  int k1 = (l+m) < (l-n) ? (l+m) : (l-n);
  double c0 = ((k0&1)?-1.0:1.0)/(dfact(k0)*dfact(l+m-k0)*dfact(l-n-k0)*dfact(n-m+k0));
  double t = c0 * dpowi(cb, 2*l+m-n-2*k0) * dpowi(sb, n-m+2*k0);
  double ratio = (sb*sb)/(cb*cb);
  double s = t;
  for(int k=k0;k<k1;k++){
    t *= -((double)(l+m-k)*(double)(l-n-k)) / ((double)(k+1)*(double)(n-m+k+1)) * ratio;
    s += t;
  }
  return pref*s;
}
__device__ inline double dh_w(int b,int j){
  double s=0.0;
  for(int k=0;k<b;k++) s += sin((2.0*j+1.0)*(2.0*k+1.0)*M_PI/(4.0*b))/(2.0*k+1.0);
  return (2.0/b)*sin(M_PI*(2.0*j+1.0)/(4.0*b))*s;
}
__device__ inline double soft_beta(int b,int j){ return M_PI*(2.0*j+1.0)/(4.0*b); }
// cos/sin of q*pi/4
__device__ inline void octcs(int q, double* c, double* s){
  const double r = 0.70710678118654752440;
  int i = q & 7;
  const double C[8]={1.0,r,0.0,-r,-1.0,-r,0.0,r};
  const double S[8]={0.0,r,1.0,r,0.0,-r,-1.0,-r};
  *c=C[i]; *s=S[i];
}

// small tables: quadrature weights + DFT twiddles
__global__ __launch_bounds__(256) void kconst0(float* __restrict__ C){
  for(int idx = blockIdx.x*256 + threadIdx.x; idx < 3670; idx += gridDim.x*256){
    if(idx < 20){ C[OFF_WI+idx]=(float)dh_w(10,idx); }
    else if(idx < 80){ int j=idx-20; C[OFF_DHW30+j]=(float)dh_w(30,j); }
    else if(idx < 110){ int j=idx-80; C[OFF_DHW15+j]=(float)dh_w(15,j); }
    else if(idx < 1850){ int q=idx-110; // E1 [29][60]
      int a=q%60; int m=q/60; double ph=-2.0*M_PI*(double)(m-14)*a/60.0;
      C[OFF_E1+2*q]=(float)cos(ph); C[OFF_E1+2*q+1]=(float)sin(ph);
    } else if(idx < 2720){ int q=idx-1850; // I1 [30][29]
      int m=q%29; int p=q/29; double ph=2.0*M_PI*(double)p*(double)(m-14)/30.0;
      C[OFF_I1+2*q]=(float)cos(ph); C[OFF_I1+2*q+1]=(float)sin(ph);
    } else if(idx < 3290){ int q=idx-2720; // E2 [19][30]
      int a=q%30; int m=q/30; double ph=-2.0*M_PI*(double)(m-9)*a/30.0;
      C[OFF_E2+2*q]=(float)cos(ph); C[OFF_E2+2*q+1]=(float)sin(ph);
    } else { int q=idx-3290; // I2 [20][19]
      int m=q%19; int p=q/19; double ph=2.0*M_PI*(double)p*(double)(m-9)/20.0;
      C[OFF_I2+2*q]=(float)cos(ph); C[OFF_I2+2*q+1]=(float)sin(ph);
    }
  }
}

// big tables (reads DHW tables written by kconst0). Y2 emitted directly as
// bf16 GEMM B-operand: [10][row=(k*19+n)*2+ri, 768-padded][g=192], packed u32.
__global__ __launch_bounds__(256) void kconst(float* __restrict__ C,
                                              unsigned int* __restrict__ Y2p){
  for(long idx = (long)blockIdx.x*blockDim.x + threadIdx.x; idx < 1332770L;
      idx += (long)gridDim.x*blockDim.x){
    if(idx < 26100L){                       // D1F [15][60][29]
      int m=(int)(idx%29); int j=(int)((idx/29)%60); int l=(int)(idx/(29*60));
      C[OFF_D1F+idx] = (float)( wig(l, m-14, 0, soft_beta(30,j)) * (double)C[OFF_DHW30+j] );
    } else if(idx < 404550L){ long q=idx-26100L;   // D1I [15][30][29][29]
      int n=(int)(q%29); int m=(int)((q/29)%29); int j=(int)((q/841)%30); int l=(int)(q/(841*30));
      C[OFF_D1I+q] = (float)wig(l, m-14, n-14, soft_beta(15,j));
    } else if(idx < 414990L){ long q=idx-404550L;  // Y1 [15][29][24] complex
      int g=(int)(q%24); int m=(int)((q/24)%29); int l=(int)(q/(24*29));
      double gb=((g>>3)+1)*(M_PI/8.0)/3.0;
      int ka = g&7;
      double mag=(2*l+1)*wig(l, m-14, 0, gb);
      double cc,ss; octcs((m-14)*ka, &cc, &ss);
      C[OFF_Y1+2*q]  =(float)(mag*cc);
      C[OFF_Y1+2*q+1]=(float)(-mag*ss);
    } else if(idx < 523290L){ long q=idx-414990L;  // D2F [10][30][19][19]
      int n=(int)(q%19); int m=(int)((q/19)%19); int j=(int)((q/361)%30); int l=(int)(q/(361*30));
      C[OFF_D2F+q]=(float)( wig(l,m-9,n-9,soft_beta(15,j)) * (double)C[OFF_DHW15+j] );
    } else if(idx < 595490L){ long q=idx-523290L;  // D2I [10][20][19][19]
      int n=(int)(q%19); int m=(int)((q/19)%19); int j=(int)((q/361)%20); int l=(int)(q/(361*20));
      C[OFF_D2I+q]=(float)wig(l,m-9,n-9,soft_beta(10,j));
    } else { long q=idx-595490L;                   // Y2bf pairs [10][768][96]
      int g2=(int)(q%96); int row=(int)((q/96)%768); int l=(int)(q/(96*768));
      unsigned int outv=0u;
      if(row<722){
        int kn=row>>1, ri=row&1, kk=kn/19, n=kn%19;
        int g0=2*g2;
        double gb=((g0>>6)+1)*(M_PI/8.0)/3.0;
        double mag=(2*l+1)*wig(l,kk-9,n-9,gb);
        int ka=(g0>>3)&7;
        double c0,s0,c1,s1;
        octcs((kk-9)*ka + (n-9)*(g0&7), &c0,&s0);
        octcs((kk-9)*ka + (n-9)*((g0+1)&7), &c1,&s1);
        float v0 = ri ? (float)(-mag*s0) : (float)(mag*c0);
        float v1 = ri ? (float)(-mag*s1) : (float)(mag*c1);
        outv = (unsigned int)f2bf(v0) | (((unsigned int)f2bf(v1))<<16);
      }
      Y2p[q]=outv;
    }
  }
}

// zero A_aug + B_augT (contiguous region)
__global__ __launch_bounds__(256) void kfill(uint4* __restrict__ p, long n16){
  uint4 z; z.x=0u; z.y=0u; z.z=0u; z.w=0u;
  for(long i=(long)blockIdx.x*256+threadIdx.x; i<n16; i+=(long)gridDim.x*256) p[i]=z;
}

// pack w2 -> bf16 [896][192] (rows >=800 zero), u32-paired
__global__ __launch_bounds__(256) void kw2(const float* __restrict__ w2,
                                           unsigned int* __restrict__ w2bf){
  int idx = blockIdx.x*256 + threadIdx.x;
  if(idx >= 896*96) return;
  int row=idx/96, g2=idx%96;
  float a=0.f, b=0.f;
  if(row<800){ a=w2[row*192+2*g2]; b=w2[row*192+2*g2+1]; }
  w2bf[idx] = (unsigned int)f2bf(a) | (((unsigned int)f2bf(b))<<16);
}

// ================= forward-pass kernels =================

__global__ __launch_bounds__(256) void k1a(const float* __restrict__ x,
                                           const float2* __restrict__ E1,
                                           float2* __restrict__ xf1){
  int idx = blockIdx.x*256 + threadIdx.x;
  if(idx >= 32*60*29) return;
  int m = idx % 29; int bj = idx / 29;
  const float* row = x + bj*60;
  float sr=0.f, si=0.f;
  for(int a=0;a<60;a++){ float2 e=E1[m*60+a]; float v=row[a]; sr+=v*e.x; si+=v*e.y; }
  xf1[idx] = make_float2(sr,si);
}

__global__ __launch_bounds__(256) void k1b(const float2* __restrict__ xf1,
                                           const float* __restrict__ D1F,
                                           float2* __restrict__ X1){
  int idx = blockIdx.x*256 + threadIdx.x;
  if(idx >= 32*15*29) return;
  int m = idx % 29; int lb = idx / 29; int l = lb % 15; int b = lb / 15;
  float sr=0.f, si=0.f;
  for(int j=0;j<60;j++){
    float d = D1F[(l*60+j)*29+m]; float2 v = xf1[(b*60+j)*29+m];
    sr += d*v.x; si += d*v.y;
  }
  X1[(b*15+l)*29+m] = make_float2(sr,si);
}

// psi1cO[o][l*29+n] = conj( sum_g w1[0,o,g] * Y1[l,n,g] )
__global__ __launch_bounds__(256) void kpsi1(const float* __restrict__ w1,
                                             const float2* __restrict__ Y1,
                                             float2* __restrict__ psi1cO){
  int idx = blockIdx.x*256 + threadIdx.x;
  if(idx >= 15*29*20) return;
  int o = idx % 20; int ln = idx / 20;
  float sr=0.f, si=0.f;
  for(int g=0;g<24;g++){ float w=w1[o*24+g]; float2 y=Y1[ln*24+g]; sr+=w*y.x; si+=w*y.y; }
  psi1cO[o*435 + ln] = make_float2(sr,-si);
}

// conv1 fused, MFMA for both inverse DFTs.
// NOTE: An/Tl are FULLY zero-initialized once — pad cols (29-31, 61-71) are
// contracted against I1A/I1C zero columns, but uninitialized LDS there can
// hold bf16-NaN patterns (0*NaN=NaN poisoned R4's graph replays).
__global__ __launch_bounds__(512) void k2(const float2* __restrict__ X1,
                                          const float2* __restrict__ psi1cO,
                                          const float* __restrict__ D1I,
                                          const float2* __restrict__ I1g,
                                          const float* __restrict__ b1,
                                          unsigned short* __restrict__ h1){
  int o=blockIdx.x, b=blockIdx.y;
  __shared__ float2 sX[15][29];
  __shared__ float2 sP[15][29];
  __shared__ __align__(16) unsigned short I1A[64][72];
  __shared__ __align__(16) unsigned short I1C[32][72];
  __shared__ __align__(16) unsigned short An[32][72];
  __shared__ __align__(16) unsigned short Tl[32][72];
  int t=threadIdx.x;
  for(int q=t;q<435;q+=512){ ((float2*)sX)[q]=X1[b*435+q]; ((float2*)sP)[q]=psi1cO[o*435+q]; }
  for(int q=t;q<64*72;q+=512){
    int R=q/72, k=q%72; float v=0.f;
    if(k<64){ int kk=k&31, kh=k>>5;
      if(kk<29){
        if(R<30){ float2 e=I1g[R*29+kk]; v = kh ? -e.y : e.x; }
        else if(R>=32 && R<62){ float2 e=I1g[(R-32)*29+kk]; v = kh ? e.x : e.y; }
      }
    }
    I1A[R][k]=f2bf(v);
  }
  for(int q=t;q<32*72;q+=512){
    int Qr=q/72, k=q%72; float v=0.f;
    if(Qr<30 && k<64){ int kk=k&31, kh=k>>5;
      if(kk<29){ float2 e=I1g[Qr*29+kk]; v = kh ? -e.y : e.x; }
    }
    I1C[Qr][k]=f2bf(v);
  }
  // full zero-init of MFMA staging tiles (pad lanes must be 0, not stale LDS)
  for(int q=t;q<32*72;q+=512){ An[q/72][q%72]=0; Tl[q/72][q%72]=0; }
  __syncthreads();
  float Pr[2][15], Pi[2][15];
  #pragma unroll
  for(int s=0;s<2;s++){
    int id=t+512*s;
    if(id<841){
      int m=id/29, n=id%29;
      #pragma unroll
      for(int l=0;l<15;l++){
        float2 xx=sX[l][m], pp=sP[l][n];
        Pr[s][l]=xx.x*pp.x-xx.y*pp.y;
        Pi[s][l]=xx.x*pp.y+xx.y*pp.x;
      }
    }
  }
  int wid=t>>6, lane=t&63;
  int fr=lane&15, ko=(lane>>4)*8;
  int mwB=wid>>1, nwB=wid&1;
  short8v aB0 = *(const short8v*)&I1A[16*mwB+fr][ko];
  short8v aB1 = *(const short8v*)&I1A[16*mwB+fr][32+ko];
  int mwC=(wid>>1)&1, nwC=wid&1;
  short8v bC0 = *(const short8v*)&I1C[16*nwC+fr][ko];
  short8v bC1 = *(const short8v*)&I1C[16*nwC+fr][32+ko];
  float bias=b1[o];
  for(int j=0;j<30;j++){
    #pragma unroll
    for(int s=0;s<2;s++){
      int id=t+512*s;
      if(id<841){
        const float* dp = D1I + j*841 + id;
        float ar=0.f, ai=0.f;
        #pragma unroll
        for(int l=0;l<15;l++){ float d=dp[l*25230]; ar+=Pr[s][l]*d; ai+=Pi[s][l]*d; }
        int m=id/29, n=id%29;
        An[n][m]   =f2bf(ar);
        An[n][32+m]=f2bf(ai);
      }
    }
    __syncthreads();
    f32x4 accB={0.f,0.f,0.f,0.f};
    short8v b0 = *(const short8v*)&An[16*nwB+fr][ko];
    short8v b1v= *(const short8v*)&An[16*nwB+fr][32+ko];
    accB=__builtin_amdgcn_mfma_f32_16x16x32_bf16(aB0,b0,accB,0,0,0);
    accB=__builtin_amdgcn_mfma_f32_16x16x32_bf16(aB1,b1v,accB,0,0,0);
    #pragma unroll
    for(int r=0;r<4;r++){
      int R=16*mwB+(lane>>4)*4+r;
      int cc=16*nwB+fr;
      Tl[R&31][(R>>5)*32+cc]=f2bf(accB[r]);
    }
    __syncthreads();
    if(wid<4){
      f32x4 accC={0.f,0.f,0.f,0.f};
      short8v a0 = *(const short8v*)&Tl[16*mwC+fr][ko];
      short8v a1 = *(const short8v*)&Tl[16*mwC+fr][32+ko];
      accC=__builtin_amdgcn_mfma_f32_16x16x32_bf16(a0,bC0,accC,0,0,0);
      accC=__builtin_amdgcn_mfma_f32_16x16x32_bf16(a1,bC1,accC,0,0,0);
      size_t base=((size_t)(b*20+o)*30+j)*900;
      #pragma unroll
      for(int r=0;r<4;r++){
        int p=16*mwC+(lane>>4)*4+r, qq=16*nwC+fr;
        if(p<30 && qq<30){
          float v=fmaxf(accC[r]+bias,0.f);
          h1[base+p*30+qq]=f2bf(v);
        }
      }
    }
  }
}

// psi2 GEMM: Cpsi[l](896x768 f32) = w2bf(896x192) x Y2bf[l]^T(192x768)
__global__ __launch_bounds__(256) void k3g(const unsigned short* __restrict__ A,
                                           const unsigned short* __restrict__ B,
                                           float* __restrict__ Cf){
  int l = blockIdx.z;
  int m0 = blockIdx.y*128, n0 = blockIdx.x*128;
  __shared__ unsigned short As[128][40];
  __shared__ unsigned short Bs[128][40];
  int t = threadIdx.x;
  int wid = t>>6, lane = t&63;
  int wr = wid>>1, wc = wid&1;
  f32x4 acc[4][4];
  #pragma unroll
  for(int a=0;a<4;a++)
    #pragma unroll
    for(int c=0;c<4;c++) acc[a][c]=(f32x4){0.f,0.f,0.f,0.f};
  const unsigned short* Ag = A;
  const unsigned short* Bg = B + (size_t)l*768*192;
  int row_a = wr*64 + (lane&15);
  int row_b = wc*64 + (lane&15);
  int ko = (lane>>4)*8;
  for(int kt=0; kt<192; kt+=32){
    #pragma unroll
    for(int it=0; it<2; it++){
      int q = t + 256*it;
      int r = q>>2, c8 = (q&3)*8;
      *(uint4*)&As[r][c8] = *(const uint4*)&Ag[(size_t)(m0+r)*192 + kt + c8];
      *(uint4*)&Bs[r][c8] = *(const uint4*)&Bg[(size_t)(n0+r)*192 + kt + c8];
    }
    __syncthreads();
    short8v af[4], bfv[4];
    #pragma unroll
    for(int f=0; f<4; f++){
      af[f]  = *(const short8v*)&As[row_a + f*16][ko];
      bfv[f] = *(const short8v*)&Bs[row_b + f*16][ko];
    }
    #pragma unroll
    for(int fm=0;fm<4;fm++)
      #pragma unroll
      for(int fn=0;fn<4;fn++)
        acc[fm][fn] = __builtin_amdgcn_mfma_f32_16x16x32_bf16(af[fm], bfv[fn], acc[fm][fn], 0,0,0);
    __syncthreads();
  }
  #pragma unroll
  for(int fm=0;fm<4;fm++){
    int mb = m0 + wr*64 + fm*16 + ((lane>>4)*4);
    #pragma unroll
    for(int fn=0;fn<4;fn++){
      int n = n0 + wc*64 + fn*16 + (lane&15);
      #pragma unroll
      for(int r=0;r<4;r++){
        Cf[((size_t)(l*896)+mb+r)*768 + n] = acc[fm][fn][r];
      }
    }
  }
}

// Cpsi -> B_augT bf16 (coalesced both sides)
__global__ __launch_bounds__(384) void kBt(const float* __restrict__ Cf,
                                           unsigned short* __restrict__ Bt){
  int c = blockIdx.x;      // o*19+kk
  int l = blockIdx.y;
  int t = threadIdx.x;
  if(t>=380) return;
  int i=t/19, n=t%19;
  int o=c/19, kk=c%19;
  float2 v = *(const float2*)&Cf[((size_t)(l*896) + i*40+o)*768 + (kk*19+n)*2];
  float zr = v.x, zi = -v.y;
  unsigned short* base = Bt + (size_t)l*1536*768;
  size_t r0=(size_t)(2*c)*768, r1=r0+768;
  int col=i*19+n;
  base[r0+col]     = f2bf(zr);
  base[r0+384+col] = f2bf(-zi);
  base[r1+col]     = f2bf(zi);
  base[r1+384+col] = f2bf(zr);
}

// per (b,i): fft2(30x30 -> 19x19) * D2F summed over j -> A_aug bf16
__global__ __launch_bounds__(384) void k4(const unsigned short* __restrict__ h1,
                                          const float* __restrict__ D2F,
                                          const float2* __restrict__ E2g,
                                          unsigned short* __restrict__ Aaug){
  int i=blockIdx.x, b=blockIdx.y;
  __shared__ float  tile[30][31];
  __shared__ float2 t1[30][19];
  __shared__ float2 sE2[19][30];
  int t=threadIdx.x;
  for(int q=t;q<570;q+=384) ((float2*)sE2)[q]=E2g[q];
  float accr[10], acci[10];
  #pragma unroll
  for(int l=0;l<10;l++){ accr[l]=0.f; acci[l]=0.f; }
  int m=t/19, n=t%19;
  __syncthreads();
  for(int j=0;j<30;j++){
    const uint2* src=(const uint2*)(h1 + ((size_t)(b*20+i)*30+j)*900);
    if(t<225){
      uint2 v=src[t];
      int base4=t*4;
      float f0=bf2f((unsigned short)(v.x&0xFFFF)), f1=bf2f((unsigned short)(v.x>>16));
      float f2v=bf2f((unsigned short)(v.y&0xFFFF)), f3=bf2f((unsigned short)(v.y>>16));
      tile[(base4)/30][(base4)%30]=f0;
      tile[(base4+1)/30][(base4+1)%30]=f1;
      tile[(base4+2)/30][(base4+2)%30]=f2v;
      tile[(base4+3)/30][(base4+3)%30]=f3;
    }
    __syncthreads();
    for(int q=t;q<570;q+=384){
      int a=q/19, nn=q%19; float sr=0.f, si=0.f;
      #pragma unroll
      for(int g=0;g<30;g++){ float vv=tile[a][g]; float2 e=sE2[nn][g]; sr+=vv*e.x; si+=vv*e.y; }
      t1[a][nn]=make_float2(sr,si);
    }
    __syncthreads();
    if(t<361){
      float xr=0.f, xi=0.f;
      #pragma unroll
      for(int a=0;a<30;a++){
        float2 e=sE2[m][a], v2=t1[a][n];
        xr += e.x*v2.x - e.y*v2.y;
        xi += e.x*v2.y + e.y*v2.x;
      }
      const float* dp = D2F + j*361 + t;
      #pragma unroll
      for(int l=0;l<10;l++){ float d=dp[l*10830]; accr[l]+=d*xr; acci[l]+=d*xi; }
    }
  }
  if(t<361){
    #pragma unroll
    for(int l=0;l<10;l++){
      size_t row=((size_t)(l*640) + b*19+m)*768;
      Aaug[row + i*19+n]       = f2bf(accr[l]);
      Aaug[row + 384 + i*19+n] = f2bf(acci[l]);
    }
  }
}

// bf16 MFMA GEMM per l: Z[l](608x1520 f32) = A_aug[l](640x768) x B_augT[l]^T
__global__ __launch_bounds__(256) void k5(const unsigned short* __restrict__ A,
                                          const unsigned short* __restrict__ B,
                                          float* __restrict__ Cf){
  int l = blockIdx.z;
  int m0 = blockIdx.y*128, n0 = blockIdx.x*128;
  __shared__ unsigned short As[128][40];
  __shared__ unsigned short Bs[128][40];
  int t = threadIdx.x;
  int wid = t>>6, lane = t&63;
  int wr = wid>>1, wc = wid&1;
  f32x4 acc[4][4];
  #pragma unroll
  for(int a=0;a<4;a++)
    #pragma unroll
    for(int c=0;c<4;c++) acc[a][c]=(f32x4){0.f,0.f,0.f,0.f};
  const unsigned short* Ag = A + (size_t)l*640*768;
  const unsigned short* Bg = B + (size_t)l*1536*768;
  int row_a = wr*64 + (lane&15);
  int row_b = wc*64 + (lane&15);
  int ko = (lane>>4)*8;
  for(int kt=0; kt<768; kt+=32){
    #pragma unroll
    for(int it=0; it<2; it++){
      int q = t + 256*it;
      int r = q>>2, c8 = (q&3)*8;
      *(uint4*)&As[r][c8] = *(const uint4*)&Ag[(size_t)(m0+r)*768 + kt + c8];
      *(uint4*)&Bs[r][c8] = *(const uint4*)&Bg[(size_t)(n0+r)*768 + kt + c8];
    }
    __syncthreads();
    short8v af[4], bfv[4];
    #pragma unroll
    for(int f=0; f<4; f++){
      af[f]  = *(const short8v*)&As[row_a + f*16][ko];
      bfv[f] = *(const short8v*)&Bs[row_b + f*16][ko];
    }
    #pragma unroll
    for(int fm=0;fm<4;fm++)
      #pragma unroll
      for(int fn=0;fn<4;fn++)
        acc[fm][fn] = __builtin_amdgcn_mfma_f32_16x16x32_bf16(af[fm], bfv[fn], acc[fm][fn], 0,0,0);
    __syncthreads();
  }
  #pragma unroll
  for(int fm=0;fm<4;fm++){
    int mb = m0 + wr*64 + fm*16 + ((lane>>4)*4);
    #pragma unroll
    for(int fn=0;fn<4;fn++){
      int n = n0 + wc*64 + fn*16 + (lane&15);
      if(n<1520){
        #pragma unroll
        for(int r=0;r<4;r++){
          int m = mb + r;
          if(m<608) Cf[((size_t)(l*608)+m)*1520 + n] = acc[fm][fn][r];
        }
      }
    }
  }
}

// conv2 inverse: block=(o,b), loop j. Z slice staged in LDS once. h2 bf16.
__global__ __launch_bounds__(256) void k6(const float2* __restrict__ Z,
                                          const float* __restrict__ D2I,
                                          const float2* __restrict__ I2g,
                                          const float* __restrict__ b2,
                                          unsigned short* __restrict__ h2){
  int o=blockIdx.x, b=blockIdx.y;
  __shared__ float2 sZ[10][19][19];
  __shared__ float  sI2r[20][21], sI2i[20][21];
  __shared__ float2 sA[19][19];
  __shared__ float2 sT[20][19];
  int t=threadIdx.x;
  for(int q=t;q<380;q+=256){ float2 e=I2g[q]; sI2r[q/19][q%19]=e.x; sI2i[q/19][q%19]=e.y; }
  for(int q=t;q<3610;q+=256){
    int l=q/361, r=q%361, m=r/19, k=r%19;
    sZ[l][m][k]=Z[(size_t)(l*608 + b*19+m)*760 + o*19+k];
  }
  __syncthreads();
  float bias=b2[o];
  for(int j=0;j<20;j++){
    for(int q=t;q<361;q+=256){
      int m=q/19, k=q%19; float sr=0.f, si=0.f;
      #pragma unroll
      for(int l=0;l<10;l++){
        float d=D2I[((l*20+j)*19+m)*19+k];
        float2 z=sZ[l][m][k];
        sr += z.x*d; si += z.y*d;
      }
      sA[m][k]=make_float2(sr,si);
    }
    __syncthreads();
    for(int q=t;q<380;q+=256){
      int p=q/19, k=q%19; float sr=0.f, si=0.f;
      #pragma unroll
      for(int m2=0;m2<19;m2++){
        float er=sI2r[p][m2], ei=sI2i[p][m2]; float2 a=sA[m2][k];
        sr += er*a.x - ei*a.y; si += er*a.y + ei*a.x;
      }
      sT[p][k]=make_float2(sr,si);
    }
    __syncthreads();
    for(int q=t;q<400;q+=256){
      int p=q/20, qq=q%20; float s=0.f;
      #pragma unroll
      for(int k=0;k<19;k++){ float2 tt=sT[p][k]; s += tt.x*sI2r[qq][k] - tt.y*sI2i[qq][k]; }
      s += bias; s = fmaxf(s,0.f);
      h2[((((size_t)b*40+o)*20+j)*20+p)*20+qq]=f2bf(s);
    }
    __syncthreads();
  }
}

// g[b,f] = (2pi/20)^2 * sum_{j,p,q} h2 * W_INT[j]   (h2 bf16, paired reads)
__global__ __launch_bounds__(256) void k7a(const unsigned int* __restrict__ h2p,
                                           const float* __restrict__ WI,
                                           float* __restrict__ g){
  int bf=blockIdx.x;
  const unsigned int* base=h2p + (size_t)bf*4000;
  int t=threadIdx.x; float s=0.f;
  for(int q=t;q<4000;q+=256){
    unsigned int v=base[q];
    float w=WI[q/200];
    s += (bf2f((unsigned short)(v&0xFFFF))+bf2f((unsigned short)(v>>16)))*w;
  }
  __shared__ float red[256];
  red[t]=s; __syncthreads();
  for(int off=128;off>0;off>>=1){ if(t<off) red[t]+=red[t+off]; __syncthreads(); }
  if(t==0){
    const float c=(float)((2.0*M_PI/20.0)*(2.0*M_PI/20.0));
    g[bf]=red[0]*c;
  }
}

__global__ __launch_bounds__(64) void k7b(const float* __restrict__ g,
                                          const float* __restrict__ wlin,
                                          const float* __restrict__ bl,
                                          float* __restrict__ out){
  int idx=blockIdx.x*64+threadIdx.x;
  if(idx>=320) return;
  int b=idx/10, c=idx%10;
  float s=bl[c];
  for(int f=0;f<40;f++) s += g[b*40+f]*wlin[c*40+f];
  out[b*10+c]=s;
}

extern "C" void kernel_launch(void* const* d_in, const int* in_sizes, int n_in,
                              void* d_out, int out_size, void* d_ws, size_t ws_size,
                              hipStream_t stream){
  (void)in_sizes; (void)n_in; (void)out_size;
  const float* x    = (const float*)d_in[0];
  const float* w1   = (const float*)d_in[1];
  const float* b1   = (const float*)d_in[2];
  const float* w2   = (const float*)d_in[3];
  const float* b2   = (const float*)d_in[4];
  const float* wlin = (const float*)d_in[5];
  const float* bl   = (const float*)d_in[6];
  float* out = (float*)d_out;
  char*  ws  = (char*)d_ws;

  if(ws_size < WS_NEED){
    fprintf(stderr, "kernel_launch: ws too small: have %zu need %lu\n", ws_size, WS_NEED);
  }

  float* C = (float*)(ws + WOFF_CONST);
  const float*  D1F = C + OFF_D1F;
  const float*  D1I = C + OFF_D1I;
  const float2* Y1  = (const float2*)(C + OFF_Y1);
  const float*  D2F = C + OFF_D2F;
  const float*  D2I = C + OFF_D2I;
  const float*  WI  = C + OFF_WI;
  const float2* E1  = (const float2*)(C + OFF_E1);
  const float2* I1  = (const float2*)(C + OFF_I1);
  const float2* E2  = (const float2*)(C + OFF_E2);
  const float2* I2  = (const float2*)(C + OFF_I2);

  float2* xf1   = (float2*)(ws + WOFF_XF1);
  float2* X1    = (float2*)(ws + WOFF_X1);
  float2* psi1c = (float2*)(ws + WOFF_PSI1);
  unsigned short* h1   = (unsigned short*)(ws + WOFF_H1);
  unsigned short* Y2bf = (unsigned short*)(ws + WOFF_Y2BF);
  unsigned short* w2bf = (unsigned short*)(ws + WOFF_W2BF);
  float*  Cpsi  = (float*)(ws + WOFF_CPSI);
  unsigned short* Aaug = (unsigned short*)(ws + WOFF_AAUG);
  unsigned short* Bt   = (unsigned short*)(ws + WOFF_BT);
  float*  Zf    = (float*)(ws + WOFF_Z);
  unsigned short* h2 = (unsigned short*)(ws + WOFF_H2);
  float*  g     = (float*)(ws + WOFF_G);

  hipLaunchKernelGGL(kconst0, dim3(16), dim3(256), 0, stream, C);
  hipLaunchKernelGGL(kconst, dim3(2048), dim3(256), 0, stream, C, (unsigned int*)Y2bf);
  hipLaunchKernelGGL(kfill, dim3(2048), dim3(256), 0, stream,
                     (uint4*)(ws + WOFF_AAUG), (long)(33423360ul/16ul));
  hipLaunchKernelGGL(kw2, dim3((896*96+255)/256), dim3(256), 0, stream, w2, (unsigned int*)w2bf);

  hipLaunchKernelGGL(k1a, dim3((32*60*29+255)/256), dim3(256), 0, stream, x, E1, xf1);
  hipLaunchKernelGGL(k1b, dim3((32*15*29+255)/256), dim3(256), 0, stream, xf1, D1F, X1);
  hipLaunchKernelGGL(kpsi1, dim3((15*29*20+255)/256), dim3(256), 0, stream, w1, Y1, psi1c);
  hipLaunchKernelGGL(k2, dim3(20,32), dim3(512), 0, stream, X1, psi1c, D1I, I1, b1, h1);
  hipLaunchKernelGGL(k4, dim3(20,32), dim3(384), 0, stream, h1, D2F, E2, Aaug);
  hipLaunchKernelGGL(k3g, dim3(6,7,10), dim3(256), 0, stream, w2bf, Y2bf, Cpsi);
  hipLaunchKernelGGL(kBt, dim3(760,10), dim3(384), 0, stream, Cpsi, Bt);
  hipLaunchKernelGGL(k5, dim3(12,5,10), dim3(256), 0, stream, Aaug, Bt, Zf);
  hipLaunchKernelGGL(k6, dim3(40,32), dim3(256), 0, stream, (const float2*)Zf, D2I, I2, b2, h2);
  hipLaunchKernelGGL(k7a, dim3(1280), dim3(256), 0, stream, (const unsigned int*)h2, WI, g);
  hipLaunchKernelGGL(k7b, dim3(5), dim3(64), 0, stream, g, wlin, bl, out);
}

// Round 6
// 535.848 us; speedup vs baseline: 2.8112x; 1.2163x over previous
//
#include <hip/hip_runtime.h>
#include <cmath>
#include <cstdio>

#ifndef M_PI
#define M_PI 3.14159265358979323846
#endif

// ---------------- constant table offsets (in floats) ----------------
#define OFF_D1F 0        // [15][60][29]
#define OFF_D1I 26100    // [15][30][29][29]
#define OFF_Y1  404550   // [15][29][24] complex
#define OFF_D2F 425430   // [10][30][19][19]
#define OFF_D2I 533730   // [10][20][19][19]
#define OFF_WI  605930   // [20]
#define OFF_E1  605950   // [29][60] complex
#define OFF_I1  609430   // [30][29] complex
#define OFF_E2  611170   // [19][30] complex
#define OFF_I2  612310   // [20][19] complex
#define OFF_DHW30 613070 // [60]
#define OFF_DHW15 613130 // [30]
#define NCONST  613160

// ---------------- workspace byte offsets ----------------
#define WOFF_CONST 0ul
#define WOFF_Y2BF  2457600ul                 // bf16 [10][768][192] = 2,949,120
#define WOFF_W2BF  5406720ul                 // bf16 [896][192]     =   344,064
#define WOFF_AAUG  5750784ul                 // bf16 [10][640][768] = 9,830,400
#define WOFF_BT    15581184ul                // bf16 [10][1536][768]= 23,592,960
#define WOFF_H1    39174144ul                // bf16 [32][20][27000]= 34,560,000
#define WOFF_CPSI  39174144ul                // f32 [10][896][768]  = 27,525,120 (h1 dead)
#define WOFF_Z     39174144ul                // f32 [10][608][1520] = 36,966,400 (Cpsi dead)
#define WOFF_H2    2457600ul                 // bf16 [32][40][8000] = 20,480,000
#define WOFF_XF1   76140544ul
#define WOFF_X1    (76140544ul + 445440ul)
#define WOFF_PSI1  (76140544ul + 445440ul + 111360ul)
#define WOFF_G     (76140544ul + 445440ul + 111360ul + 69600ul)
#define WS_NEED    (WOFF_G + 5120ul)

typedef __attribute__((ext_vector_type(8))) short short8v;
typedef __attribute__((ext_vector_type(4))) float f32x4;

__device__ inline unsigned short f2bf(float x){
  unsigned int u = __float_as_uint(x);
  u += 0x7FFFu + ((u >> 16) & 1u);
  return (unsigned short)(u >> 16);
}
__device__ inline float bf2f(unsigned short u){
  return __uint_as_float(((unsigned int)u) << 16);
}

// ================= device helpers for constant generation =================
__device__ inline double dfact(int n){ double r=1.0; for(int i=2;i<=n;i++) r*=(double)i; return r; }
__device__ inline double dpowi(double x,int e){ double r=1.0; for(int i=0;i<e;i++) r*=x; return r; }
__device__ double wig(int l,int m,int n,double beta){
  if(m < -l || m > l || n < -l || n > l) return 0.0;
  double cb=cos(0.5*beta), sb=sin(0.5*beta);
  double pref=sqrt(dfact(l+m)*dfact(l-m)*dfact(l+n)*dfact(l-n));
  int k0 = (m-n)>0 ? (m-n) : 0;
  int k1 = (l+m) < (l-n) ? (l+m) : (l-n);
  double c0 = ((k0&1)?-1.0:1.0)/(dfact(k0)*dfact(l+m-k0)*dfact(l-n-k0)*dfact(n-m+k0));
  double t = c0 * dpowi(cb, 2*l+m-n-2*k0) * dpowi(sb, n-m+2*k0);
  double ratio = (sb*sb)/(cb*cb);
  double s = t;
  for(int k=k0;k<k1;k++){
    t *= -((double)(l+m-k)*(double)(l-n-k)) / ((double)(k+1)*(double)(n-m+k+1)) * ratio;
    s += t;
  }
  return pref*s;
}
__device__ inline double dh_w(int b,int j){
  double s=0.0;
  for(int k=0;k<b;k++) s += sin((2.0*j+1.0)*(2.0*k+1.0)*M_PI/(4.0*b))/(2.0*k+1.0);
  return (2.0/b)*sin(M_PI*(2.0*j+1.0)/(4.0*b))*s;
}
__device__ inline double soft_beta(int b,int j){ return M_PI*(2.0*j+1.0)/(4.0*b); }
__device__ inline void octcs(int q, double* c, double* s){
  const double r = 0.70710678118654752440;
  int i = q & 7;
  const double C[8]={1.0,r,0.0,-r,-1.0,-r,0.0,r};
  const double S[8]={0.0,r,1.0,r,0.0,-r,-1.0,-r};
  *c=C[i]; *s=S[i];
}

// small tables: quadrature weights + DFT twiddles
__global__ __launch_bounds__(256) void kconst0(float* __restrict__ C){
  for(int idx = blockIdx.x*256 + threadIdx.x; idx < 3670; idx += gridDim.x*256){
    if(idx < 20){ C[OFF_WI+idx]=(float)dh_w(10,idx); }
    else if(idx < 80){ int j=idx-20; C[OFF_DHW30+j]=(float)dh_w(30,j); }
    else if(idx < 110){ int j=idx-80; C[OFF_DHW15+j]=(float)dh_w(15,j); }
    else if(idx < 1850){ int q=idx-110; // E1 [29][60]
      int a=q%60; int m=q/60; double ph=-2.0*M_PI*(double)(m-14)*a/60.0;
      C[OFF_E1+2*q]=(float)cos(ph); C[OFF_E1+2*q+1]=(float)sin(ph);
    } else if(idx < 2720){ int q=idx-1850; // I1 [30][29]
      int m=q%29; int p=q/29; double ph=2.0*M_PI*(double)p*(double)(m-14)/30.0;
      C[OFF_I1+2*q]=(float)cos(ph); C[OFF_I1+2*q+1]=(float)sin(ph);
    } else if(idx < 3290){ int q=idx-2720; // E2 [19][30]
      int a=q%30; int m=q/30; double ph=-2.0*M_PI*(double)(m-9)*a/30.0;
      C[OFF_E2+2*q]=(float)cos(ph); C[OFF_E2+2*q+1]=(float)sin(ph);
    } else { int q=idx-3290; // I2 [20][19]
      int m=q%19; int p=q/19; double ph=2.0*M_PI*(double)p*(double)(m-9)/20.0;
      C[OFF_I2+2*q]=(float)cos(ph); C[OFF_I2+2*q+1]=(float)sin(ph);
    }
  }
}

// big tables (reads DHW tables written by kconst0)
__global__ __launch_bounds__(256) void kconst(float* __restrict__ C,
                                              unsigned int* __restrict__ Y2p){
  for(long idx = (long)blockIdx.x*blockDim.x + threadIdx.x; idx < 1332770L;
      idx += (long)gridDim.x*blockDim.x){
    if(idx < 26100L){                       // D1F [15][60][29]
      int m=(int)(idx%29); int j=(int)((idx/29)%60); int l=(int)(idx/(29*60));
      C[OFF_D1F+idx] = (float)( wig(l, m-14, 0, soft_beta(30,j)) * (double)C[OFF_DHW30+j] );
    } else if(idx < 404550L){ long q=idx-26100L;   // D1I [15][30][29][29]
      int n=(int)(q%29); int m=(int)((q/29)%29); int j=(int)((q/841)%30); int l=(int)(q/(841*30));
      C[OFF_D1I+q] = (float)wig(l, m-14, n-14, soft_beta(15,j));
    } else if(idx < 414990L){ long q=idx-404550L;  // Y1 [15][29][24] complex
      int g=(int)(q%24); int m=(int)((q/24)%29); int l=(int)(q/(24*29));
      double gb=((g>>3)+1)*(M_PI/8.0)/3.0;
      int ka = g&7;
      double mag=(2*l+1)*wig(l, m-14, 0, gb);
      double cc,ss; octcs((m-14)*ka, &cc, &ss);
      C[OFF_Y1+2*q]  =(float)(mag*cc);
      C[OFF_Y1+2*q+1]=(float)(-mag*ss);
    } else if(idx < 523290L){ long q=idx-414990L;  // D2F [10][30][19][19]
      int n=(int)(q%19); int m=(int)((q/19)%19); int j=(int)((q/361)%30); int l=(int)(q/(361*30));
      C[OFF_D2F+q]=(float)( wig(l,m-9,n-9,soft_beta(15,j)) * (double)C[OFF_DHW15+j] );
    } else if(idx < 595490L){ long q=idx-523290L;  // D2I [10][20][19][19]
      int n=(int)(q%19); int m=(int)((q/19)%19); int j=(int)((q/361)%20); int l=(int)(q/(361*20));
      C[OFF_D2I+q]=(float)wig(l,m-9,n-9,soft_beta(10,j));
    } else { long q=idx-595490L;                   // Y2bf pairs [10][768][96]
      int g2=(int)(q%96); int row=(int)((q/96)%768); int l=(int)(q/(96*768));
      unsigned int outv=0u;
      if(row<722){
        int kn=row>>1, ri=row&1, kk=kn/19, n=kn%19;
        int g0=2*g2;
        double gb=((g0>>6)+1)*(M_PI/8.0)/3.0;
        double mag=(2*l+1)*wig(l,kk-9,n-9,gb);
        int ka=(g0>>3)&7;
        double c0,s0,c1,s1;
        octcs((kk-9)*ka + (n-9)*(g0&7), &c0,&s0);
        octcs((kk-9)*ka + (n-9)*((g0+1)&7), &c1,&s1);
        float v0 = ri ? (float)(-mag*s0) : (float)(mag*c0);
        float v1 = ri ? (float)(-mag*s1) : (float)(mag*c1);
        outv = (unsigned int)f2bf(v0) | (((unsigned int)f2bf(v1))<<16);
      }
      Y2p[q]=outv;
    }
  }
}

// zero A_aug + B_augT (contiguous region)
__global__ __launch_bounds__(256) void kfill(uint4* __restrict__ p, long n16){
  uint4 z; z.x=0u; z.y=0u; z.z=0u; z.w=0u;
  for(long i=(long)blockIdx.x*256+threadIdx.x; i<n16; i+=(long)gridDim.x*256) p[i]=z;
}

// pack w2 -> bf16 [896][192] (rows >=800 zero), u32-paired
__global__ __launch_bounds__(256) void kw2(const float* __restrict__ w2,
                                           unsigned int* __restrict__ w2bf){
  int idx = blockIdx.x*256 + threadIdx.x;
  if(idx >= 896*96) return;
  int row=idx/96, g2=idx%96;
  float a=0.f, b=0.f;
  if(row<800){ a=w2[row*192+2*g2]; b=w2[row*192+2*g2+1]; }
  w2bf[idx] = (unsigned int)f2bf(a) | (((unsigned int)f2bf(b))<<16);
}

// ================= forward-pass kernels =================

__global__ __launch_bounds__(256) void k1a(const float* __restrict__ x,
                                           const float2* __restrict__ E1,
                                           float2* __restrict__ xf1){
  int idx = blockIdx.x*256 + threadIdx.x;
  if(idx >= 32*60*29) return;
  int m = idx % 29; int bj = idx / 29;
  const float* row = x + bj*60;
  float sr=0.f, si=0.f;
  for(int a=0;a<60;a++){ float2 e=E1[m*60+a]; float v=row[a]; sr+=v*e.x; si+=v*e.y; }
  xf1[idx] = make_float2(sr,si);
}

__global__ __launch_bounds__(256) void k1b(const float2* __restrict__ xf1,
                                           const float* __restrict__ D1F,
                                           float2* __restrict__ X1){
  int idx = blockIdx.x*256 + threadIdx.x;
  if(idx >= 32*15*29) return;
  int m = idx % 29; int lb = idx / 29; int l = lb % 15; int b = lb / 15;
  float sr=0.f, si=0.f;
  for(int j=0;j<60;j++){
    float d = D1F[(l*60+j)*29+m]; float2 v = xf1[(b*60+j)*29+m];
    sr += d*v.x; si += d*v.y;
  }
  X1[(b*15+l)*29+m] = make_float2(sr,si);
}

// psi1cO[o][l*29+n] = conj( sum_g w1[0,o,g] * Y1[l,n,g] )
__global__ __launch_bounds__(256) void kpsi1(const float* __restrict__ w1,
                                             const float2* __restrict__ Y1,
                                             float2* __restrict__ psi1cO){
  int idx = blockIdx.x*256 + threadIdx.x;
  if(idx >= 15*29*20) return;
  int o = idx % 20; int ln = idx / 20;
  float sr=0.f, si=0.f;
  for(int g=0;g<24;g++){ float w=w1[o*24+g]; float2 y=Y1[ln*24+g]; sr+=w*y.x; si+=w*y.y; }
  psi1cO[o*435 + ln] = make_float2(sr,-si);
}

// conv1 fused, MFMA for both inverse DFTs (An/Tl fully zero-initialized).
__global__ __launch_bounds__(512) void k2(const float2* __restrict__ X1,
                                          const float2* __restrict__ psi1cO,
                                          const float* __restrict__ D1I,
                                          const float2* __restrict__ I1g,
                                          const float* __restrict__ b1,
                                          unsigned short* __restrict__ h1){
  int o=blockIdx.x, b=blockIdx.y;
  __shared__ float2 sX[15][29];
  __shared__ float2 sP[15][29];
  __shared__ __align__(16) unsigned short I1A[64][72];
  __shared__ __align__(16) unsigned short I1C[32][72];
  __shared__ __align__(16) unsigned short An[32][72];
  __shared__ __align__(16) unsigned short Tl[32][72];
  int t=threadIdx.x;
  for(int q=t;q<435;q+=512){ ((float2*)sX)[q]=X1[b*435+q]; ((float2*)sP)[q]=psi1cO[o*435+q]; }
  for(int q=t;q<64*72;q+=512){
    int R=q/72, k=q%72; float v=0.f;
    if(k<64){ int kk=k&31, kh=k>>5;
      if(kk<29){
        if(R<30){ float2 e=I1g[R*29+kk]; v = kh ? -e.y : e.x; }
        else if(R>=32 && R<62){ float2 e=I1g[(R-32)*29+kk]; v = kh ? e.x : e.y; }
      }
    }
    I1A[R][k]=f2bf(v);
  }
  for(int q=t;q<32*72;q+=512){
    int Qr=q/72, k=q%72; float v=0.f;
    if(Qr<30 && k<64){ int kk=k&31, kh=k>>5;
      if(kk<29){ float2 e=I1g[Qr*29+kk]; v = kh ? -e.y : e.x; }
    }
    I1C[Qr][k]=f2bf(v);
  }
  for(int q=t;q<32*72;q+=512){ An[q/72][q%72]=0; Tl[q/72][q%72]=0; }
  __syncthreads();
  float Pr[2][15], Pi[2][15];
  #pragma unroll
  for(int s=0;s<2;s++){
    int id=t+512*s;
    if(id<841){
      int m=id/29, n=id%29;
      #pragma unroll
      for(int l=0;l<15;l++){
        float2 xx=sX[l][m], pp=sP[l][n];
        Pr[s][l]=xx.x*pp.x-xx.y*pp.y;
        Pi[s][l]=xx.x*pp.y+xx.y*pp.x;
      }
    }
  }
  int wid=t>>6, lane=t&63;
  int fr=lane&15, ko=(lane>>4)*8;
  int mwB=wid>>1, nwB=wid&1;
  short8v aB0 = *(const short8v*)&I1A[16*mwB+fr][ko];
  short8v aB1 = *(const short8v*)&I1A[16*mwB+fr][32+ko];
  int mwC=(wid>>1)&1, nwC=wid&1;
  short8v bC0 = *(const short8v*)&I1C[16*nwC+fr][ko];
  short8v bC1 = *(const short8v*)&I1C[16*nwC+fr][32+ko];
  float bias=b1[o];
  for(int j=0;j<30;j++){
    #pragma unroll
    for(int s=0;s<2;s++){
      int id=t+512*s;
      if(id<841){
        const float* dp = D1I + j*841 + id;
        float ar=0.f, ai=0.f;
        #pragma unroll
        for(int l=0;l<15;l++){ float d=dp[l*25230]; ar+=Pr[s][l]*d; ai+=Pi[s][l]*d; }
        int m=id/29, n=id%29;
        An[n][m]   =f2bf(ar);
        An[n][32+m]=f2bf(ai);
      }
    }
    __syncthreads();
    f32x4 accB={0.f,0.f,0.f,0.f};
    short8v b0 = *(const short8v*)&An[16*nwB+fr][ko];
    short8v b1v= *(const short8v*)&An[16*nwB+fr][32+ko];
    accB=__builtin_amdgcn_mfma_f32_16x16x32_bf16(aB0,b0,accB,0,0,0);
    accB=__builtin_amdgcn_mfma_f32_16x16x32_bf16(aB1,b1v,accB,0,0,0);
    #pragma unroll
    for(int r=0;r<4;r++){
      int R=16*mwB+(lane>>4)*4+r;
      int cc=16*nwB+fr;
      Tl[R&31][(R>>5)*32+cc]=f2bf(accB[r]);
    }
    __syncthreads();
    if(wid<4){
      f32x4 accC={0.f,0.f,0.f,0.f};
      short8v a0 = *(const short8v*)&Tl[16*mwC+fr][ko];
      short8v a1 = *(const short8v*)&Tl[16*mwC+fr][32+ko];
      accC=__builtin_amdgcn_mfma_f32_16x16x32_bf16(a0,bC0,accC,0,0,0);
      accC=__builtin_amdgcn_mfma_f32_16x16x32_bf16(a1,bC1,accC,0,0,0);
      size_t base=((size_t)(b*20+o)*30+j)*900;
      #pragma unroll
      for(int r=0;r<4;r++){
        int p=16*mwC+(lane>>4)*4+r, qq=16*nwC+fr;
        if(p<30 && qq<30){
          float v=fmaxf(accC[r]+bias,0.f);
          h1[base+p*30+qq]=f2bf(v);
        }
      }
    }
  }
}

// psi2 GEMM: Cpsi[l](896x768 f32) = w2bf(896x192) x Y2bf[l]^T(192x768)
__global__ __launch_bounds__(256) void k3g(const unsigned short* __restrict__ A,
                                           const unsigned short* __restrict__ B,
                                           float* __restrict__ Cf){
  int l = blockIdx.z;
  int m0 = blockIdx.y*128, n0 = blockIdx.x*128;
  __shared__ unsigned short As[128][40];
  __shared__ unsigned short Bs[128][40];
  int t = threadIdx.x;
  int wid = t>>6, lane = t&63;
  int wr = wid>>1, wc = wid&1;
  f32x4 acc[4][4];
  #pragma unroll
  for(int a=0;a<4;a++)
    #pragma unroll
    for(int c=0;c<4;c++) acc[a][c]=(f32x4){0.f,0.f,0.f,0.f};
  const unsigned short* Ag = A;
  const unsigned short* Bg = B + (size_t)l*768*192;
  int row_a = wr*64 + (lane&15);
  int row_b = wc*64 + (lane&15);
  int ko = (lane>>4)*8;
  for(int kt=0; kt<192; kt+=32){
    #pragma unroll
    for(int it=0; it<2; it++){
      int q = t + 256*it;
      int r = q>>2, c8 = (q&3)*8;
      *(uint4*)&As[r][c8] = *(const uint4*)&Ag[(size_t)(m0+r)*192 + kt + c8];
      *(uint4*)&Bs[r][c8] = *(const uint4*)&Bg[(size_t)(n0+r)*192 + kt + c8];
    }
    __syncthreads();
    short8v af[4], bfv[4];
    #pragma unroll
    for(int f=0; f<4; f++){
      af[f]  = *(const short8v*)&As[row_a + f*16][ko];
      bfv[f] = *(const short8v*)&Bs[row_b + f*16][ko];
    }
    #pragma unroll
    for(int fm=0;fm<4;fm++)
      #pragma unroll
      for(int fn=0;fn<4;fn++)
        acc[fm][fn] = __builtin_amdgcn_mfma_f32_16x16x32_bf16(af[fm], bfv[fn], acc[fm][fn], 0,0,0);
    __syncthreads();
  }
  #pragma unroll
  for(int fm=0;fm<4;fm++){
    int mb = m0 + wr*64 + fm*16 + ((lane>>4)*4);
    #pragma unroll
    for(int fn=0;fn<4;fn++){
      int n = n0 + wc*64 + fn*16 + (lane&15);
      #pragma unroll
      for(int r=0;r<4;r++){
        Cf[((size_t)(l*896)+mb+r)*768 + n] = acc[fm][fn][r];
      }
    }
  }
}

// Cpsi -> B_augT bf16 (coalesced both sides)
__global__ __launch_bounds__(384) void kBt(const float* __restrict__ Cf,
                                           unsigned short* __restrict__ Bt){
  int c = blockIdx.x;      // o*19+kk
  int l = blockIdx.y;
  int t = threadIdx.x;
  if(t>=380) return;
  int i=t/19, n=t%19;
  int o=c/19, kk=c%19;
  float2 v = *(const float2*)&Cf[((size_t)(l*896) + i*40+o)*768 + (kk*19+n)*2];
  float zr = v.x, zi = -v.y;
  unsigned short* base = Bt + (size_t)l*1536*768;
  size_t r0=(size_t)(2*c)*768, r1=r0+768;
  int col=i*19+n;
  base[r0+col]     = f2bf(zr);
  base[r0+384+col] = f2bf(-zi);
  base[r1+col]     = f2bf(zi);
  base[r1+384+col] = f2bf(zr);
}

// per (b,i): fft2(30x30 -> 19x19) * D2F summed over j -> A_aug bf16
__global__ __launch_bounds__(384) void k4(const unsigned short* __restrict__ h1,
                                          const float* __restrict__ D2F,
                                          const float2* __restrict__ E2g,
                                          unsigned short* __restrict__ Aaug){
  int i=blockIdx.x, b=blockIdx.y;
  __shared__ float  tile[30][31];
  __shared__ float2 t1[30][19];
  __shared__ float2 sE2[19][30];
  int t=threadIdx.x;
  for(int q=t;q<570;q+=384) ((float2*)sE2)[q]=E2g[q];
  float accr[10], acci[10];
  #pragma unroll
  for(int l=0;l<10;l++){ accr[l]=0.f; acci[l]=0.f; }
  int m=t/19, n=t%19;
  __syncthreads();
  for(int j=0;j<30;j++){
    const uint2* src=(const uint2*)(h1 + ((size_t)(b*20+i)*30+j)*900);
    if(t<225){
      uint2 v=src[t];
      int base4=t*4;
      float f0=bf2f((unsigned short)(v.x&0xFFFF)), f1=bf2f((unsigned short)(v.x>>16));
      float f2v=bf2f((unsigned short)(v.y&0xFFFF)), f3=bf2f((unsigned short)(v.y>>16));
      tile[(base4)/30][(base4)%30]=f0;
      tile[(base4+1)/30][(base4+1)%30]=f1;
      tile[(base4+2)/30][(base4+2)%30]=f2v;
      tile[(base4+3)/30][(base4+3)%30]=f3;
    }
    __syncthreads();
    for(int q=t;q<570;q+=384){
      int a=q/19, nn=q%19; float sr=0.f, si=0.f;
      #pragma unroll
      for(int g=0;g<30;g++){ float vv=tile[a][g]; float2 e=sE2[nn][g]; sr+=vv*e.x; si+=vv*e.y; }
      t1[a][nn]=make_float2(sr,si);
    }
    __syncthreads();
    if(t<361){
      float xr=0.f, xi=0.f;
      #pragma unroll
      for(int a=0;a<30;a++){
        float2 e=sE2[m][a], v2=t1[a][n];
        xr += e.x*v2.x - e.y*v2.y;
        xi += e.x*v2.y + e.y*v2.x;
      }
      const float* dp = D2F + j*361 + t;
      #pragma unroll
      for(int l=0;l<10;l++){ float d=dp[l*10830]; accr[l]+=d*xr; acci[l]+=d*xi; }
    }
  }
  if(t<361){
    #pragma unroll
    for(int l=0;l<10;l++){
      size_t row=((size_t)(l*640) + b*19+m)*768;
      Aaug[row + i*19+n]       = f2bf(accr[l]);
      Aaug[row + 384 + i*19+n] = f2bf(acci[l]);
    }
  }
}

// bf16 MFMA GEMM per l: Z[l](608x1520 f32) = A_aug[l](640x768) x B_augT[l]^T
__global__ __launch_bounds__(256) void k5(const unsigned short* __restrict__ A,
                                          const unsigned short* __restrict__ B,
                                          float* __restrict__ Cf){
  int l = blockIdx.z;
  int m0 = blockIdx.y*128, n0 = blockIdx.x*128;
  __shared__ unsigned short As[128][40];
  __shared__ unsigned short Bs[128][40];
  int t = threadIdx.x;
  int wid = t>>6, lane = t&63;
  int wr = wid>>1, wc = wid&1;
  f32x4 acc[4][4];
  #pragma unroll
  for(int a=0;a<4;a++)
    #pragma unroll
    for(int c=0;c<4;c++) acc[a][c]=(f32x4){0.f,0.f,0.f,0.f};
  const unsigned short* Ag = A + (size_t)l*640*768;
  const unsigned short* Bg = B + (size_t)l*1536*768;
  int row_a = wr*64 + (lane&15);
  int row_b = wc*64 + (lane&15);
  int ko = (lane>>4)*8;
  for(int kt=0; kt<768; kt+=32){
    #pragma unroll
    for(int it=0; it<2; it++){
      int q = t + 256*it;
      int r = q>>2, c8 = (q&3)*8;
      *(uint4*)&As[r][c8] = *(const uint4*)&Ag[(size_t)(m0+r)*768 + kt + c8];
      *(uint4*)&Bs[r][c8] = *(const uint4*)&Bg[(size_t)(n0+r)*768 + kt + c8];
    }
    __syncthreads();
    short8v af[4], bfv[4];
    #pragma unroll
    for(int f=0; f<4; f++){
      af[f]  = *(const short8v*)&As[row_a + f*16][ko];
      bfv[f] = *(const short8v*)&Bs[row_b + f*16][ko];
    }
    #pragma unroll
    for(int fm=0;fm<4;fm++)
      #pragma unroll
      for(int fn=0;fn<4;fn++)
        acc[fm][fn] = __builtin_amdgcn_mfma_f32_16x16x32_bf16(af[fm], bfv[fn], acc[fm][fn], 0,0,0);
    __syncthreads();
  }
  #pragma unroll
  for(int fm=0;fm<4;fm++){
    int mb = m0 + wr*64 + fm*16 + ((lane>>4)*4);
    #pragma unroll
    for(int fn=0;fn<4;fn++){
      int n = n0 + wc*64 + fn*16 + (lane&15);
      if(n<1520){
        #pragma unroll
        for(int r=0;r<4;r++){
          int m = mb + r;
          if(m<608) Cf[((size_t)(l*608)+m)*1520 + n] = acc[fm][fn][r];
        }
      }
    }
  }
}

// conv2 inverse, MFMA batched over j (no j-loop):
// stage1 VALU: A[(j,k)][m_aug] = sum_l Z*D2I  -> An bf16 (B-operand)
// GEMM1: T(40aug x 380) = I2A(40x38aug) @ A_stack    [72 tiles]
// GEMM2: Y(400 x 20) = Tflat(400x38aug) @ I2C^T      [52 tiles]
// An/Tl overlay one zero-initialized LDS union (NaN-safety per R4 lesson).
__global__ __launch_bounds__(512) void k6(const float2* __restrict__ Z,
                                          const float* __restrict__ D2I,
                                          const float2* __restrict__ I2g,
                                          const float* __restrict__ b2,
                                          unsigned short* __restrict__ h2){
  int o=blockIdx.x, b=blockIdx.y;
  __shared__ __align__(16) unsigned short U[29952];   // An[384][72] / Tl[416][72]
  __shared__ __align__(16) unsigned short I2A[48][72];
  __shared__ __align__(16) unsigned short I2C[32][72];
  int t=threadIdx.x;
  for(int q=t;q<14976;q+=512) ((unsigned int*)U)[q]=0u;
  for(int q=t;q<48*72;q+=512){
    int R=q/72, kd=q%72; float v=0.f;
    if(kd<38){
      int mm = (kd<19)? kd : kd-19; int hi = (kd>=19);
      if(R<20){ float2 e=I2g[R*19+mm]; v = hi ? -e.y : e.x; }
      else if(R<40){ float2 e=I2g[(R-20)*19+mm]; v = hi ? e.x : e.y; }
    }
    I2A[R][kd]=f2bf(v);
  }
  for(int q=t;q<32*72;q+=512){
    int Qr=q/72, kd=q%72; float v=0.f;
    if(Qr<20 && kd<38){
      int kk2 = (kd<19)? kd : kd-19; int hi = (kd>=19);
      float2 e=I2g[Qr*19+kk2]; v = hi ? -e.y : e.x;
    }
    I2C[Qr][kd]=f2bf(v);
  }
  float zr[10], zi[10];
  int m=t/19, kk=t%19;   // valid t<361
  if(t<361){
    #pragma unroll
    for(int l=0;l<10;l++){
      float2 z=Z[(size_t)(l*608 + b*19+m)*760 + o*19+kk];
      zr[l]=z.x; zi[l]=z.y;
    }
  }
  __syncthreads();
  if(t<361){
    for(int j=0;j<20;j++){
      float ar=0.f, ai=0.f;
      const float* dp = D2I + j*361 + t;
      #pragma unroll
      for(int l=0;l<10;l++){ float d=dp[l*7220]; ar+=zr[l]*d; ai+=zi[l]*d; }
      U[(j*19+kk)*72 + m]      = f2bf(ar);
      U[(j*19+kk)*72 + 19 + m] = f2bf(ai);
    }
  }
  __syncthreads();
  int wid=t>>6, lane=t&63, fr=lane&15, ko=(lane>>4)*8;
  f32x4 acc1[9];
  #pragma unroll
  for(int u=0;u<9;u++){
    int tile=wid+8*u;           // 0..71
    int mt=tile/24, nt=tile%24;
    short8v a0=*(const short8v*)&I2A[16*mt+fr][ko];
    short8v a1=*(const short8v*)&I2A[16*mt+fr][32+ko];
    short8v bb0=*(const short8v*)&U[(16*nt+fr)*72+ko];
    short8v bb1=*(const short8v*)&U[(16*nt+fr)*72+32+ko];
    f32x4 ac={0.f,0.f,0.f,0.f};
    ac=__builtin_amdgcn_mfma_f32_16x16x32_bf16(a0,bb0,ac,0,0,0);
    ac=__builtin_amdgcn_mfma_f32_16x16x32_bf16(a1,bb1,ac,0,0,0);
    acc1[u]=ac;
  }
  __syncthreads();   // all An reads done before Tl overlay writes
  #pragma unroll
  for(int u=0;u<9;u++){
    int tile=wid+8*u; int mt=tile/24, nt=tile%24;
    #pragma unroll
    for(int r=0;r<4;r++){
      int R=16*mt+(lane>>4)*4+r;
      int n=16*nt+fr;
      if(R<40 && n<380){
        int j=n/19, kq=n%19;
        U[(j*20 + (R%20))*72 + (R/20)*19 + kq] = f2bf(acc1[u][r]);
      }
    }
  }
  __syncthreads();
  float bias=b2[o];
  size_t obase=((size_t)b*40+o)*8000;
  #pragma unroll
  for(int u=0;u<7;u++){
    int tile=wid+8*u;
    if(tile<52){
      int mt=tile>>1, nt=tile&1;
      short8v a0=*(const short8v*)&U[(16*mt+fr)*72+ko];
      short8v a1=*(const short8v*)&U[(16*mt+fr)*72+32+ko];
      short8v bb0=*(const short8v*)&I2C[16*nt+fr][ko];
      short8v bb1=*(const short8v*)&I2C[16*nt+fr][32+ko];
      f32x4 ac={0.f,0.f,0.f,0.f};
      ac=__builtin_amdgcn_mfma_f32_16x16x32_bf16(a0,bb0,ac,0,0,0);
      ac=__builtin_amdgcn_mfma_f32_16x16x32_bf16(a1,bb1,ac,0,0,0);
      #pragma unroll
      for(int r=0;r<4;r++){
        int row=16*mt+(lane>>4)*4+r;
        int q=16*nt+fr;
        if(row<400 && q<20){
          float v=fmaxf(ac[r]+bias,0.f);
          h2[obase + row*20 + q]=f2bf(v);
        }
      }
    }
  }
}

// g[b,f] = (2pi/20)^2 * sum_{j,p,q} h2 * W_INT[j]   (h2 bf16, paired reads)
__global__ __launch_bounds__(256) void k7a(const unsigned int* __restrict__ h2p,
                                           const float* __restrict__ WI,
                                           float* __restrict__ g){
  int bf=blockIdx.x;
  const unsigned int* base=h2p + (size_t)bf*4000;
  int t=threadIdx.x; float s=0.f;
  for(int q=t;q<4000;q+=256){
    unsigned int v=base[q];
    float w=WI[q/200];
    s += (bf2f((unsigned short)(v&0xFFFF))+bf2f((unsigned short)(v>>16)))*w;
  }
  __shared__ float red[256];
  red[t]=s; __syncthreads();
  for(int off=128;off>0;off>>=1){ if(t<off) red[t]+=red[t+off]; __syncthreads(); }
  if(t==0){
    const float c=(float)((2.0*M_PI/20.0)*(2.0*M_PI/20.0));
    g[bf]=red[0]*c;
  }
}

__global__ __launch_bounds__(64) void k7b(const float* __restrict__ g,
                                          const float* __restrict__ wlin,
                                          const float* __restrict__ bl,
                                          float* __restrict__ out){
  int idx=blockIdx.x*64+threadIdx.x;
  if(idx>=320) return;
  int b=idx/10, c=idx%10;
  float s=bl[c];
  for(int f=0;f<40;f++) s += g[b*40+f]*wlin[c*40+f];
  out[b*10+c]=s;
}

extern "C" void kernel_launch(void* const* d_in, const int* in_sizes, int n_in,
                              void* d_out, int out_size, void* d_ws, size_t ws_size,
                              hipStream_t stream){
  (void)in_sizes; (void)n_in; (void)out_size;
  const float* x    = (const float*)d_in[0];
  const float* w1   = (const float*)d_in[1];
  const float* b1   = (const float*)d_in[2];
  const float* w2   = (const float*)d_in[3];
  const float* b2   = (const float*)d_in[4];
  const float* wlin = (const float*)d_in[5];
  const float* bl   = (const float*)d_in[6];
  float* out = (float*)d_out;
  char*  ws  = (char*)d_ws;

  if(ws_size < WS_NEED){
    fprintf(stderr, "kernel_launch: ws too small: have %zu need %lu\n", ws_size, WS_NEED);
  }

  float* C = (float*)(ws + WOFF_CONST);
  const float*  D1F = C + OFF_D1F;
  const float*  D1I = C + OFF_D1I;
  const float2* Y1  = (const float2*)(C + OFF_Y1);
  const float*  D2F = C + OFF_D2F;
  const float*  D2I = C + OFF_D2I;
  const float*  WI  = C + OFF_WI;
  const float2* E1  = (const float2*)(C + OFF_E1);
  const float2* I1  = (const float2*)(C + OFF_I1);
  const float2* E2  = (const float2*)(C + OFF_E2);
  const float2* I2  = (const float2*)(C + OFF_I2);

  float2* xf1   = (float2*)(ws + WOFF_XF1);
  float2* X1    = (float2*)(ws + WOFF_X1);
  float2* psi1c = (float2*)(ws + WOFF_PSI1);
  unsigned short* h1   = (unsigned short*)(ws + WOFF_H1);
  unsigned short* Y2bf = (unsigned short*)(ws + WOFF_Y2BF);
  unsigned short* w2bf = (unsigned short*)(ws + WOFF_W2BF);
  float*  Cpsi  = (float*)(ws + WOFF_CPSI);
  unsigned short* Aaug = (unsigned short*)(ws + WOFF_AAUG);
  unsigned short* Bt   = (unsigned short*)(ws + WOFF_BT);
  float*  Zf    = (float*)(ws + WOFF_Z);
  unsigned short* h2 = (unsigned short*)(ws + WOFF_H2);
  float*  g     = (float*)(ws + WOFF_G);

  hipLaunchKernelGGL(kconst0, dim3(16), dim3(256), 0, stream, C);
  hipLaunchKernelGGL(kconst, dim3(2048), dim3(256), 0, stream, C, (unsigned int*)Y2bf);
  hipLaunchKernelGGL(kfill, dim3(2048), dim3(256), 0, stream,
                     (uint4*)(ws + WOFF_AAUG), (long)(33423360ul/16ul));
  hipLaunchKernelGGL(kw2, dim3((896*96+255)/256), dim3(256), 0, stream, w2, (unsigned int*)w2bf);

  hipLaunchKernelGGL(k1a, dim3((32*60*29+255)/256), dim3(256), 0, stream, x, E1, xf1);
  hipLaunchKernelGGL(k1b, dim3((32*15*29+255)/256), dim3(256), 0, stream, xf1, D1F, X1);
  hipLaunchKernelGGL(kpsi1, dim3((15*29*20+255)/256), dim3(256), 0, stream, w1, Y1, psi1c);
  hipLaunchKernelGGL(k2, dim3(20,32), dim3(512), 0, stream, X1, psi1c, D1I, I1, b1, h1);
  hipLaunchKernelGGL(k4, dim3(20,32), dim3(384), 0, stream, h1, D2F, E2, Aaug);
  hipLaunchKernelGGL(k3g, dim3(6,7,10), dim3(256), 0, stream, w2bf, Y2bf, Cpsi);
  hipLaunchKernelGGL(kBt, dim3(760,10), dim3(384), 0, stream, Cpsi, Bt);
  hipLaunchKernelGGL(k5, dim3(12,5,10), dim3(256), 0, stream, Aaug, Bt, Zf);
  hipLaunchKernelGGL(k6, dim3(40,32), dim3(512), 0, stream, (const float2*)Zf, D2I, I2, b2, h2);
  hipLaunchKernelGGL(k7a, dim3(1280), dim3(256), 0, stream, (const unsigned int*)h2, WI, g);
  hipLaunchKernelGGL(k7b, dim3(5), dim3(64), 0, stream, g, wlin, bl, out);
}

// Round 7
// 435.373 us; speedup vs baseline: 3.4599x; 1.2308x over previous
//
#include <hip/hip_runtime.h>
#include <cmath>
#include <cstdio>

#ifndef M_PI
#define M_PI 3.14159265358979323846
#endif

// ---------------- constant table offsets (in floats) ----------------
#define OFF_D1F 0        // [15][60][29]
#define OFF_D1I 26100    // [15][30][29][29]
#define OFF_Y1  404550   // [15][29][24] complex
#define OFF_D2F 425430   // [10][30][19][19]
#define OFF_D2I 533730   // [10][20][19][19]
#define OFF_WI  605930   // [20]
#define OFF_E1  605950   // [29][60] complex
#define OFF_I1  609430   // [30][29] complex
#define OFF_E2  611170   // [19][30] complex
#define OFF_I2  612310   // [20][19] complex
#define OFF_DHW30 613070 // [60]
#define OFF_DHW15 613130 // [30]
#define NCONST  613160

// ---------------- workspace byte offsets ----------------
#define WOFF_CONST 0ul
#define WOFF_Y2BF  2457600ul                 // bf16 [10][768][192] = 2,949,120
#define WOFF_W2BF  5406720ul                 // bf16 [896][192]     =   344,064
#define WOFF_AAUG  5750784ul                 // bf16 [10][640][768] = 9,830,400
#define WOFF_BT    15581184ul                // bf16 [10][1536][768]= 23,592,960
#define WOFF_H1    39174144ul                // bf16 [32][20][27000]= 34,560,000 (+512B zero pad)
#define WOFF_CPSI  39174144ul                // f32 [10][896][768]  = 27,525,120 (h1 dead)
#define WOFF_Z     39174144ul                // f32 [10][608][1520] = 36,966,400 (Cpsi dead)
#define WOFF_H2    2457600ul                 // bf16 [32][40][8000] = 20,480,000
#define WOFF_XF1   76140544ul
#define WOFF_X1    (76140544ul + 445440ul)
#define WOFF_PSI1  (76140544ul + 445440ul + 111360ul)
#define WOFF_G     (76140544ul + 445440ul + 111360ul + 69600ul)
#define WS_NEED    (WOFF_G + 5120ul)

typedef __attribute__((ext_vector_type(8))) short short8v;
typedef __attribute__((ext_vector_type(4))) float f32x4;

__device__ inline unsigned short f2bf(float x){
  unsigned int u = __float_as_uint(x);
  u += 0x7FFFu + ((u >> 16) & 1u);
  return (unsigned short)(u >> 16);
}
__device__ inline float bf2f(unsigned short u){
  return __uint_as_float(((unsigned int)u) << 16);
}

// ================= device helpers for constant generation =================
__device__ inline double dfact(int n){ double r=1.0; for(int i=2;i<=n;i++) r*=(double)i; return r; }
__device__ inline double dpowi(double x,int e){ double r=1.0; for(int i=0;i<e;i++) r*=x; return r; }
__device__ double wig(int l,int m,int n,double beta){
  if(m < -l || m > l || n < -l || n > l) return 0.0;
  double cb=cos(0.5*beta), sb=sin(0.5*beta);
  double pref=sqrt(dfact(l+m)*dfact(l-m)*dfact(l+n)*dfact(l-n));
  int k0 = (m-n)>0 ? (m-n) : 0;
  int k1 = (l+m) < (l-n) ? (l+m) : (l-n);
  double c0 = ((k0&1)?-1.0:1.0)/(dfact(k0)*dfact(l+m-k0)*dfact(l-n-k0)*dfact(n-m+k0));
  double t = c0 * dpowi(cb, 2*l+m-n-2*k0) * dpowi(sb, n-m+2*k0);
  double ratio = (sb*sb)/(cb*cb);
  double s = t;
  for(int k=k0;k<k1;k++){
    t *= -((double)(l+m-k)*(double)(l-n-k)) / ((double)(k+1)*(double)(n-m+k+1)) * ratio;
    s += t;
  }
  return pref*s;
}
__device__ inline double dh_w(int b,int j){
  double s=0.0;
  for(int k=0;k<b;k++) s += sin((2.0*j+1.0)*(2.0*k+1.0)*M_PI/(4.0*b))/(2.0*k+1.0);
  return (2.0/b)*sin(M_PI*(2.0*j+1.0)/(4.0*b))*s;
}
__device__ inline double soft_beta(int b,int j){ return M_PI*(2.0*j+1.0)/(4.0*b); }
__device__ inline void octcs(int q, double* c, double* s){
  const double r = 0.70710678118654752440;
  int i = q & 7;
  const double C[8]={1.0,r,0.0,-r,-1.0,-r,0.0,r};
  const double S[8]={0.0,r,1.0,r,0.0,-r,-1.0,-r};
  *c=C[i]; *s=S[i];
}

// small tables: quadrature weights + DFT twiddles
__global__ __launch_bounds__(256) void kconst0(float* __restrict__ C){
  for(int idx = blockIdx.x*256 + threadIdx.x; idx < 3670; idx += gridDim.x*256){
    if(idx < 20){ C[OFF_WI+idx]=(float)dh_w(10,idx); }
    else if(idx < 80){ int j=idx-20; C[OFF_DHW30+j]=(float)dh_w(30,j); }
    else if(idx < 110){ int j=idx-80; C[OFF_DHW15+j]=(float)dh_w(15,j); }
    else if(idx < 1850){ int q=idx-110; // E1 [29][60]
      int a=q%60; int m=q/60; double ph=-2.0*M_PI*(double)(m-14)*a/60.0;
      C[OFF_E1+2*q]=(float)cos(ph); C[OFF_E1+2*q+1]=(float)sin(ph);
    } else if(idx < 2720){ int q=idx-1850; // I1 [30][29]
      int m=q%29; int p=q/29; double ph=2.0*M_PI*(double)p*(double)(m-14)/30.0;
      C[OFF_I1+2*q]=(float)cos(ph); C[OFF_I1+2*q+1]=(float)sin(ph);
    } else if(idx < 3290){ int q=idx-2720; // E2 [19][30]
      int a=q%30; int m=q/30; double ph=-2.0*M_PI*(double)(m-9)*a/30.0;
      C[OFF_E2+2*q]=(float)cos(ph); C[OFF_E2+2*q+1]=(float)sin(ph);
    } else { int q=idx-3290; // I2 [20][19]
      int m=q%19; int p=q/19; double ph=2.0*M_PI*(double)p*(double)(m-9)/20.0;
      C[OFF_I2+2*q]=(float)cos(ph); C[OFF_I2+2*q+1]=(float)sin(ph);
    }
  }
}

// big tables (reads DHW tables written by kconst0)
__global__ __launch_bounds__(256) void kconst(float* __restrict__ C,
                                              unsigned int* __restrict__ Y2p){
  for(long idx = (long)blockIdx.x*blockDim.x + threadIdx.x; idx < 1332770L;
      idx += (long)gridDim.x*blockDim.x){
    if(idx < 26100L){                       // D1F [15][60][29]
      int m=(int)(idx%29); int j=(int)((idx/29)%60); int l=(int)(idx/(29*60));
      C[OFF_D1F+idx] = (float)( wig(l, m-14, 0, soft_beta(30,j)) * (double)C[OFF_DHW30+j] );
    } else if(idx < 404550L){ long q=idx-26100L;   // D1I [15][30][29][29]
      int n=(int)(q%29); int m=(int)((q/29)%29); int j=(int)((q/841)%30); int l=(int)(q/(841*30));
      C[OFF_D1I+q] = (float)wig(l, m-14, n-14, soft_beta(15,j));
    } else if(idx < 414990L){ long q=idx-404550L;  // Y1 [15][29][24] complex
      int g=(int)(q%24); int m=(int)((q/24)%29); int l=(int)(q/(24*29));
      double gb=((g>>3)+1)*(M_PI/8.0)/3.0;
      int ka = g&7;
      double mag=(2*l+1)*wig(l, m-14, 0, gb);
      double cc,ss; octcs((m-14)*ka, &cc, &ss);
      C[OFF_Y1+2*q]  =(float)(mag*cc);
      C[OFF_Y1+2*q+1]=(float)(-mag*ss);
    } else if(idx < 523290L){ long q=idx-414990L;  // D2F [10][30][19][19]
      int n=(int)(q%19); int m=(int)((q/19)%19); int j=(int)((q/361)%30); int l=(int)(q/(361*30));
      C[OFF_D2F+q]=(float)( wig(l,m-9,n-9,soft_beta(15,j)) * (double)C[OFF_DHW15+j] );
    } else if(idx < 595490L){ long q=idx-523290L;  // D2I [10][20][19][19]
      int n=(int)(q%19); int m=(int)((q/19)%19); int j=(int)((q/361)%20); int l=(int)(q/(361*20));
      C[OFF_D2I+q]=(float)wig(l,m-9,n-9,soft_beta(10,j));
    } else { long q=idx-595490L;                   // Y2bf pairs [10][768][96]
      int g2=(int)(q%96); int row=(int)((q/96)%768); int l=(int)(q/(96*768));
      unsigned int outv=0u;
      if(row<722){
        int kn=row>>1, ri=row&1, kk=kn/19, n=kn%19;
        int g0=2*g2;
        double gb=((g0>>6)+1)*(M_PI/8.0)/3.0;
        double mag=(2*l+1)*wig(l,kk-9,n-9,gb);
        int ka=(g0>>3)&7;
        double c0,s0,c1,s1;
        octcs((kk-9)*ka + (n-9)*(g0&7), &c0,&s0);
        octcs((kk-9)*ka + (n-9)*((g0+1)&7), &c1,&s1);
        float v0 = ri ? (float)(-mag*s0) : (float)(mag*c0);
        float v1 = ri ? (float)(-mag*s1) : (float)(mag*c1);
        outv = (unsigned int)f2bf(v0) | (((unsigned int)f2bf(v1))<<16);
      }
      Y2p[q]=outv;
    }
  }
}

// zero a contiguous region
__global__ __launch_bounds__(256) void kfill(uint4* __restrict__ p, long n16){
  uint4 z; z.x=0u; z.y=0u; z.z=0u; z.w=0u;
  for(long i=(long)blockIdx.x*256+threadIdx.x; i<n16; i+=(long)gridDim.x*256) p[i]=z;
}

// pack w2 -> bf16 [896][192] (rows >=800 zero), u32-paired
__global__ __launch_bounds__(256) void kw2(const float* __restrict__ w2,
                                           unsigned int* __restrict__ w2bf){
  int idx = blockIdx.x*256 + threadIdx.x;
  if(idx >= 896*96) return;
  int row=idx/96, g2=idx%96;
  float a=0.f, b=0.f;
  if(row<800){ a=w2[row*192+2*g2]; b=w2[row*192+2*g2+1]; }
  w2bf[idx] = (unsigned int)f2bf(a) | (((unsigned int)f2bf(b))<<16);
}

// ================= forward-pass kernels =================

__global__ __launch_bounds__(256) void k1a(const float* __restrict__ x,
                                           const float2* __restrict__ E1,
                                           float2* __restrict__ xf1){
  int idx = blockIdx.x*256 + threadIdx.x;
  if(idx >= 32*60*29) return;
  int m = idx % 29; int bj = idx / 29;
  const float* row = x + bj*60;
  float sr=0.f, si=0.f;
  for(int a=0;a<60;a++){ float2 e=E1[m*60+a]; float v=row[a]; sr+=v*e.x; si+=v*e.y; }
  xf1[idx] = make_float2(sr,si);
}

__global__ __launch_bounds__(256) void k1b(const float2* __restrict__ xf1,
                                           const float* __restrict__ D1F,
                                           float2* __restrict__ X1){
  int idx = blockIdx.x*256 + threadIdx.x;
  if(idx >= 32*15*29) return;
  int m = idx % 29; int lb = idx / 29; int l = lb % 15; int b = lb / 15;
  float sr=0.f, si=0.f;
  for(int j=0;j<60;j++){
    float d = D1F[(l*60+j)*29+m]; float2 v = xf1[(b*60+j)*29+m];
    sr += d*v.x; si += d*v.y;
  }
  X1[(b*15+l)*29+m] = make_float2(sr,si);
}

// psi1cO[o][l*29+n] = conj( sum_g w1[0,o,g] * Y1[l,n,g] )
__global__ __launch_bounds__(256) void kpsi1(const float* __restrict__ w1,
                                             const float2* __restrict__ Y1,
                                             float2* __restrict__ psi1cO){
  int idx = blockIdx.x*256 + threadIdx.x;
  if(idx >= 15*29*20) return;
  int o = idx % 20; int ln = idx / 20;
  float sr=0.f, si=0.f;
  for(int g=0;g<24;g++){ float w=w1[o*24+g]; float2 y=Y1[ln*24+g]; sr+=w*y.x; si+=w*y.y; }
  psi1cO[o*435 + ln] = make_float2(sr,-si);
}

// conv1 fused, MFMA for both inverse DFTs (An/Tl fully zero-initialized).
__global__ __launch_bounds__(512) void k2(const float2* __restrict__ X1,
                                          const float2* __restrict__ psi1cO,
                                          const float* __restrict__ D1I,
                                          const float2* __restrict__ I1g,
                                          const float* __restrict__ b1,
                                          unsigned short* __restrict__ h1){
  int o=blockIdx.x, b=blockIdx.y;
  __shared__ float2 sX[15][29];
  __shared__ float2 sP[15][29];
  __shared__ __align__(16) unsigned short I1A[64][72];
  __shared__ __align__(16) unsigned short I1C[32][72];
  __shared__ __align__(16) unsigned short An[32][72];
  __shared__ __align__(16) unsigned short Tl[32][72];
  int t=threadIdx.x;
  for(int q=t;q<435;q+=512){ ((float2*)sX)[q]=X1[b*435+q]; ((float2*)sP)[q]=psi1cO[o*435+q]; }
  for(int q=t;q<64*72;q+=512){
    int R=q/72, k=q%72; float v=0.f;
    if(k<64){ int kk=k&31, kh=k>>5;
      if(kk<29){
        if(R<30){ float2 e=I1g[R*29+kk]; v = kh ? -e.y : e.x; }
        else if(R>=32 && R<62){ float2 e=I1g[(R-32)*29+kk]; v = kh ? e.x : e.y; }
      }
    }
    I1A[R][k]=f2bf(v);
  }
  for(int q=t;q<32*72;q+=512){
    int Qr=q/72, k=q%72; float v=0.f;
    if(Qr<30 && k<64){ int kk=k&31, kh=k>>5;
      if(kk<29){ float2 e=I1g[Qr*29+kk]; v = kh ? -e.y : e.x; }
    }
    I1C[Qr][k]=f2bf(v);
  }
  for(int q=t;q<32*72;q+=512){ An[q/72][q%72]=0; Tl[q/72][q%72]=0; }
  __syncthreads();
  float Pr[2][15], Pi[2][15];
  #pragma unroll
  for(int s=0;s<2;s++){
    int id=t+512*s;
    if(id<841){
      int m=id/29, n=id%29;
      #pragma unroll
      for(int l=0;l<15;l++){
        float2 xx=sX[l][m], pp=sP[l][n];
        Pr[s][l]=xx.x*pp.x-xx.y*pp.y;
        Pi[s][l]=xx.x*pp.y+xx.y*pp.x;
      }
    }
  }
  int wid=t>>6, lane=t&63;
  int fr=lane&15, ko=(lane>>4)*8;
  int mwB=wid>>1, nwB=wid&1;
  short8v aB0 = *(const short8v*)&I1A[16*mwB+fr][ko];
  short8v aB1 = *(const short8v*)&I1A[16*mwB+fr][32+ko];
  int mwC=(wid>>1)&1, nwC=wid&1;
  short8v bC0 = *(const short8v*)&I1C[16*nwC+fr][ko];
  short8v bC1 = *(const short8v*)&I1C[16*nwC+fr][32+ko];
  float bias=b1[o];
  for(int j=0;j<30;j++){
    #pragma unroll
    for(int s=0;s<2;s++){
      int id=t+512*s;
      if(id<841){
        const float* dp = D1I + j*841 + id;
        float ar=0.f, ai=0.f;
        #pragma unroll
        for(int l=0;l<15;l++){ float d=dp[l*25230]; ar+=Pr[s][l]*d; ai+=Pi[s][l]*d; }
        int m=id/29, n=id%29;
        An[n][m]   =f2bf(ar);
        An[n][32+m]=f2bf(ai);
      }
    }
    __syncthreads();
    f32x4 accB={0.f,0.f,0.f,0.f};
    short8v b0 = *(const short8v*)&An[16*nwB+fr][ko];
    short8v b1v= *(const short8v*)&An[16*nwB+fr][32+ko];
    accB=__builtin_amdgcn_mfma_f32_16x16x32_bf16(aB0,b0,accB,0,0,0);
    accB=__builtin_amdgcn_mfma_f32_16x16x32_bf16(aB1,b1v,accB,0,0,0);
    #pragma unroll
    for(int r=0;r<4;r++){
      int R=16*mwB+(lane>>4)*4+r;
      int cc=16*nwB+fr;
      Tl[R&31][(R>>5)*32+cc]=f2bf(accB[r]);
    }
    __syncthreads();
    if(wid<4){
      f32x4 accC={0.f,0.f,0.f,0.f};
      short8v a0 = *(const short8v*)&Tl[16*mwC+fr][ko];
      short8v a1 = *(const short8v*)&Tl[16*mwC+fr][32+ko];
      accC=__builtin_amdgcn_mfma_f32_16x16x32_bf16(a0,bC0,accC,0,0,0);
      accC=__builtin_amdgcn_mfma_f32_16x16x32_bf16(a1,bC1,accC,0,0,0);
      size_t base=((size_t)(b*20+o)*30+j)*900;
      #pragma unroll
      for(int r=0;r<4;r++){
        int p=16*mwC+(lane>>4)*4+r, qq=16*nwC+fr;
        if(p<30 && qq<30){
          float v=fmaxf(accC[r]+bias,0.f);
          h1[base+p*30+qq]=f2bf(v);
        }
      }
    }
  }
}

// psi2 GEMM: Cpsi[l](896x768 f32) = w2bf(896x192) x Y2bf[l]^T(192x768)
__global__ __launch_bounds__(256) void k3g(const unsigned short* __restrict__ A,
                                           const unsigned short* __restrict__ B,
                                           float* __restrict__ Cf){
  int l = blockIdx.z;
  int m0 = blockIdx.y*128, n0 = blockIdx.x*128;
  __shared__ unsigned short As[128][40];
  __shared__ unsigned short Bs[128][40];
  int t = threadIdx.x;
  int wid = t>>6, lane = t&63;
  int wr = wid>>1, wc = wid&1;
  f32x4 acc[4][4];
  #pragma unroll
  for(int a=0;a<4;a++)
    #pragma unroll
    for(int c=0;c<4;c++) acc[a][c]=(f32x4){0.f,0.f,0.f,0.f};
  const unsigned short* Ag = A;
  const unsigned short* Bg = B + (size_t)l*768*192;
  int row_a = wr*64 + (lane&15);
  int row_b = wc*64 + (lane&15);
  int ko = (lane>>4)*8;
  for(int kt=0; kt<192; kt+=32){
    #pragma unroll
    for(int it=0; it<2; it++){
      int q = t + 256*it;
      int r = q>>2, c8 = (q&3)*8;
      *(uint4*)&As[r][c8] = *(const uint4*)&Ag[(size_t)(m0+r)*192 + kt + c8];
      *(uint4*)&Bs[r][c8] = *(const uint4*)&Bg[(size_t)(n0+r)*192 + kt + c8];
    }
    __syncthreads();
    short8v af[4], bfv[4];
    #pragma unroll
    for(int f=0; f<4; f++){
      af[f]  = *(const short8v*)&As[row_a + f*16][ko];
      bfv[f] = *(const short8v*)&Bs[row_b + f*16][ko];
    }
    #pragma unroll
    for(int fm=0;fm<4;fm++)
      #pragma unroll
      for(int fn=0;fn<4;fn++)
        acc[fm][fn] = __builtin_amdgcn_mfma_f32_16x16x32_bf16(af[fm], bfv[fn], acc[fm][fn], 0,0,0);
    __syncthreads();
  }
  #pragma unroll
  for(int fm=0;fm<4;fm++){
    int mb = m0 + wr*64 + fm*16 + ((lane>>4)*4);
    #pragma unroll
    for(int fn=0;fn<4;fn++){
      int n = n0 + wc*64 + fn*16 + (lane&15);
      #pragma unroll
      for(int r=0;r<4;r++){
        Cf[((size_t)(l*896)+mb+r)*768 + n] = acc[fm][fn][r];
      }
    }
  }
}

// Cpsi -> B_augT bf16 (coalesced both sides)
__global__ __launch_bounds__(384) void kBt(const float* __restrict__ Cf,
                                           unsigned short* __restrict__ Bt){
  int c = blockIdx.x;      // o*19+kk
  int l = blockIdx.y;
  int t = threadIdx.x;
  if(t>=380) return;
  int i=t/19, n=t%19;
  int o=c/19, kk=c%19;
  float2 v = *(const float2*)&Cf[((size_t)(l*896) + i*40+o)*768 + (kk*19+n)*2];
  float zr = v.x, zi = -v.y;
  unsigned short* base = Bt + (size_t)l*1536*768;
  size_t r0=(size_t)(2*c)*768, r1=r0+768;
  int col=i*19+n;
  base[r0+col]     = f2bf(zr);
  base[r0+384+col] = f2bf(-zi);
  base[r1+col]     = f2bf(zi);
  base[r1+384+col] = f2bf(zr);
}

// per (b,i): fft2(30x30 -> 19x19) * D2F summed over j -> A_aug bf16.
// MFMA batched over j (chunks of 10, 3 passes):
//  S1 GEMM: T1[(j,a)][n'] = h1 @ E2c^T    (M=300,N=38,K=32) -> LDS [jn][a_aug72]
//  S2 GEMM: U2[m'][(j,n)] = E2A @ T1      (M=38, N=190,K=64) -> LDS [jn][m'44]
//  S3 VALU: acc[l] += D2F[l,j,m,n] * xf   (register accumulators across passes)
// T1/U2 fully zero-initialized (NaN lesson); h1 has 512B zeroed tail pad for
// the K/M overreads of S1's global A-fragments.
__global__ __launch_bounds__(512) void k4(const unsigned short* __restrict__ h1,
                                          const float* __restrict__ D2F,
                                          const float2* __restrict__ E2g,
                                          unsigned short* __restrict__ Aaug){
  int i=blockIdx.x, b=blockIdx.y;
  __shared__ __align__(16) unsigned short E2c[48][32];
  __shared__ __align__(16) unsigned short E2A[48][64];
  __shared__ __align__(16) unsigned short T1[192][72];
  __shared__ __align__(16) unsigned short U2[192][44];
  int t=threadIdx.x;
  for(int q=t;q<48*32;q+=512){
    int R=q>>5, g=q&31; float v=0.f;
    if(R<38 && g<30){ float2 e=E2g[(R%19)*30+g]; v=(R<19)? e.x : e.y; }
    E2c[R][g]=f2bf(v);
  }
  for(int q=t;q<48*64;q+=512){
    int R=q>>6, c=q&63; float v=0.f;
    if(R<38){
      int mm=R%19; int mi=(R>=19);
      if(c<30){ float2 e=E2g[mm*30+c]; v = mi ? e.y : e.x; }
      else if(c>=32 && c<62){ float2 e=E2g[mm*30+(c-32)]; v = mi ? e.x : -e.y; }
    }
    E2A[R][c]=f2bf(v);
  }
  for(int q=t;q<192*72;q+=512) T1[q/72][q%72]=0;
  for(int q=t;q<192*44;q+=512) U2[q/44][q%44]=0;
  float accr[10], acci[10];
  #pragma unroll
  for(int l=0;l<10;l++){ accr[l]=0.f; acci[l]=0.f; }
  int m3=t/19, n3=t%19;                // stage3 ids (valid t<361)
  int wid=t>>6, lane=t&63, fr=lane&15, fc=lane&15, ko=(lane>>4)*8, rq=(lane>>4)*4;
  size_t blk=(size_t)(b*20+i)*27000;
  const unsigned int* h1u=(const unsigned int*)h1;
  __syncthreads();
  for(int p=0;p<3;p++){
    int j0=p*10;
    // ---- S1: T1 = h1_chunk @ E2c^T (A from global) ----
    for(int mt=wid; mt<19; mt+=8){
      int rg=16*mt+fr;
      size_t base=blk + (size_t)j0*900 + (size_t)rg*30 + ko;   // even element idx
      union{ unsigned int u[4]; short8v v; } A;
      const unsigned int* pp=h1u + (base>>1);
      A.u[0]=pp[0]; A.u[1]=pp[1]; A.u[2]=pp[2]; A.u[3]=pp[3];
      #pragma unroll
      for(int nt=0;nt<3;nt++){
        short8v Bf=*(const short8v*)&E2c[16*nt+fr][ko];
        f32x4 ac={0.f,0.f,0.f,0.f};
        ac=__builtin_amdgcn_mfma_f32_16x16x32_bf16(A.v,Bf,ac,0,0,0);
        int np=16*nt+fc;
        if(np<38){
          int ri=(np>=19), nn=np-19*ri;
          #pragma unroll
          for(int r=0;r<4;r++){
            int rgw=16*mt+rq+r;
            if(rgw<300){
              int jr=rgw/30, a=rgw%30;
              T1[jr*19+nn][32*ri+a]=f2bf(ac[r]);
            }
          }
        }
      }
    }
    __syncthreads();
    // ---- S2: U2 = E2A @ T1 ----
    for(int u=0;u<5;u++){
      int tile=wid+8*u; if(tile>=36) break;
      int mt2=tile/12, nt2=tile%12;
      short8v a0=*(const short8v*)&E2A[16*mt2+fr][ko];
      short8v a1=*(const short8v*)&E2A[16*mt2+fr][32+ko];
      short8v b0=*(const short8v*)&T1[16*nt2+fr][ko];
      short8v b1=*(const short8v*)&T1[16*nt2+fr][32+ko];
      f32x4 ac={0.f,0.f,0.f,0.f};
      ac=__builtin_amdgcn_mfma_f32_16x16x32_bf16(a0,b0,ac,0,0,0);
      ac=__builtin_amdgcn_mfma_f32_16x16x32_bf16(a1,b1,ac,0,0,0);
      int jn=16*nt2+fc;
      if(jn<190){
        #pragma unroll
        for(int r=0;r<4;r++){
          int R=16*mt2+rq+r;
          if(R<38) U2[jn][R]=f2bf(ac[r]);
        }
      }
    }
    __syncthreads();
    // ---- S3: D2F contraction into registers ----
    if(t<361){
      for(int jr=0;jr<10;jr++){
        int jg=j0+jr;
        const float* dp=D2F + (size_t)jg*361 + t;
        float xr=bf2f(U2[jr*19+n3][m3]);
        float xi=bf2f(U2[jr*19+n3][19+m3]);
        #pragma unroll
        for(int l=0;l<10;l++){ float d=dp[l*10830]; accr[l]+=d*xr; acci[l]+=d*xi; }
      }
    }
  }
  if(t<361){
    #pragma unroll
    for(int l=0;l<10;l++){
      size_t row=((size_t)(l*640) + b*19+m3)*768;
      Aaug[row + i*19+n3]       = f2bf(accr[l]);
      Aaug[row + 384 + i*19+n3] = f2bf(acci[l]);
    }
  }
}

// bf16 MFMA GEMM per l: Z[l](608x1520 f32) = A_aug[l](640x768) x B_augT[l]^T
__global__ __launch_bounds__(256) void k5(const unsigned short* __restrict__ A,
                                          const unsigned short* __restrict__ B,
                                          float* __restrict__ Cf){
  int l = blockIdx.z;
  int m0 = blockIdx.y*128, n0 = blockIdx.x*128;
  __shared__ unsigned short As[128][40];
  __shared__ unsigned short Bs[128][40];
  int t = threadIdx.x;
  int wid = t>>6, lane = t&63;
  int wr = wid>>1, wc = wid&1;
  f32x4 acc[4][4];
  #pragma unroll
  for(int a=0;a<4;a++)
    #pragma unroll
    for(int c=0;c<4;c++) acc[a][c]=(f32x4){0.f,0.f,0.f,0.f};
  const unsigned short* Ag = A + (size_t)l*640*768;
  const unsigned short* Bg = B + (size_t)l*1536*768;
  int row_a = wr*64 + (lane&15);
  int row_b = wc*64 + (lane&15);
  int ko = (lane>>4)*8;
  for(int kt=0; kt<768; kt+=32){
    #pragma unroll
    for(int it=0; it<2; it++){
      int q = t + 256*it;
      int r = q>>2, c8 = (q&3)*8;
      *(uint4*)&As[r][c8] = *(const uint4*)&Ag[(size_t)(m0+r)*768 + kt + c8];
      *(uint4*)&Bs[r][c8] = *(const uint4*)&Bg[(size_t)(n0+r)*768 + kt + c8];
    }
    __syncthreads();
    short8v af[4], bfv[4];
    #pragma unroll
    for(int f=0; f<4; f++){
      af[f]  = *(const short8v*)&As[row_a + f*16][ko];
      bfv[f] = *(const short8v*)&Bs[row_b + f*16][ko];
    }
    #pragma unroll
    for(int fm=0;fm<4;fm++)
      #pragma unroll
      for(int fn=0;fn<4;fn++)
        acc[fm][fn] = __builtin_amdgcn_mfma_f32_16x16x32_bf16(af[fm], bfv[fn], acc[fm][fn], 0,0,0);
    __syncthreads();
  }
  #pragma unroll
  for(int fm=0;fm<4;fm++){
    int mb = m0 + wr*64 + fm*16 + ((lane>>4)*4);
    #pragma unroll
    for(int fn=0;fn<4;fn++){
      int n = n0 + wc*64 + fn*16 + (lane&15);
      if(n<1520){
        #pragma unroll
        for(int r=0;r<4;r++){
          int m = mb + r;
          if(m<608) Cf[((size_t)(l*608)+m)*1520 + n] = acc[fm][fn][r];
        }
      }
    }
  }
}

// conv2 inverse, MFMA batched over j (no j-loop)
__global__ __launch_bounds__(512) void k6(const float2* __restrict__ Z,
                                          const float* __restrict__ D2I,
                                          const float2* __restrict__ I2g,
                                          const float* __restrict__ b2,
                                          unsigned short* __restrict__ h2){
  int o=blockIdx.x, b=blockIdx.y;
  __shared__ __align__(16) unsigned short U[29952];   // An[384][72] / Tl[416][72]
  __shared__ __align__(16) unsigned short I2A[48][72];
  __shared__ __align__(16) unsigned short I2C[32][72];
  int t=threadIdx.x;
  for(int q=t;q<14976;q+=512) ((unsigned int*)U)[q]=0u;
  for(int q=t;q<48*72;q+=512){
    int R=q/72, kd=q%72; float v=0.f;
    if(kd<38){
      int mm = (kd<19)? kd : kd-19; int hi = (kd>=19);
      if(R<20){ float2 e=I2g[R*19+mm]; v = hi ? -e.y : e.x; }
      else if(R<40){ float2 e=I2g[(R-20)*19+mm]; v = hi ? e.x : e.y; }
    }
    I2A[R][kd]=f2bf(v);
  }
  for(int q=t;q<32*72;q+=512){
    int Qr=q/72, kd=q%72; float v=0.f;
    if(Qr<20 && kd<38){
      int kk2 = (kd<19)? kd : kd-19; int hi = (kd>=19);
      float2 e=I2g[Qr*19+kk2]; v = hi ? -e.y : e.x;
    }
    I2C[Qr][kd]=f2bf(v);
  }
  float zr[10], zi[10];
  int m=t/19, kk=t%19;   // valid t<361
  if(t<361){
    #pragma unroll
    for(int l=0;l<10;l++){
      float2 z=Z[(size_t)(l*608 + b*19+m)*760 + o*19+kk];
      zr[l]=z.x; zi[l]=z.y;
    }
  }
  __syncthreads();
  if(t<361){
    for(int j=0;j<20;j++){
      float ar=0.f, ai=0.f;
      const float* dp = D2I + j*361 + t;
      #pragma unroll
      for(int l=0;l<10;l++){ float d=dp[l*7220]; ar+=zr[l]*d; ai+=zi[l]*d; }
      U[(j*19+kk)*72 + m]      = f2bf(ar);
      U[(j*19+kk)*72 + 19 + m] = f2bf(ai);
    }
  }
  __syncthreads();
  int wid=t>>6, lane=t&63, fr=lane&15, ko=(lane>>4)*8;
  f32x4 acc1[9];
  #pragma unroll
  for(int u=0;u<9;u++){
    int tile=wid+8*u;           // 0..71
    int mt=tile/24, nt=tile%24;
    short8v a0=*(const short8v*)&I2A[16*mt+fr][ko];
    short8v a1=*(const short8v*)&I2A[16*mt+fr][32+ko];
    short8v bb0=*(const short8v*)&U[(16*nt+fr)*72+ko];
    short8v bb1=*(const short8v*)&U[(16*nt+fr)*72+32+ko];
    f32x4 ac={0.f,0.f,0.f,0.f};
    ac=__builtin_amdgcn_mfma_f32_16x16x32_bf16(a0,bb0,ac,0,0,0);
    ac=__builtin_amdgcn_mfma_f32_16x16x32_bf16(a1,bb1,ac,0,0,0);
    acc1[u]=ac;
  }
  __syncthreads();   // all An reads done before Tl overlay writes
  #pragma unroll
  for(int u=0;u<9;u++){
    int tile=wid+8*u; int mt=tile/24, nt=tile%24;
    #pragma unroll
    for(int r=0;r<4;r++){
      int R=16*mt+(lane>>4)*4+r;
      int n=16*nt+fr;
      if(R<40 && n<380){
        int j=n/19, kq=n%19;
        U[(j*20 + (R%20))*72 + (R/20)*19 + kq] = f2bf(acc1[u][r]);
      }
    }
  }
  __syncthreads();
  float bias=b2[o];
  size_t obase=((size_t)b*40+o)*8000;
  #pragma unroll
  for(int u=0;u<7;u++){
    int tile=wid+8*u;
    if(tile<52){
      int mt=tile>>1, nt=tile&1;
      short8v a0=*(const short8v*)&U[(16*mt+fr)*72+ko];
      short8v a1=*(const short8v*)&U[(16*mt+fr)*72+32+ko];
      short8v bb0=*(const short8v*)&I2C[16*nt+fr][ko];
      short8v bb1=*(const short8v*)&I2C[16*nt+fr][32+ko];
      f32x4 ac={0.f,0.f,0.f,0.f};
      ac=__builtin_amdgcn_mfma_f32_16x16x32_bf16(a0,bb0,ac,0,0,0);
      ac=__builtin_amdgcn_mfma_f32_16x16x32_bf16(a1,bb1,ac,0,0,0);
      #pragma unroll
      for(int r=0;r<4;r++){
        int row=16*mt+(lane>>4)*4+r;
        int q=16*nt+fr;
        if(row<400 && q<20){
          float v=fmaxf(ac[r]+bias,0.f);
          h2[obase + row*20 + q]=f2bf(v);
        }
      }
    }
  }
}

// g[b,f] = (2pi/20)^2 * sum_{j,p,q} h2 * W_INT[j]   (h2 bf16, paired reads)
__global__ __launch_bounds__(256) void k7a(const unsigned int* __restrict__ h2p,
                                           const float* __restrict__ WI,
                                           float* __restrict__ g){
  int bf=blockIdx.x;
  const unsigned int* base=h2p + (size_t)bf*4000;
  int t=threadIdx.x; float s=0.f;
  for(int q=t;q<4000;q+=256){
    unsigned int v=base[q];
    float w=WI[q/200];
    s += (bf2f((unsigned short)(v&0xFFFF))+bf2f((unsigned short)(v>>16)))*w;
  }
  __shared__ float red[256];
  red[t]=s; __syncthreads();
  for(int off=128;off>0;off>>=1){ if(t<off) red[t]+=red[t+off]; __syncthreads(); }
  if(t==0){
    const float c=(float)((2.0*M_PI/20.0)*(2.0*M_PI/20.0));
    g[bf]=red[0]*c;
  }
}

__global__ __launch_bounds__(64) void k7b(const float* __restrict__ g,
                                          const float* __restrict__ wlin,
                                          const float* __restrict__ bl,
                                          float* __restrict__ out){
  int idx=blockIdx.x*64+threadIdx.x;
  if(idx>=320) return;
  int b=idx/10, c=idx%10;
  float s=bl[c];
  for(int f=0;f<40;f++) s += g[b*40+f]*wlin[c*40+f];
  out[b*10+c]=s;
}

extern "C" void kernel_launch(void* const* d_in, const int* in_sizes, int n_in,
                              void* d_out, int out_size, void* d_ws, size_t ws_size,
                              hipStream_t stream){
  (void)in_sizes; (void)n_in; (void)out_size;
  const float* x    = (const float*)d_in[0];
  const float* w1   = (const float*)d_in[1];
  const float* b1   = (const float*)d_in[2];
  const float* w2   = (const float*)d_in[3];
  const float* b2   = (const float*)d_in[4];
  const float* wlin = (const float*)d_in[5];
  const float* bl   = (const float*)d_in[6];
  float* out = (float*)d_out;
  char*  ws  = (char*)d_ws;

  if(ws_size < WS_NEED){
    fprintf(stderr, "kernel_launch: ws too small: have %zu need %lu\n", ws_size, WS_NEED);
  }

  float* C = (float*)(ws + WOFF_CONST);
  const float*  D1F = C + OFF_D1F;
  const float*  D1I = C + OFF_D1I;
  const float2* Y1  = (const float2*)(C + OFF_Y1);
  const float*  D2F = C + OFF_D2F;
  const float*  D2I = C + OFF_D2I;
  const float*  WI  = C + OFF_WI;
  const float2* E1  = (const float2*)(C + OFF_E1);
  const float2* I1  = (const float2*)(C + OFF_I1);
  const float2* E2  = (const float2*)(C + OFF_E2);
  const float2* I2  = (const float2*)(C + OFF_I2);

  float2* xf1   = (float2*)(ws + WOFF_XF1);
  float2* X1    = (float2*)(ws + WOFF_X1);
  float2* psi1c = (float2*)(ws + WOFF_PSI1);
  unsigned short* h1   = (unsigned short*)(ws + WOFF_H1);
  unsigned short* Y2bf = (unsigned short*)(ws + WOFF_Y2BF);
  unsigned short* w2bf = (unsigned short*)(ws + WOFF_W2BF);
  float*  Cpsi  = (float*)(ws + WOFF_CPSI);
  unsigned short* Aaug = (unsigned short*)(ws + WOFF_AAUG);
  unsigned short* Bt   = (unsigned short*)(ws + WOFF_BT);
  float*  Zf    = (float*)(ws + WOFF_Z);
  unsigned short* h2 = (unsigned short*)(ws + WOFF_H2);
  float*  g     = (float*)(ws + WOFF_G);

  hipLaunchKernelGGL(kconst0, dim3(16), dim3(256), 0, stream, C);
  hipLaunchKernelGGL(kconst, dim3(2048), dim3(256), 0, stream, C, (unsigned int*)Y2bf);
  hipLaunchKernelGGL(kfill, dim3(2048), dim3(256), 0, stream,
                     (uint4*)(ws + WOFF_AAUG), (long)(33423360ul/16ul));
  // zero 512B tail pad after h1 (k4's S1 A-fragments overread up to ~256B)
  hipLaunchKernelGGL(kfill, dim3(1), dim3(256), 0, stream,
                     (uint4*)(ws + WOFF_H1 + 34560000ul), 32L);
  hipLaunchKernelGGL(kw2, dim3((896*96+255)/256), dim3(256), 0, stream, w2, (unsigned int*)w2bf);

  hipLaunchKernelGGL(k1a, dim3((32*60*29+255)/256), dim3(256), 0, stream, x, E1, xf1);
  hipLaunchKernelGGL(k1b, dim3((32*15*29+255)/256), dim3(256), 0, stream, xf1, D1F, X1);
  hipLaunchKernelGGL(kpsi1, dim3((15*29*20+255)/256), dim3(256), 0, stream, w1, Y1, psi1c);
  hipLaunchKernelGGL(k2, dim3(20,32), dim3(512), 0, stream, X1, psi1c, D1I, I1, b1, h1);
  hipLaunchKernelGGL(k4, dim3(20,32), dim3(512), 0, stream, h1, D2F, E2, Aaug);
  hipLaunchKernelGGL(k3g, dim3(6,7,10), dim3(256), 0, stream, w2bf, Y2bf, Cpsi);
  hipLaunchKernelGGL(kBt, dim3(760,10), dim3(384), 0, stream, Cpsi, Bt);
  hipLaunchKernelGGL(k5, dim3(12,5,10), dim3(256), 0, stream, Aaug, Bt, Zf);
  hipLaunchKernelGGL(k6, dim3(40,32), dim3(512), 0, stream, (const float2*)Zf, D2I, I2, b2, h2);
  hipLaunchKernelGGL(k7a, dim3(1280), dim3(256), 0, stream, (const unsigned int*)h2, WI, g);
  hipLaunchKernelGGL(k7b, dim3(5), dim3(64), 0, stream, g, wlin, bl, out);
}

// Round 8
// 433.878 us; speedup vs baseline: 3.4718x; 1.0034x over previous
//
#include <hip/hip_runtime.h>
#include <cmath>
#include <cstdio>

#ifndef M_PI
#define M_PI 3.14159265358979323846
#endif

// ---------------- constant table offsets (in floats) ----------------
#define OFF_D1F 0        // [15][60][29]
#define OFF_D1I 26100    // [15][30][29][29]
#define OFF_Y1  404550   // [15][29][24] complex
#define OFF_D2F 425430   // [10][30][19][19]
#define OFF_D2I 533730   // [10][20][19][19]
#define OFF_WI  605930   // [20]
#define OFF_E1  605950   // [29][60] complex
#define OFF_I1  609430   // [30][29] complex
#define OFF_E2  611170   // [19][30] complex
#define OFF_I2  612310   // [20][19] complex
#define OFF_DHW30 613070 // [60]
#define OFF_DHW15 613130 // [30]
#define NCONST  613160

// ---------------- workspace byte offsets ----------------
#define WOFF_CONST 0ul
#define WOFF_Y2BF  2457600ul                 // bf16 [10][768][192] = 2,949,120
#define WOFF_W2BF  5406720ul                 // bf16 [896][192]     =   344,064
#define WOFF_AAUG  5750784ul                 // bf16 [10][640][768] = 9,830,400
#define WOFF_BT    15581184ul                // bf16 [10][1536][768]= 23,592,960
#define WOFF_H1    39174144ul                // bf16 [32][20][27000]= 34,560,000 (+512B zero pad)
#define WOFF_CPSI  39174144ul                // f32 [10][896][768]  = 27,525,120 (h1 dead)
#define WOFF_Z     39174144ul                // f32 [10][608][1520] = 36,966,400 (Cpsi dead)
#define WOFF_H2    2457600ul                 // bf16 [32][40][8000] = 20,480,000
#define WOFF_XF1   76140544ul
#define WOFF_X1    (76140544ul + 445440ul)
#define WOFF_PSI1  (76140544ul + 445440ul + 111360ul)
#define WOFF_G     (76140544ul + 445440ul + 111360ul + 69600ul)
#define WS_NEED    (WOFF_G + 5120ul)

typedef __attribute__((ext_vector_type(8))) short short8v;
typedef __attribute__((ext_vector_type(4))) float f32x4;

__device__ inline unsigned short f2bf(float x){
  unsigned int u = __float_as_uint(x);
  u += 0x7FFFu + ((u >> 16) & 1u);
  return (unsigned short)(u >> 16);
}
__device__ inline float bf2f(unsigned short u){
  return __uint_as_float(((unsigned int)u) << 16);
}

// ================= device helpers for constant generation =================
__device__ inline double dfact(int n){ double r=1.0; for(int i=2;i<=n;i++) r*=(double)i; return r; }
__device__ inline double dpowi(double x,int e){ double r=1.0; for(int i=0;i<e;i++) r*=x; return r; }
__device__ double wig(int l,int m,int n,double beta){
  if(m < -l || m > l || n < -l || n > l) return 0.0;
  double cb=cos(0.5*beta), sb=sin(0.5*beta);
  double pref=sqrt(dfact(l+m)*dfact(l-m)*dfact(l+n)*dfact(l-n));
  int k0 = (m-n)>0 ? (m-n) : 0;
  int k1 = (l+m) < (l-n) ? (l+m) : (l-n);
  double c0 = ((k0&1)?-1.0:1.0)/(dfact(k0)*dfact(l+m-k0)*dfact(l-n-k0)*dfact(n-m+k0));
  double t = c0 * dpowi(cb, 2*l+m-n-2*k0) * dpowi(sb, n-m+2*k0);
  double ratio = (sb*sb)/(cb*cb);
  double s = t;
  for(int k=k0;k<k1;k++){
    t *= -((double)(l+m-k)*(double)(l-n-k)) / ((double)(k+1)*(double)(n-m+k+1)) * ratio;
    s += t;
  }
  return pref*s;
}
__device__ inline double dh_w(int b,int j){
  double s=0.0;
  for(int k=0;k<b;k++) s += sin((2.0*j+1.0)*(2.0*k+1.0)*M_PI/(4.0*b))/(2.0*k+1.0);
  return (2.0/b)*sin(M_PI*(2.0*j+1.0)/(4.0*b))*s;
}
__device__ inline double soft_beta(int b,int j){ return M_PI*(2.0*j+1.0)/(4.0*b); }
__device__ inline void octcs(int q, double* c, double* s){
  const double r = 0.70710678118654752440;
  int i = q & 7;
  const double C[8]={1.0,r,0.0,-r,-1.0,-r,0.0,r};
  const double S[8]={0.0,r,1.0,r,0.0,-r,-1.0,-r};
  *c=C[i]; *s=S[i];
}

// small tables: quadrature weights + DFT twiddles
__global__ __launch_bounds__(256) void kconst0(float* __restrict__ C){
  for(int idx = blockIdx.x*256 + threadIdx.x; idx < 3670; idx += gridDim.x*256){
    if(idx < 20){ C[OFF_WI+idx]=(float)dh_w(10,idx); }
    else if(idx < 80){ int j=idx-20; C[OFF_DHW30+j]=(float)dh_w(30,j); }
    else if(idx < 110){ int j=idx-80; C[OFF_DHW15+j]=(float)dh_w(15,j); }
    else if(idx < 1850){ int q=idx-110; // E1 [29][60]
      int a=q%60; int m=q/60; double ph=-2.0*M_PI*(double)(m-14)*a/60.0;
      C[OFF_E1+2*q]=(float)cos(ph); C[OFF_E1+2*q+1]=(float)sin(ph);
    } else if(idx < 2720){ int q=idx-1850; // I1 [30][29]
      int m=q%29; int p=q/29; double ph=2.0*M_PI*(double)p*(double)(m-14)/30.0;
      C[OFF_I1+2*q]=(float)cos(ph); C[OFF_I1+2*q+1]=(float)sin(ph);
    } else if(idx < 3290){ int q=idx-2720; // E2 [19][30]
      int a=q%30; int m=q/30; double ph=-2.0*M_PI*(double)(m-9)*a/30.0;
      C[OFF_E2+2*q]=(float)cos(ph); C[OFF_E2+2*q+1]=(float)sin(ph);
    } else { int q=idx-3290; // I2 [20][19]
      int m=q%19; int p=q/19; double ph=2.0*M_PI*(double)p*(double)(m-9)/20.0;
      C[OFF_I2+2*q]=(float)cos(ph); C[OFF_I2+2*q+1]=(float)sin(ph);
    }
  }
}

// big tables (reads DHW tables written by kconst0)
__global__ __launch_bounds__(256) void kconst(float* __restrict__ C,
                                              unsigned int* __restrict__ Y2p){
  for(long idx = (long)blockIdx.x*blockDim.x + threadIdx.x; idx < 1332770L;
      idx += (long)gridDim.x*blockDim.x){
    if(idx < 26100L){                       // D1F [15][60][29]
      int m=(int)(idx%29); int j=(int)((idx/29)%60); int l=(int)(idx/(29*60));
      C[OFF_D1F+idx] = (float)( wig(l, m-14, 0, soft_beta(30,j)) * (double)C[OFF_DHW30+j] );
    } else if(idx < 404550L){ long q=idx-26100L;   // D1I [15][30][29][29]
      int n=(int)(q%29); int m=(int)((q/29)%29); int j=(int)((q/841)%30); int l=(int)(q/(841*30));
      C[OFF_D1I+q] = (float)wig(l, m-14, n-14, soft_beta(15,j));
    } else if(idx < 414990L){ long q=idx-404550L;  // Y1 [15][29][24] complex
      int g=(int)(q%24); int m=(int)((q/24)%29); int l=(int)(q/(24*29));
      double gb=((g>>3)+1)*(M_PI/8.0)/3.0;
      int ka = g&7;
      double mag=(2*l+1)*wig(l, m-14, 0, gb);
      double cc,ss; octcs((m-14)*ka, &cc, &ss);
      C[OFF_Y1+2*q]  =(float)(mag*cc);
      C[OFF_Y1+2*q+1]=(float)(-mag*ss);
    } else if(idx < 523290L){ long q=idx-414990L;  // D2F [10][30][19][19]
      int n=(int)(q%19); int m=(int)((q/19)%19); int j=(int)((q/361)%30); int l=(int)(q/(361*30));
      C[OFF_D2F+q]=(float)( wig(l,m-9,n-9,soft_beta(15,j)) * (double)C[OFF_DHW15+j] );
    } else if(idx < 595490L){ long q=idx-523290L;  // D2I [10][20][19][19]
      int n=(int)(q%19); int m=(int)((q/19)%19); int j=(int)((q/361)%20); int l=(int)(q/(361*20));
      C[OFF_D2I+q]=(float)wig(l,m-9,n-9,soft_beta(10,j));
    } else { long q=idx-595490L;                   // Y2bf pairs [10][768][96]
      int g2=(int)(q%96); int row=(int)((q/96)%768); int l=(int)(q/(96*768));
      unsigned int outv=0u;
      if(row<722){
        int kn=row>>1, ri=row&1, kk=kn/19, n=kn%19;
        int g0=2*g2;
        double gb=((g0>>6)+1)*(M_PI/8.0)/3.0;
        double mag=(2*l+1)*wig(l,kk-9,n-9,gb);
        int ka=(g0>>3)&7;
        double c0,s0,c1,s1;
        octcs((kk-9)*ka + (n-9)*(g0&7), &c0,&s0);
        octcs((kk-9)*ka + (n-9)*((g0+1)&7), &c1,&s1);
        float v0 = ri ? (float)(-mag*s0) : (float)(mag*c0);
        float v1 = ri ? (float)(-mag*s1) : (float)(mag*c1);
        outv = (unsigned int)f2bf(v0) | (((unsigned int)f2bf(v1))<<16);
      }
      Y2p[q]=outv;
    }
  }
}

// zero a contiguous region
__global__ __launch_bounds__(256) void kfill(uint4* __restrict__ p, long n16){
  uint4 z; z.x=0u; z.y=0u; z.z=0u; z.w=0u;
  for(long i=(long)blockIdx.x*256+threadIdx.x; i<n16; i+=(long)gridDim.x*256) p[i]=z;
}

// pack w2 -> bf16 [896][192] (rows >=800 zero), u32-paired
__global__ __launch_bounds__(256) void kw2(const float* __restrict__ w2,
                                           unsigned int* __restrict__ w2bf){
  int idx = blockIdx.x*256 + threadIdx.x;
  if(idx >= 896*96) return;
  int row=idx/96, g2=idx%96;
  float a=0.f, b=0.f;
  if(row<800){ a=w2[row*192+2*g2]; b=w2[row*192+2*g2+1]; }
  w2bf[idx] = (unsigned int)f2bf(a) | (((unsigned int)f2bf(b))<<16);
}

// ================= forward-pass kernels =================

__global__ __launch_bounds__(256) void k1a(const float* __restrict__ x,
                                           const float2* __restrict__ E1,
                                           float2* __restrict__ xf1){
  int idx = blockIdx.x*256 + threadIdx.x;
  if(idx >= 32*60*29) return;
  int m = idx % 29; int bj = idx / 29;
  const float* row = x + bj*60;
  float sr=0.f, si=0.f;
  for(int a=0;a<60;a++){ float2 e=E1[m*60+a]; float v=row[a]; sr+=v*e.x; si+=v*e.y; }
  xf1[idx] = make_float2(sr,si);
}

__global__ __launch_bounds__(256) void k1b(const float2* __restrict__ xf1,
                                           const float* __restrict__ D1F,
                                           float2* __restrict__ X1){
  int idx = blockIdx.x*256 + threadIdx.x;
  if(idx >= 32*15*29) return;
  int m = idx % 29; int lb = idx / 29; int l = lb % 15; int b = lb / 15;
  float sr=0.f, si=0.f;
  for(int j=0;j<60;j++){
    float d = D1F[(l*60+j)*29+m]; float2 v = xf1[(b*60+j)*29+m];
    sr += d*v.x; si += d*v.y;
  }
  X1[(b*15+l)*29+m] = make_float2(sr,si);
}

// psi1cO[o][l*29+n] = conj( sum_g w1[0,o,g] * Y1[l,n,g] )
__global__ __launch_bounds__(256) void kpsi1(const float* __restrict__ w1,
                                             const float2* __restrict__ Y1,
                                             float2* __restrict__ psi1cO){
  int idx = blockIdx.x*256 + threadIdx.x;
  if(idx >= 15*29*20) return;
  int o = idx % 20; int ln = idx / 20;
  float sr=0.f, si=0.f;
  for(int g=0;g<24;g++){ float w=w1[o*24+g]; float2 y=Y1[ln*24+g]; sr+=w*y.x; si+=w*y.y; }
  psi1cO[o*435 + ln] = make_float2(sr,-si);
}

// conv1 fused, j batched through MFMA (JC=6 per block, grid.z=5 chunks).
// Phases: A (VALU, D1I contraction -> An bf16 in U) | B (T=I1A@An^T, regs,
// then Tl overlay into U) | C (y=Tflat@I1C^T -> bias+ReLU -> h1).
// U fully zero-initialized (NaN lesson R4); 4 barriers total per block.
#define JC 6
__global__ __launch_bounds__(512) void k2(const float2* __restrict__ X1,
                                          const float2* __restrict__ psi1cO,
                                          const float* __restrict__ D1I,
                                          const float2* __restrict__ I1g,
                                          const float* __restrict__ b1,
                                          unsigned short* __restrict__ h1){
  int o=blockIdx.x, b=blockIdx.y, j0=blockIdx.z*JC;
  __shared__ float2 sX[15][29];
  __shared__ float2 sP[15][29];
  __shared__ __align__(16) unsigned short I1A[64][72];
  __shared__ __align__(16) unsigned short I1C[32][72];
  __shared__ __align__(16) unsigned short U[JC*32*72];  // An[jn][72] / Tl[32][JC*64]
  int t=threadIdx.x;
  for(int q=t;q<435;q+=512){ ((float2*)sX)[q]=X1[b*435+q]; ((float2*)sP)[q]=psi1cO[o*435+q]; }
  for(int q=t;q<64*72;q+=512){
    int R=q/72, k=q%72; float v=0.f;
    if(k<64){ int kk=k&31, kh=k>>5;
      if(kk<29){
        if(R<30){ float2 e=I1g[R*29+kk]; v = kh ? -e.y : e.x; }
        else if(R>=32 && R<62){ float2 e=I1g[(R-32)*29+kk]; v = kh ? e.x : e.y; }
      }
    }
    I1A[R][k]=f2bf(v);
  }
  for(int q=t;q<32*72;q+=512){
    int Qr=q/72, k=q%72; float v=0.f;
    if(Qr<30 && k<64){ int kk=k&31, kh=k>>5;
      if(kk<29){ float2 e=I1g[Qr*29+kk]; v = kh ? -e.y : e.x; }
    }
    I1C[Qr][k]=f2bf(v);
  }
  for(int q=t;q<JC*32*36;q+=512) ((unsigned int*)U)[q]=0u;
  __syncthreads();
  // P = X1 * conj(psi) cached in regs per (m,n) id
  float Pr[2][15], Pi[2][15];
  #pragma unroll
  for(int s=0;s<2;s++){
    int id=t+512*s;
    if(id<841){
      int m=id/29, n=id%29;
      #pragma unroll
      for(int l=0;l<15;l++){
        float2 xx=sX[l][m], pp=sP[l][n];
        Pr[s][l]=xx.x*pp.x-xx.y*pp.y;
        Pi[s][l]=xx.x*pp.y+xx.y*pp.x;
      }
    }
  }
  int wid=t>>6, lane=t&63;
  int fr=lane&15, fc=lane&15, rq=(lane>>4)*4, ko=(lane>>4)*8;
  float bias=b1[o];
  // ---- stage A: An[jr*32+n][m_aug] for all JC j ----
  #pragma unroll
  for(int s=0;s<2;s++){
    int id=t+512*s;
    if(id<841){
      int m=id/29, n=id%29;
      for(int jr=0;jr<JC;jr++){
        const float* dp = D1I + (j0+jr)*841 + id;
        float ar=0.f, ai=0.f;
        #pragma unroll
        for(int l=0;l<15;l++){ float d=dp[l*25230]; ar+=Pr[s][l]*d; ai+=Pi[s][l]*d; }
        U[(jr*32+n)*72 + m]    = f2bf(ar);
        U[(jr*32+n)*72 + 32+m] = f2bf(ai);
      }
    }
  }
  __syncthreads();
  // ---- stage B: T = I1A(64x64) @ An^T(64 x JC*32); 4 x 2JC tiles ----
  f32x4 accB[JC];
  #pragma unroll
  for(int u=0;u<JC;u++){
    int tile = wid + 8*u;            // 0 .. 8*JC-1
    int mt = tile/(2*JC), nt = tile%(2*JC);
    short8v a0=*(const short8v*)&I1A[16*mt+fr][ko];
    short8v a1=*(const short8v*)&I1A[16*mt+fr][32+ko];
    short8v b0=*(const short8v*)&U[(16*nt+fr)*72+ko];
    short8v b1=*(const short8v*)&U[(16*nt+fr)*72+32+ko];
    f32x4 ac={0.f,0.f,0.f,0.f};
    ac=__builtin_amdgcn_mfma_f32_16x16x32_bf16(a0,b0,ac,0,0,0);
    ac=__builtin_amdgcn_mfma_f32_16x16x32_bf16(a1,b1,ac,0,0,0);
    accB[u]=ac;
  }
  __syncthreads();   // all An reads done before Tl overlay writes
  #pragma unroll
  for(int u=0;u<JC;u++){
    int tile = wid + 8*u;
    int mt = tile/(2*JC), nt = tile%(2*JC);
    #pragma unroll
    for(int r=0;r<4;r++){
      int R=16*mt+rq+r;              // 0..63
      int jn=16*nt+fc;               // 0..JC*32-1
      int p=R&31, hi=R>>5, jj=jn>>5, n=jn&31;
      U[p*(JC*64) + jj*64 + hi*32 + n] = f2bf(accB[u][r]);
    }
  }
  __syncthreads();
  // ---- stage C: per j, y(32x32) = Tflat(32x64) @ I1C^T; 4*JC tiles ----
  #pragma unroll
  for(int u=0;u<(4*JC+7)/8;u++){
    int tile = wid + 8*u;
    if(tile < 4*JC){
      int jj=tile>>2, sub=tile&3, mtC=sub>>1, ntC=sub&1;
      short8v a0=*(const short8v*)&U[(16*mtC+fr)*(JC*64) + jj*64 + ko];
      short8v a1=*(const short8v*)&U[(16*mtC+fr)*(JC*64) + jj*64 + 32 + ko];
      short8v b0=*(const short8v*)&I1C[16*ntC+fr][ko];
      short8v b1=*(const short8v*)&I1C[16*ntC+fr][32+ko];
      f32x4 ac={0.f,0.f,0.f,0.f};
      ac=__builtin_amdgcn_mfma_f32_16x16x32_bf16(a0,b0,ac,0,0,0);
      ac=__builtin_amdgcn_mfma_f32_16x16x32_bf16(a1,b1,ac,0,0,0);
      size_t base=((size_t)(b*20+o)*30+(j0+jj))*900;
      #pragma unroll
      for(int r=0;r<4;r++){
        int p=16*mtC+rq+r, qq=16*ntC+fc;
        if(p<30 && qq<30){
          float v=fmaxf(ac[r]+bias,0.f);
          h1[base+p*30+qq]=f2bf(v);
        }
      }
    }
  }
}

// psi2 GEMM: Cpsi[l](896x768 f32) = w2bf(896x192) x Y2bf[l]^T(192x768)
__global__ __launch_bounds__(256) void k3g(const unsigned short* __restrict__ A,
                                           const unsigned short* __restrict__ B,
                                           float* __restrict__ Cf){
  int l = blockIdx.z;
  int m0 = blockIdx.y*128, n0 = blockIdx.x*128;
  __shared__ unsigned short As[128][40];
  __shared__ unsigned short Bs[128][40];
  int t = threadIdx.x;
  int wid = t>>6, lane = t&63;
  int wr = wid>>1, wc = wid&1;
  f32x4 acc[4][4];
  #pragma unroll
  for(int a=0;a<4;a++)
    #pragma unroll
    for(int c=0;c<4;c++) acc[a][c]=(f32x4){0.f,0.f,0.f,0.f};
  const unsigned short* Ag = A;
  const unsigned short* Bg = B + (size_t)l*768*192;
  int row_a = wr*64 + (lane&15);
  int row_b = wc*64 + (lane&15);
  int ko = (lane>>4)*8;
  for(int kt=0; kt<192; kt+=32){
    #pragma unroll
    for(int it=0; it<2; it++){
      int q = t + 256*it;
      int r = q>>2, c8 = (q&3)*8;
      *(uint4*)&As[r][c8] = *(const uint4*)&Ag[(size_t)(m0+r)*192 + kt + c8];
      *(uint4*)&Bs[r][c8] = *(const uint4*)&Bg[(size_t)(n0+r)*192 + kt + c8];
    }
    __syncthreads();
    short8v af[4], bfv[4];
    #pragma unroll
    for(int f=0; f<4; f++){
      af[f]  = *(const short8v*)&As[row_a + f*16][ko];
      bfv[f] = *(const short8v*)&Bs[row_b + f*16][ko];
    }
    #pragma unroll
    for(int fm=0;fm<4;fm++)
      #pragma unroll
      for(int fn=0;fn<4;fn++)
        acc[fm][fn] = __builtin_amdgcn_mfma_f32_16x16x32_bf16(af[fm], bfv[fn], acc[fm][fn], 0,0,0);
    __syncthreads();
  }
  #pragma unroll
  for(int fm=0;fm<4;fm++){
    int mb = m0 + wr*64 + fm*16 + ((lane>>4)*4);
    #pragma unroll
    for(int fn=0;fn<4;fn++){
      int n = n0 + wc*64 + fn*16 + (lane&15);
      #pragma unroll
      for(int r=0;r<4;r++){
        Cf[((size_t)(l*896)+mb+r)*768 + n] = acc[fm][fn][r];
      }
    }
  }
}

// Cpsi -> B_augT bf16 (coalesced both sides)
__global__ __launch_bounds__(384) void kBt(const float* __restrict__ Cf,
                                           unsigned short* __restrict__ Bt){
  int c = blockIdx.x;      // o*19+kk
  int l = blockIdx.y;
  int t = threadIdx.x;
  if(t>=380) return;
  int i=t/19, n=t%19;
  int o=c/19, kk=c%19;
  float2 v = *(const float2*)&Cf[((size_t)(l*896) + i*40+o)*768 + (kk*19+n)*2];
  float zr = v.x, zi = -v.y;
  unsigned short* base = Bt + (size_t)l*1536*768;
  size_t r0=(size_t)(2*c)*768, r1=r0+768;
  int col=i*19+n;
  base[r0+col]     = f2bf(zr);
  base[r0+384+col] = f2bf(-zi);
  base[r1+col]     = f2bf(zi);
  base[r1+384+col] = f2bf(zr);
}

// per (b,i): fft2(30x30 -> 19x19) * D2F summed over j -> A_aug bf16.
__global__ __launch_bounds__(512) void k4(const unsigned short* __restrict__ h1,
                                          const float* __restrict__ D2F,
                                          const float2* __restrict__ E2g,
                                          unsigned short* __restrict__ Aaug){
  int i=blockIdx.x, b=blockIdx.y;
  __shared__ __align__(16) unsigned short E2c[48][32];
  __shared__ __align__(16) unsigned short E2A[48][64];
  __shared__ __align__(16) unsigned short T1[192][72];
  __shared__ __align__(16) unsigned short U2[192][44];
  int t=threadIdx.x;
  for(int q=t;q<48*32;q+=512){
    int R=q>>5, g=q&31; float v=0.f;
    if(R<38 && g<30){ float2 e=E2g[(R%19)*30+g]; v=(R<19)? e.x : e.y; }
    E2c[R][g]=f2bf(v);
  }
  for(int q=t;q<48*64;q+=512){
    int R=q>>6, c=q&63; float v=0.f;
    if(R<38){
      int mm=R%19; int mi=(R>=19);
      if(c<30){ float2 e=E2g[mm*30+c]; v = mi ? e.y : e.x; }
      else if(c>=32 && c<62){ float2 e=E2g[mm*30+(c-32)]; v = mi ? e.x : -e.y; }
    }
    E2A[R][c]=f2bf(v);
  }
  for(int q=t;q<192*72;q+=512) T1[q/72][q%72]=0;
  for(int q=t;q<192*44;q+=512) U2[q/44][q%44]=0;
  float accr[10], acci[10];
  #pragma unroll
  for(int l=0;l<10;l++){ accr[l]=0.f; acci[l]=0.f; }
  int m3=t/19, n3=t%19;                // stage3 ids (valid t<361)
  int wid=t>>6, lane=t&63, fr=lane&15, fc=lane&15, ko=(lane>>4)*8, rq=(lane>>4)*4;
  size_t blk=(size_t)(b*20+i)*27000;
  const unsigned int* h1u=(const unsigned int*)h1;
  __syncthreads();
  for(int p=0;p<3;p++){
    int j0=p*10;
    // ---- S1: T1 = h1_chunk @ E2c^T (A from global) ----
    for(int mt=wid; mt<19; mt+=8){
      int rg=16*mt+fr;
      size_t base=blk + (size_t)j0*900 + (size_t)rg*30 + ko;   // even element idx
      union{ unsigned int u[4]; short8v v; } A;
      const unsigned int* pp=h1u + (base>>1);
      A.u[0]=pp[0]; A.u[1]=pp[1]; A.u[2]=pp[2]; A.u[3]=pp[3];
      #pragma unroll
      for(int nt=0;nt<3;nt++){
        short8v Bf=*(const short8v*)&E2c[16*nt+fr][ko];
        f32x4 ac={0.f,0.f,0.f,0.f};
        ac=__builtin_amdgcn_mfma_f32_16x16x32_bf16(A.v,Bf,ac,0,0,0);
        int np=16*nt+fc;
        if(np<38){
          int ri=(np>=19), nn=np-19*ri;
          #pragma unroll
          for(int r=0;r<4;r++){
            int rgw=16*mt+rq+r;
            if(rgw<300){
              int jr=rgw/30, a=rgw%30;
              T1[jr*19+nn][32*ri+a]=f2bf(ac[r]);
            }
          }
        }
      }
    }
    __syncthreads();
    // ---- S2: U2 = E2A @ T1 ----
    for(int u=0;u<5;u++){
      int tile=wid+8*u; if(tile>=36) break;
      int mt2=tile/12, nt2=tile%12;
      short8v a0=*(const short8v*)&E2A[16*mt2+fr][ko];
      short8v a1=*(const short8v*)&E2A[16*mt2+fr][32+ko];
      short8v b0=*(const short8v*)&T1[16*nt2+fr][ko];
      short8v b1=*(const short8v*)&T1[16*nt2+fr][32+ko];
      f32x4 ac={0.f,0.f,0.f,0.f};
      ac=__builtin_amdgcn_mfma_f32_16x16x32_bf16(a0,b0,ac,0,0,0);
      ac=__builtin_amdgcn_mfma_f32_16x16x32_bf16(a1,b1,ac,0,0,0);
      int jn=16*nt2+fc;
      if(jn<190){
        #pragma unroll
        for(int r=0;r<4;r++){
          int R=16*mt2+rq+r;
          if(R<38) U2[jn][R]=f2bf(ac[r]);
        }
      }
    }
    __syncthreads();
    // ---- S3: D2F contraction into registers ----
    if(t<361){
      for(int jr=0;jr<10;jr++){
        int jg=j0+jr;
        const float* dp=D2F + (size_t)jg*361 + t;
        float xr=bf2f(U2[jr*19+n3][m3]);
        float xi=bf2f(U2[jr*19+n3][19+m3]);
        #pragma unroll
        for(int l=0;l<10;l++){ float d=dp[l*10830]; accr[l]+=d*xr; acci[l]+=d*xi; }
      }
    }
  }
  if(t<361){
    #pragma unroll
    for(int l=0;l<10;l++){
      size_t row=((size_t)(l*640) + b*19+m3)*768;
      Aaug[row + i*19+n3]       = f2bf(accr[l]);
      Aaug[row + 384 + i*19+n3] = f2bf(acci[l]);
    }
  }
}

// bf16 MFMA GEMM per l: Z[l](608x1520 f32) = A_aug[l](640x768) x B_augT[l]^T
__global__ __launch_bounds__(256) void k5(const unsigned short* __restrict__ A,
                                          const unsigned short* __restrict__ B,
                                          float* __restrict__ Cf){
  int l = blockIdx.z;
  int m0 = blockIdx.y*128, n0 = blockIdx.x*128;
  __shared__ unsigned short As[128][40];
  __shared__ unsigned short Bs[128][40];
  int t = threadIdx.x;
  int wid = t>>6, lane = t&63;
  int wr = wid>>1, wc = wid&1;
  f32x4 acc[4][4];
  #pragma unroll
  for(int a=0;a<4;a++)
    #pragma unroll
    for(int c=0;c<4;c++) acc[a][c]=(f32x4){0.f,0.f,0.f,0.f};
  const unsigned short* Ag = A + (size_t)l*640*768;
  const unsigned short* Bg = B + (size_t)l*1536*768;
  int row_a = wr*64 + (lane&15);
  int row_b = wc*64 + (lane&15);
  int ko = (lane>>4)*8;
  for(int kt=0; kt<768; kt+=32){
    #pragma unroll
    for(int it=0; it<2; it++){
      int q = t + 256*it;
      int r = q>>2, c8 = (q&3)*8;
      *(uint4*)&As[r][c8] = *(const uint4*)&Ag[(size_t)(m0+r)*768 + kt + c8];
      *(uint4*)&Bs[r][c8] = *(const uint4*)&Bg[(size_t)(n0+r)*768 + kt + c8];
    }
    __syncthreads();
    short8v af[4], bfv[4];
    #pragma unroll
    for(int f=0; f<4; f++){
      af[f]  = *(const short8v*)&As[row_a + f*16][ko];
      bfv[f] = *(const short8v*)&Bs[row_b + f*16][ko];
    }
    #pragma unroll
    for(int fm=0;fm<4;fm++)
      #pragma unroll
      for(int fn=0;fn<4;fn++)
        acc[fm][fn] = __builtin_amdgcn_mfma_f32_16x16x32_bf16(af[fm], bfv[fn], acc[fm][fn], 0,0,0);
    __syncthreads();
  }
  #pragma unroll
  for(int fm=0;fm<4;fm++){
    int mb = m0 + wr*64 + fm*16 + ((lane>>4)*4);
    #pragma unroll
    for(int fn=0;fn<4;fn++){
      int n = n0 + wc*64 + fn*16 + (lane&15);
      if(n<1520){
        #pragma unroll
        for(int r=0;r<4;r++){
          int m = mb + r;
          if(m<608) Cf[((size_t)(l*608)+m)*1520 + n] = acc[fm][fn][r];
        }
      }
    }
  }
}

// conv2 inverse, MFMA batched over j (no j-loop)
__global__ __launch_bounds__(512) void k6(const float2* __restrict__ Z,
                                          const float* __restrict__ D2I,
                                          const float2* __restrict__ I2g,
                                          const float* __restrict__ b2,
                                          unsigned short* __restrict__ h2){
  int o=blockIdx.x, b=blockIdx.y;
  __shared__ __align__(16) unsigned short U[29952];   // An[384][72] / Tl[416][72]
  __shared__ __align__(16) unsigned short I2A[48][72];
  __shared__ __align__(16) unsigned short I2C[32][72];
  int t=threadIdx.x;
  for(int q=t;q<14976;q+=512) ((unsigned int*)U)[q]=0u;
  for(int q=t;q<48*72;q+=512){
    int R=q/72, kd=q%72; float v=0.f;
    if(kd<38){
      int mm = (kd<19)? kd : kd-19; int hi = (kd>=19);
      if(R<20){ float2 e=I2g[R*19+mm]; v = hi ? -e.y : e.x; }
      else if(R<40){ float2 e=I2g[(R-20)*19+mm]; v = hi ? e.x : e.y; }
    }
    I2A[R][kd]=f2bf(v);
  }
  for(int q=t;q<32*72;q+=512){
    int Qr=q/72, kd=q%72; float v=0.f;
    if(Qr<20 && kd<38){
      int kk2 = (kd<19)? kd : kd-19; int hi = (kd>=19);
      float2 e=I2g[Qr*19+kk2]; v = hi ? -e.y : e.x;
    }
    I2C[Qr][kd]=f2bf(v);
  }
  float zr[10], zi[10];
  int m=t/19, kk=t%19;   // valid t<361
  if(t<361){
    #pragma unroll
    for(int l=0;l<10;l++){
      float2 z=Z[(size_t)(l*608 + b*19+m)*760 + o*19+kk];
      zr[l]=z.x; zi[l]=z.y;
    }
  }
  __syncthreads();
  if(t<361){
    for(int j=0;j<20;j++){
      float ar=0.f, ai=0.f;
      const float* dp = D2I + j*361 + t;
      #pragma unroll
      for(int l=0;l<10;l++){ float d=dp[l*7220]; ar+=zr[l]*d; ai+=zi[l]*d; }
      U[(j*19+kk)*72 + m]      = f2bf(ar);
      U[(j*19+kk)*72 + 19 + m] = f2bf(ai);
    }
  }
  __syncthreads();
  int wid=t>>6, lane=t&63, fr=lane&15, ko=(lane>>4)*8;
  f32x4 acc1[9];
  #pragma unroll
  for(int u=0;u<9;u++){
    int tile=wid+8*u;           // 0..71
    int mt=tile/24, nt=tile%24;
    short8v a0=*(const short8v*)&I2A[16*mt+fr][ko];
    short8v a1=*(const short8v*)&I2A[16*mt+fr][32+ko];
    short8v bb0=*(const short8v*)&U[(16*nt+fr)*72+ko];
    short8v bb1=*(const short8v*)&U[(16*nt+fr)*72+32+ko];
    f32x4 ac={0.f,0.f,0.f,0.f};
    ac=__builtin_amdgcn_mfma_f32_16x16x32_bf16(a0,bb0,ac,0,0,0);
    ac=__builtin_amdgcn_mfma_f32_16x16x32_bf16(a1,bb1,ac,0,0,0);
    acc1[u]=ac;
  }
  __syncthreads();   // all An reads done before Tl overlay writes
  #pragma unroll
  for(int u=0;u<9;u++){
    int tile=wid+8*u; int mt=tile/24, nt=tile%24;
    #pragma unroll
    for(int r=0;r<4;r++){
      int R=16*mt+(lane>>4)*4+r;
      int n=16*nt+fr;
      if(R<40 && n<380){
        int j=n/19, kq=n%19;
        U[(j*20 + (R%20))*72 + (R/20)*19 + kq] = f2bf(acc1[u][r]);
      }
    }
  }
  __syncthreads();
  float bias=b2[o];
  size_t obase=((size_t)b*40+o)*8000;
  #pragma unroll
  for(int u=0;u<7;u++){
    int tile=wid+8*u;
    if(tile<52){
      int mt=tile>>1, nt=tile&1;
      short8v a0=*(const short8v*)&U[(16*mt+fr)*72+ko];
      short8v a1=*(const short8v*)&U[(16*mt+fr)*72+32+ko];
      short8v bb0=*(const short8v*)&I2C[16*nt+fr][ko];
      short8v bb1=*(const short8v*)&I2C[16*nt+fr][32+ko];
      f32x4 ac={0.f,0.f,0.f,0.f};
      ac=__builtin_amdgcn_mfma_f32_16x16x32_bf16(a0,bb0,ac,0,0,0);
      ac=__builtin_amdgcn_mfma_f32_16x16x32_bf16(a1,bb1,ac,0,0,0);
      #pragma unroll
      for(int r=0;r<4;r++){
        int row=16*mt+(lane>>4)*4+r;
        int q=16*nt+fr;
        if(row<400 && q<20){
          float v=fmaxf(ac[r]+bias,0.f);
          h2[obase + row*20 + q]=f2bf(v);
        }
      }
    }
  }
}

// g[b,f] = (2pi/20)^2 * sum_{j,p,q} h2 * W_INT[j]   (h2 bf16, paired reads)
__global__ __launch_bounds__(256) void k7a(const unsigned int* __restrict__ h2p,
                                           const float* __restrict__ WI,
                                           float* __restrict__ g){
  int bf=blockIdx.x;
  const unsigned int* base=h2p + (size_t)bf*4000;
  int t=threadIdx.x; float s=0.f;
  for(int q=t;q<4000;q+=256){
    unsigned int v=base[q];
    float w=WI[q/200];
    s += (bf2f((unsigned short)(v&0xFFFF))+bf2f((unsigned short)(v>>16)))*w;
  }
  __shared__ float red[256];
  red[t]=s; __syncthreads();
  for(int off=128;off>0;off>>=1){ if(t<off) red[t]+=red[t+off]; __syncthreads(); }
  if(t==0){
    const float c=(float)((2.0*M_PI/20.0)*(2.0*M_PI/20.0));
    g[bf]=red[0]*c;
  }
}

__global__ __launch_bounds__(64) void k7b(const float* __restrict__ g,
                                          const float* __restrict__ wlin,
                                          const float* __restrict__ bl,
                                          float* __restrict__ out){
  int idx=blockIdx.x*64+threadIdx.x;
  if(idx>=320) return;
  int b=idx/10, c=idx%10;
  float s=bl[c];
  for(int f=0;f<40;f++) s += g[b*40+f]*wlin[c*40+f];
  out[b*10+c]=s;
}

extern "C" void kernel_launch(void* const* d_in, const int* in_sizes, int n_in,
                              void* d_out, int out_size, void* d_ws, size_t ws_size,
                              hipStream_t stream){
  (void)in_sizes; (void)n_in; (void)out_size;
  const float* x    = (const float*)d_in[0];
  const float* w1   = (const float*)d_in[1];
  const float* b1   = (const float*)d_in[2];
  const float* w2   = (const float*)d_in[3];
  const float* b2   = (const float*)d_in[4];
  const float* wlin = (const float*)d_in[5];
  const float* bl   = (const float*)d_in[6];
  float* out = (float*)d_out;
  char*  ws  = (char*)d_ws;

  if(ws_size < WS_NEED){
    fprintf(stderr, "kernel_launch: ws too small: have %zu need %lu\n", ws_size, WS_NEED);
  }

  float* C = (float*)(ws + WOFF_CONST);
  const float*  D1F = C + OFF_D1F;
  const float*  D1I = C + OFF_D1I;
  const float2* Y1  = (const float2*)(C + OFF_Y1);
  const float*  D2F = C + OFF_D2F;
  const float*  D2I = C + OFF_D2I;
  const float*  WI  = C + OFF_WI;
  const float2* E1  = (const float2*)(C + OFF_E1);
  const float2* I1  = (const float2*)(C + OFF_I1);
  const float2* E2  = (const float2*)(C + OFF_E2);
  const float2* I2  = (const float2*)(C + OFF_I2);

  float2* xf1   = (float2*)(ws + WOFF_XF1);
  float2* X1    = (float2*)(ws + WOFF_X1);
  float2* psi1c = (float2*)(ws + WOFF_PSI1);
  unsigned short* h1   = (unsigned short*)(ws + WOFF_H1);
  unsigned short* Y2bf = (unsigned short*)(ws + WOFF_Y2BF);
  unsigned short* w2bf = (unsigned short*)(ws + WOFF_W2BF);
  float*  Cpsi  = (float*)(ws + WOFF_CPSI);
  unsigned short* Aaug = (unsigned short*)(ws + WOFF_AAUG);
  unsigned short* Bt   = (unsigned short*)(ws + WOFF_BT);
  float*  Zf    = (float*)(ws + WOFF_Z);
  unsigned short* h2 = (unsigned short*)(ws + WOFF_H2);
  float*  g     = (float*)(ws + WOFF_G);

  hipLaunchKernelGGL(kconst0, dim3(16), dim3(256), 0, stream, C);
  hipLaunchKernelGGL(kconst, dim3(2048), dim3(256), 0, stream, C, (unsigned int*)Y2bf);
  hipLaunchKernelGGL(kfill, dim3(2048), dim3(256), 0, stream,
                     (uint4*)(ws + WOFF_AAUG), (long)(33423360ul/16ul));
  // zero 512B tail pad after h1 (k4's S1 A-fragments overread up to ~256B)
  hipLaunchKernelGGL(kfill, dim3(1), dim3(256), 0, stream,
                     (uint4*)(ws + WOFF_H1 + 34560000ul), 32L);
  hipLaunchKernelGGL(kw2, dim3((896*96+255)/256), dim3(256), 0, stream, w2, (unsigned int*)w2bf);

  hipLaunchKernelGGL(k1a, dim3((32*60*29+255)/256), dim3(256), 0, stream, x, E1, xf1);
  hipLaunchKernelGGL(k1b, dim3((32*15*29+255)/256), dim3(256), 0, stream, xf1, D1F, X1);
  hipLaunchKernelGGL(kpsi1, dim3((15*29*20+255)/256), dim3(256), 0, stream, w1, Y1, psi1c);
  hipLaunchKernelGGL(k2, dim3(20,32,5), dim3(512), 0, stream, X1, psi1c, D1I, I1, b1, h1);
  hipLaunchKernelGGL(k4, dim3(20,32), dim3(512), 0, stream, h1, D2F, E2, Aaug);
  hipLaunchKernelGGL(k3g, dim3(6,7,10), dim3(256), 0, stream, w2bf, Y2bf, Cpsi);
  hipLaunchKernelGGL(kBt, dim3(760,10), dim3(384), 0, stream, Cpsi, Bt);
  hipLaunchKernelGGL(k5, dim3(12,5,10), dim3(256), 0, stream, Aaug, Bt, Zf);
  hipLaunchKernelGGL(k6, dim3(40,32), dim3(512), 0, stream, (const float2*)Zf, D2I, I2, b2, h2);
  hipLaunchKernelGGL(k7a, dim3(1280), dim3(256), 0, stream, (const unsigned int*)h2, WI, g);
  hipLaunchKernelGGL(k7b, dim3(5), dim3(64), 0, stream, g, wlin, bl, out);
}

// Round 10
// 421.622 us; speedup vs baseline: 3.5728x; 1.0291x over previous
//
#include <hip/hip_runtime.h>
#include <cmath>
#include <cstdio>

#ifndef M_PI
#define M_PI 3.14159265358979323846
#endif

// ---------------- constant table offsets (in float/u32 slots) ----------------
#define OFF_D1F   0        // f32 [15][60][29]
#define OFF_D1IP  26100    // u32 [30][8][841]  bf16-pair (l=2p lo, 2p+1 hi; l=15 pad 0)
#define OFF_D2FP  227940   // u32 [30][5][361]  bf16-pair (incl dhw15)
#define OFF_D2IP  282090   // u32 [20][5][361]  bf16-pair
#define OFF_Y1    318190   // f32 [15][29][24] complex
#define OFF_WI    339070   // [20]
#define OFF_E1    339090   // [29][60] complex
#define OFF_I1    342570   // [30][29] complex
#define OFF_E2    344310   // [19][30] complex
#define OFF_I2    345450   // [20][19] complex
#define OFF_DHW30 346210   // [60]
#define OFF_DHW15 346270   // [30]
#define NCONST    346300

// ---------------- workspace byte offsets ----------------
#define WOFF_CONST 0ul
#define WOFF_Y2BF  2457600ul                 // bf16 [10][768][192] = 2,949,120
#define WOFF_W2BF  5406720ul                 // bf16 [896][192]     =   344,064
#define WOFF_AAUG  5750784ul                 // bf16 [10][640][768] = 9,830,400
#define WOFF_BT    15581184ul                // bf16 [10][1536][768]= 23,592,960
#define WOFF_H1    39174144ul                // bf16 [32][20][27000]= 34,560,000 (+512B zero pad)
#define WOFF_CPSI  39174144ul                // f32 [10][896][768]  = 27,525,120 (h1 dead)
#define WOFF_Z     39174144ul                // f32 [10][608][1520] = 36,966,400 (Cpsi dead)
#define WOFF_H2    2457600ul                 // bf16 [32][40][8000] = 20,480,000
#define WOFF_XF1   76140544ul
#define WOFF_X1    (76140544ul + 445440ul)
#define WOFF_PSI1  (76140544ul + 445440ul + 111360ul)
#define WOFF_G     (76140544ul + 445440ul + 111360ul + 69600ul)
#define WS_NEED    (WOFF_G + 5120ul)

typedef __attribute__((ext_vector_type(8))) short short8v;
typedef __attribute__((ext_vector_type(4))) float f32x4;

__device__ inline unsigned short f2bf(float x){
  unsigned int u = __float_as_uint(x);
  u += 0x7FFFu + ((u >> 16) & 1u);
  return (unsigned short)(u >> 16);
}
__device__ inline float bf2f(unsigned short u){
  return __uint_as_float(((unsigned int)u) << 16);
}
__device__ inline unsigned int packbf(float a, float b){
  return (unsigned int)f2bf(a) | (((unsigned int)f2bf(b))<<16);
}

// ================= device helpers for constant generation =================
__device__ inline double dfact(int n){ double r=1.0; for(int i=2;i<=n;i++) r*=(double)i; return r; }
__device__ inline double dpowi(double x,int e){ double r=1.0; for(int i=0;i<e;i++) r*=x; return r; }
__device__ double wig(int l,int m,int n,double beta){
  if(m < -l || m > l || n < -l || n > l) return 0.0;
  double cb=cos(0.5*beta), sb=sin(0.5*beta);
  double pref=sqrt(dfact(l+m)*dfact(l-m)*dfact(l+n)*dfact(l-n));
  int k0 = (m-n)>0 ? (m-n) : 0;
  int k1 = (l+m) < (l-n) ? (l+m) : (l-n);
  double c0 = ((k0&1)?-1.0:1.0)/(dfact(k0)*dfact(l+m-k0)*dfact(l-n-k0)*dfact(n-m+k0));
  double t = c0 * dpowi(cb, 2*l+m-n-2*k0) * dpowi(sb, n-m+2*k0);
  double ratio = (sb*sb)/(cb*cb);
  double s = t;
  for(int k=k0;k<k1;k++){
    t *= -((double)(l+m-k)*(double)(l-n-k)) / ((double)(k+1)*(double)(n-m+k+1)) * ratio;
    s += t;
  }
  return pref*s;
}
__device__ inline double dh_w(int b,int j){
  double s=0.0;
  for(int k=0;k<b;k++) s += sin((2.0*j+1.0)*(2.0*k+1.0)*M_PI/(4.0*b))/(2.0*k+1.0);
  return (2.0/b)*sin(M_PI*(2.0*j+1.0)/(4.0*b))*s;
}
__device__ inline double soft_beta(int b,int j){ return M_PI*(2.0*j+1.0)/(4.0*b); }
__device__ inline void octcs(int q, double* c, double* s){
  const double r = 0.70710678118654752440;
  int i = q & 7;
  const double C[8]={1.0,r,0.0,-r,-1.0,-r,0.0,r};
  const double S[8]={0.0,r,1.0,r,0.0,-r,-1.0,-r};
  *c=C[i]; *s=S[i];
}

// small tables: quadrature weights + DFT twiddles
__global__ __launch_bounds__(256) void kconst0(float* __restrict__ C){
  for(int idx = blockIdx.x*256 + threadIdx.x; idx < 3670; idx += gridDim.x*256){
    if(idx < 20){ C[OFF_WI+idx]=(float)dh_w(10,idx); }
    else if(idx < 80){ int j=idx-20; C[OFF_DHW30+j]=(float)dh_w(30,j); }
    else if(idx < 110){ int j=idx-80; C[OFF_DHW15+j]=(float)dh_w(15,j); }
    else if(idx < 1850){ int q=idx-110; // E1 [29][60]
      int a=q%60; int m=q/60; double ph=-2.0*M_PI*(double)(m-14)*a/60.0;
      C[OFF_E1+2*q]=(float)cos(ph); C[OFF_E1+2*q+1]=(float)sin(ph);
    } else if(idx < 2720){ int q=idx-1850; // I1 [30][29]
      int m=q%29; int p=q/29; double ph=2.0*M_PI*(double)p*(double)(m-14)/30.0;
      C[OFF_I1+2*q]=(float)cos(ph); C[OFF_I1+2*q+1]=(float)sin(ph);
    } else if(idx < 3290){ int q=idx-2720; // E2 [19][30]
      int a=q%30; int m=q/30; double ph=-2.0*M_PI*(double)(m-9)*a/30.0;
      C[OFF_E2+2*q]=(float)cos(ph); C[OFF_E2+2*q+1]=(float)sin(ph);
    } else { int q=idx-3290; // I2 [20][19]
      int m=q%19; int p=q/19; double ph=2.0*M_PI*(double)p*(double)(m-9)/20.0;
      C[OFF_I2+2*q]=(float)cos(ph); C[OFF_I2+2*q+1]=(float)sin(ph);
    }
  }
}

// big tables (reads DHW tables written by kconst0); D-tables emitted as
// bf16 l-pair-packed u32 in the id-fastest layout each consumer loads.
__global__ __launch_bounds__(256) void kconst(float* __restrict__ C,
                                              unsigned int* __restrict__ Y2p){
  unsigned int* Cu = (unsigned int*)C;
  for(long idx = (long)blockIdx.x*blockDim.x + threadIdx.x; idx < 1065910L;
      idx += (long)gridDim.x*blockDim.x){
    if(idx < 26100L){                       // D1F [15][60][29] f32
      int m=(int)(idx%29); int j=(int)((idx/29)%60); int l=(int)(idx/(29*60));
      C[OFF_D1F+idx] = (float)( wig(l, m-14, 0, soft_beta(30,j)) * (double)C[OFF_DHW30+j] );
    } else if(idx < 227940L){ long q=idx-26100L;   // D1IP [30][8][841], id=n*29+m
      int id=(int)(q%841); int lp=(int)((q/841)%8); int j=(int)(q/6728);
      int n=id/29, m=id%29;
      double beta=soft_beta(15,j);
      double w0=wig(2*lp,   m-14, n-14, beta);
      double w1=(2*lp+1<15)? wig(2*lp+1, m-14, n-14, beta) : 0.0;
      Cu[OFF_D1IP+q]=packbf((float)w0,(float)w1);
    } else if(idx < 282090L){ long q=idx-227940L;  // D2FP [30][5][361], id=m*19+n
      int id=(int)(q%361); int lp=(int)((q/361)%5); int j=(int)(q/1805);
      int m=id/19, n=id%19;
      double beta=soft_beta(15,j); double dw=(double)C[OFF_DHW15+j];
      double w0=wig(2*lp,   m-9, n-9, beta)*dw;
      double w1=wig(2*lp+1, m-9, n-9, beta)*dw;
      Cu[OFF_D2FP+q]=packbf((float)w0,(float)w1);
    } else if(idx < 318190L){ long q=idx-282090L;  // D2IP [20][5][361], id=m*19+n
      int id=(int)(q%361); int lp=(int)((q/361)%5); int j=(int)(q/1805);
      int m=id/19, n=id%19;
      double beta=soft_beta(10,j);
      double w0=wig(2*lp,   m-9, n-9, beta);
      double w1=wig(2*lp+1, m-9, n-9, beta);
      Cu[OFF_D2IP+q]=packbf((float)w0,(float)w1);
    } else if(idx < 328630L){ long q=idx-318190L;  // Y1 [15][29][24] complex
      int g=(int)(q%24); int m=(int)((q/24)%29); int l=(int)(q/(24*29));
      double gb=((g>>3)+1)*(M_PI/8.0)/3.0;
      int ka = g&7;
      double mag=(2*l+1)*wig(l, m-14, 0, gb);
      double cc,ss; octcs((m-14)*ka, &cc, &ss);
      C[OFF_Y1+2*q]  =(float)(mag*cc);
      C[OFF_Y1+2*q+1]=(float)(-mag*ss);
    } else { long q=idx-328630L;                   // Y2bf pairs [10][768][96]
      int g2=(int)(q%96); int row=(int)((q/96)%768); int l=(int)(q/(96*768));
      unsigned int outv=0u;
      if(row<722){
        int kn=row>>1, ri=row&1, kk=kn/19, n=kn%19;
        int g0=2*g2;
        double gb=((g0>>6)+1)*(M_PI/8.0)/3.0;
        double mag=(2*l+1)*wig(l,kk-9,n-9,gb);
        int ka=(g0>>3)&7;
        double c0,s0,c1,s1;
        octcs((kk-9)*ka + (n-9)*(g0&7), &c0,&s0);
        octcs((kk-9)*ka + (n-9)*((g0+1)&7), &c1,&s1);
        float v0 = ri ? (float)(-mag*s0) : (float)(mag*c0);
        float v1 = ri ? (float)(-mag*s1) : (float)(mag*c1);
        outv = (unsigned int)f2bf(v0) | (((unsigned int)f2bf(v1))<<16);
      }
      Y2p[q]=outv;
    }
  }
}

// zero a contiguous region
__global__ __launch_bounds__(256) void kfill(uint4* __restrict__ p, long n16){
  uint4 z; z.x=0u; z.y=0u; z.z=0u; z.w=0u;
  for(long i=(long)blockIdx.x*256+threadIdx.x; i<n16; i+=(long)gridDim.x*256) p[i]=z;
}

// pack w2 -> bf16 [896][192] (rows >=800 zero), u32-paired
__global__ __launch_bounds__(256) void kw2(const float* __restrict__ w2,
                                           unsigned int* __restrict__ w2bf){
  int idx = blockIdx.x*256 + threadIdx.x;
  if(idx >= 896*96) return;
  int row=idx/96, g2=idx%96;
  float a=0.f, b=0.f;
  if(row<800){ a=w2[row*192+2*g2]; b=w2[row*192+2*g2+1]; }
  w2bf[idx] = (unsigned int)f2bf(a) | (((unsigned int)f2bf(b))<<16);
}

// ================= forward-pass kernels =================

__global__ __launch_bounds__(256) void k1a(const float* __restrict__ x,
                                           const float2* __restrict__ E1,
                                           float2* __restrict__ xf1){
  int idx = blockIdx.x*256 + threadIdx.x;
  if(idx >= 32*60*29) return;
  int m = idx % 29; int bj = idx / 29;
  const float* row = x + bj*60;
  float sr=0.f, si=0.f;
  for(int a=0;a<60;a++){ float2 e=E1[m*60+a]; float v=row[a]; sr+=v*e.x; si+=v*e.y; }
  xf1[idx] = make_float2(sr,si);
}

__global__ __launch_bounds__(256) void k1b(const float2* __restrict__ xf1,
                                           const float* __restrict__ D1F,
                                           float2* __restrict__ X1){
  int idx = blockIdx.x*256 + threadIdx.x;
  if(idx >= 32*15*29) return;
  int m = idx % 29; int lb = idx / 29; int l = lb % 15; int b = lb / 15;
  float sr=0.f, si=0.f;
  for(int j=0;j<60;j++){
    float d = D1F[(l*60+j)*29+m]; float2 v = xf1[(b*60+j)*29+m];
    sr += d*v.x; si += d*v.y;
  }
  X1[(b*15+l)*29+m] = make_float2(sr,si);
}

// psi1cO[o][l*29+n] = conj( sum_g w1[0,o,g] * Y1[l,n,g] )
__global__ __launch_bounds__(256) void kpsi1(const float* __restrict__ w1,
                                             const float2* __restrict__ Y1,
                                             float2* __restrict__ psi1cO){
  int idx = blockIdx.x*256 + threadIdx.x;
  if(idx >= 15*29*20) return;
  int o = idx % 20; int ln = idx / 20;
  float sr=0.f, si=0.f;
  for(int g=0;g<24;g++){ float w=w1[o*24+g]; float2 y=Y1[ln*24+g]; sr+=w*y.x; si+=w*y.y; }
  psi1cO[o*435 + ln] = make_float2(sr,-si);
}

// conv1 fused, j batched through MFMA (JC=6, grid.z=5 chunks).
// Stage A uses bf16-pair-packed D1IP (8 coalesced u32 loads per id per j)
// and m-fast id ordering so U writes are contiguous (no 8-way conflicts).
#define JC 6
__global__ __launch_bounds__(512) void k2(const float2* __restrict__ X1,
                                          const float2* __restrict__ psi1cO,
                                          const unsigned int* __restrict__ D1IP,
                                          const float2* __restrict__ I1g,
                                          const float* __restrict__ b1,
                                          unsigned short* __restrict__ h1){
  int o=blockIdx.x, b=blockIdx.y, j0=blockIdx.z*JC;
  __shared__ float2 sX[15][29];
  __shared__ float2 sP[15][29];
  __shared__ __align__(16) unsigned short I1A[64][72];
  __shared__ __align__(16) unsigned short I1C[32][72];
  __shared__ __align__(16) unsigned short U[JC*32*72];  // An[jn][72] / Tl[32][JC*64]
  int t=threadIdx.x;
  for(int q=t;q<435;q+=512){ ((float2*)sX)[q]=X1[b*435+q]; ((float2*)sP)[q]=psi1cO[o*435+q]; }
  for(int q=t;q<64*72;q+=512){
    int R=q/72, k=q%72; float v=0.f;
    if(k<64){ int kk=k&31, kh=k>>5;
      if(kk<29){
        if(R<30){ float2 e=I1g[R*29+kk]; v = kh ? -e.y : e.x; }
        else if(R>=32 && R<62){ float2 e=I1g[(R-32)*29+kk]; v = kh ? e.x : e.y; }
      }
    }
    I1A[R][k]=f2bf(v);
  }
  for(int q=t;q<32*72;q+=512){
    int Qr=q/72, k=q%72; float v=0.f;
    if(Qr<30 && k<64){ int kk=k&31, kh=k>>5;
      if(kk<29){ float2 e=I1g[Qr*29+kk]; v = kh ? -e.y : e.x; }
    }
    I1C[Qr][k]=f2bf(v);
  }
  for(int q=t;q<JC*32*36;q+=512) ((unsigned int*)U)[q]=0u;
  __syncthreads();
  // P = X1 * conj(psi) cached in regs per id (id = n*29+m, m fast); l=15 pad 0
  float Pr[2][16], Pi[2][16];
  #pragma unroll
  for(int s=0;s<2;s++){
    int id=t+512*s;
    if(id<841){
      int n=id/29, m=id%29;
      #pragma unroll
      for(int l=0;l<15;l++){
        float2 xx=sX[l][m], pp=sP[l][n];
        Pr[s][l]=xx.x*pp.x-xx.y*pp.y;
        Pi[s][l]=xx.x*pp.y+xx.y*pp.x;
      }
      Pr[s][15]=0.f; Pi[s][15]=0.f;
    }
  }
  int wid=t>>6, lane=t&63;
  int fr=lane&15, fc=lane&15, rq=(lane>>4)*4, ko=(lane>>4)*8;
  float bias=b1[o];
  // ---- stage A: An[jr*32+n][m_aug] for all JC j (packed bf16 D1I) ----
  #pragma unroll
  for(int s=0;s<2;s++){
    int id=t+512*s;
    if(id<841){
      int n=id/29, m=id%29;
      for(int jr=0;jr<JC;jr++){
        const unsigned int* dp = D1IP + (size_t)(j0+jr)*6728 + id;
        float ar=0.f, ai=0.f;
        #pragma unroll
        for(int p=0;p<8;p++){
          unsigned int v = dp[p*841];
          float f0=__uint_as_float(v<<16);
          float f1=__uint_as_float(v&0xFFFF0000u);
          ar += Pr[s][2*p]*f0 + Pr[s][2*p+1]*f1;
          ai += Pi[s][2*p]*f0 + Pi[s][2*p+1]*f1;
        }
        U[(jr*32+n)*72 + m]    = f2bf(ar);
        U[(jr*32+n)*72 + 32+m] = f2bf(ai);
      }
    }
  }
  __syncthreads();
  // ---- stage B: T = I1A(64x64) @ An^T(64 x JC*32); 4 x 2JC tiles ----
  f32x4 accB[JC];
  #pragma unroll
  for(int u=0;u<JC;u++){
    int tile = wid + 8*u;            // 0 .. 8*JC-1
    int mt = tile/(2*JC), nt = tile%(2*JC);
    short8v a0=*(const short8v*)&I1A[16*mt+fr][ko];
    short8v a1=*(const short8v*)&I1A[16*mt+fr][32+ko];
    short8v b0=*(const short8v*)&U[(16*nt+fr)*72+ko];
    short8v b1=*(const short8v*)&U[(16*nt+fr)*72+32+ko];
    f32x4 ac={0.f,0.f,0.f,0.f};
    ac=__builtin_amdgcn_mfma_f32_16x16x32_bf16(a0,b0,ac,0,0,0);
    ac=__builtin_amdgcn_mfma_f32_16x16x32_bf16(a1,b1,ac,0,0,0);
    accB[u]=ac;
  }
  __syncthreads();   // all An reads done before Tl overlay writes
  #pragma unroll
  for(int u=0;u<JC;u++){
    int tile = wid + 8*u;
    int mt = tile/(2*JC), nt = tile%(2*JC);
    #pragma unroll
    for(int r=0;r<4;r++){
      int R=16*mt+rq+r;              // 0..63
      int jn=16*nt+fc;               // 0..JC*32-1
      int p=R&31, hi=R>>5, jj=jn>>5, n=jn&31;
      U[p*(JC*64) + jj*64 + hi*32 + n] = f2bf(accB[u][r]);
    }
  }
  __syncthreads();
  // ---- stage C: per j, y(32x32) = Tflat(32x64) @ I1C^T; 4*JC tiles ----
  #pragma unroll
  for(int u=0;u<(4*JC+7)/8;u++){
    int tile = wid + 8*u;
    if(tile < 4*JC){
      int jj=tile>>2, sub=tile&3, mtC=sub>>1, ntC=sub&1;
      short8v a0=*(const short8v*)&U[(16*mtC+fr)*(JC*64) + jj*64 + ko];
      short8v a1=*(const short8v*)&U[(16*mtC+fr)*(JC*64) + jj*64 + 32 + ko];
      short8v b0=*(const short8v*)&I1C[16*ntC+fr][ko];
      short8v b1=*(const short8v*)&I1C[16*ntC+fr][32+ko];
      f32x4 ac={0.f,0.f,0.f,0.f};
      ac=__builtin_amdgcn_mfma_f32_16x16x32_bf16(a0,b0,ac,0,0,0);
      ac=__builtin_amdgcn_mfma_f32_16x16x32_bf16(a1,b1,ac,0,0,0);
      size_t base=((size_t)(b*20+o)*30+(j0+jj))*900;
      #pragma unroll
      for(int r=0;r<4;r++){
        int p=16*mtC+rq+r, qq=16*ntC+fc;
        if(p<30 && qq<30){
          float v=fmaxf(ac[r]+bias,0.f);
          h1[base+p*30+qq]=f2bf(v);
        }
      }
    }
  }
}

// psi2 GEMM: Cpsi[l](896x768 f32) = w2bf(896x192) x Y2bf[l]^T(192x768)
__global__ __launch_bounds__(256) void k3g(const unsigned short* __restrict__ A,
                                           const unsigned short* __restrict__ B,
                                           float* __restrict__ Cf){
  int l = blockIdx.z;
  int m0 = blockIdx.y*128, n0 = blockIdx.x*128;
  __shared__ unsigned short As[128][40];
  __shared__ unsigned short Bs[128][40];
  int t = threadIdx.x;
  int wid = t>>6, lane = t&63;
  int wr = wid>>1, wc = wid&1;
  f32x4 acc[4][4];
  #pragma unroll
  for(int a=0;a<4;a++)
    #pragma unroll
    for(int c=0;c<4;c++) acc[a][c]=(f32x4){0.f,0.f,0.f,0.f};
  const unsigned short* Ag = A;
  const unsigned short* Bg = B + (size_t)l*768*192;
  int row_a = wr*64 + (lane&15);
  int row_b = wc*64 + (lane&15);
  int ko = (lane>>4)*8;
  for(int kt=0; kt<192; kt+=32){
    #pragma unroll
    for(int it=0; it<2; it++){
      int q = t + 256*it;
      int r = q>>2, c8 = (q&3)*8;
      *(uint4*)&As[r][c8] = *(const uint4*)&Ag[(size_t)(m0+r)*192 + kt + c8];
      *(uint4*)&Bs[r][c8] = *(const uint4*)&Bg[(size_t)(n0+r)*192 + kt + c8];
    }
    __syncthreads();
    short8v af[4], bfv[4];
    #pragma unroll
    for(int f=0; f<4; f++){
      af[f]  = *(const short8v*)&As[row_a + f*16][ko];
      bfv[f] = *(const short8v*)&Bs[row_b + f*16][ko];
    }
    #pragma unroll
    for(int fm=0;fm<4;fm++)
      #pragma unroll
      for(int fn=0;fn<4;fn++)
        acc[fm][fn] = __builtin_amdgcn_mfma_f32_16x16x32_bf16(af[fm], bfv[fn], acc[fm][fn], 0,0,0);
    __syncthreads();
  }
  #pragma unroll
  for(int fm=0;fm<4;fm++){
    int mb = m0 + wr*64 + fm*16 + ((lane>>4)*4);
    #pragma unroll
    for(int fn=0;fn<4;fn++){
      int n = n0 + wc*64 + fn*16 + (lane&15);
      #pragma unroll
      for(int r=0;r<4;r++){
        Cf[((size_t)(l*896)+mb+r)*768 + n] = acc[fm][fn][r];
      }
    }
  }
}

// Cpsi -> B_augT bf16 (coalesced both sides)
__global__ __launch_bounds__(384) void kBt(const float* __restrict__ Cf,
                                           unsigned short* __restrict__ Bt){
  int c = blockIdx.x;      // o*19+kk
  int l = blockIdx.y;
  int t = threadIdx.x;
  if(t>=380) return;
  int i=t/19, n=t%19;
  int o=c/19, kk=c%19;
  float2 v = *(const float2*)&Cf[((size_t)(l*896) + i*40+o)*768 + (kk*19+n)*2];
  float zr = v.x, zi = -v.y;
  unsigned short* base = Bt + (size_t)l*1536*768;
  size_t r0=(size_t)(2*c)*768, r1=r0+768;
  int col=i*19+n;
  base[r0+col]     = f2bf(zr);
  base[r0+384+col] = f2bf(-zi);
  base[r1+col]     = f2bf(zi);
  base[r1+384+col] = f2bf(zr);
}

// per (b,i): fft2(30x30 -> 19x19) * D2F summed over j -> A_aug bf16.
__global__ __launch_bounds__(512) void k4(const unsigned short* __restrict__ h1,
                                          const unsigned int* __restrict__ D2FP,
                                          const float2* __restrict__ E2g,
                                          unsigned short* __restrict__ Aaug){
  int i=blockIdx.x, b=blockIdx.y;
  __shared__ __align__(16) unsigned short E2c[48][32];
  __shared__ __align__(16) unsigned short E2A[48][64];
  __shared__ __align__(16) unsigned short T1[192][72];
  __shared__ __align__(16) unsigned short U2[192][44];
  int t=threadIdx.x;
  for(int q=t;q<48*32;q+=512){
    int R=q>>5, g=q&31; float v=0.f;
    if(R<38 && g<30){ float2 e=E2g[(R%19)*30+g]; v=(R<19)? e.x : e.y; }
    E2c[R][g]=f2bf(v);
  }
  for(int q=t;q<48*64;q+=512){
    int R=q>>6, c=q&63; float v=0.f;
    if(R<38){
      int mm=R%19; int mi=(R>=19);
      if(c<30){ float2 e=E2g[mm*30+c]; v = mi ? e.y : e.x; }
      else if(c>=32 && c<62){ float2 e=E2g[mm*30+(c-32)]; v = mi ? e.x : -e.y; }
    }
    E2A[R][c]=f2bf(v);
  }
  for(int q=t;q<192*72;q+=512) T1[q/72][q%72]=0;
  for(int q=t;q<192*44;q+=512) U2[q/44][q%44]=0;
  float accr[10], acci[10];
  #pragma unroll
  for(int l=0;l<10;l++){ accr[l]=0.f; acci[l]=0.f; }
  int m3=t/19, n3=t%19;                // stage3 ids (valid t<361)
  int wid=t>>6, lane=t&63, fr=lane&15, fc=lane&15, ko=(lane>>4)*8, rq=(lane>>4)*4;
  size_t blk=(size_t)(b*20+i)*27000;
  const unsigned int* h1u=(const unsigned int*)h1;
  __syncthreads();
  for(int p=0;p<3;p++){
    int j0=p*10;
    // ---- S1: T1 = h1_chunk @ E2c^T (A from global) ----
    for(int mt=wid; mt<19; mt+=8){
      int rg=16*mt+fr;
      size_t base=blk + (size_t)j0*900 + (size_t)rg*30 + ko;   // even element idx
      union{ unsigned int u[4]; short8v v; } A;
      const unsigned int* pp=h1u + (base>>1);
      A.u[0]=pp[0]; A.u[1]=pp[1]; A.u[2]=pp[2]; A.u[3]=pp[3];
      #pragma unroll
      for(int nt=0;nt<3;nt++){
        short8v Bf=*(const short8v*)&E2c[16*nt+fr][ko];
        f32x4 ac={0.f,0.f,0.f,0.f};
        ac=__builtin_amdgcn_mfma_f32_16x16x32_bf16(A.v,Bf,ac,0,0,0);
        int np=16*nt+fc;
        if(np<38){
          int ri=(np>=19), nn=np-19*ri;
          #pragma unroll
          for(int r=0;r<4;r++){
            int rgw=16*mt+rq+r;
            if(rgw<300){
              int jr=rgw/30, a=rgw%30;
              T1[jr*19+nn][32*ri+a]=f2bf(ac[r]);
            }
          }
        }
      }
    }
    __syncthreads();
    // ---- S2: U2 = E2A @ T1 ----
    for(int u=0;u<5;u++){
      int tile=wid+8*u; if(tile>=36) break;
      int mt2=tile/12, nt2=tile%12;
      short8v a0=*(const short8v*)&E2A[16*mt2+fr][ko];
      short8v a1=*(const short8v*)&E2A[16*mt2+fr][32+ko];
      short8v b0=*(const short8v*)&T1[16*nt2+fr][ko];
      short8v b1=*(const short8v*)&T1[16*nt2+fr][32+ko];
      f32x4 ac={0.f,0.f,0.f,0.f};
      ac=__builtin_amdgcn_mfma_f32_16x16x32_bf16(a0,b0,ac,0,0,0);
      ac=__builtin_amdgcn_mfma_f32_16x16x32_bf16(a1,b1,ac,0,0,0);
      int jn=16*nt2+fc;
      if(jn<190){
        #pragma unroll
        for(int r=0;r<4;r++){
          int R=16*mt2+rq+r;
          if(R<38) U2[jn][R]=f2bf(ac[r]);
        }
      }
    }
    __syncthreads();
    // ---- S3: packed-bf16 D2F contraction into registers ----
    if(t<361){
      for(int jr=0;jr<10;jr++){
        int jg=j0+jr;
        const unsigned int* dp = D2FP + (size_t)jg*1805 + t;
        float xr=bf2f(U2[jr*19+n3][m3]);
        float xi=bf2f(U2[jr*19+n3][19+m3]);
        #pragma unroll
        for(int pp2=0;pp2<5;pp2++){
          unsigned int v=dp[pp2*361];
          float f0=__uint_as_float(v<<16);
          float f1=__uint_as_float(v&0xFFFF0000u);
          accr[2*pp2]  +=f0*xr; acci[2*pp2]  +=f0*xi;
          accr[2*pp2+1]+=f1*xr; acci[2*pp2+1]+=f1*xi;
        }
      }
    }
  }
  if(t<361){
    #pragma unroll
    for(int l=0;l<10;l++){
      size_t row=((size_t)(l*640) + b*19+m3)*768;
      Aaug[row + i*19+n3]       = f2bf(accr[l]);
      Aaug[row + 384 + i*19+n3] = f2bf(acci[l]);
    }
  }
}

// bf16 MFMA GEMM per l: Z[l](608x1520 f32) = A_aug[l](640x768) x B_augT[l]^T
__global__ __launch_bounds__(256) void k5(const unsigned short* __restrict__ A,
                                          const unsigned short* __restrict__ B,
                                          float* __restrict__ Cf){
  int l = blockIdx.z;
  int m0 = blockIdx.y*128, n0 = blockIdx.x*128;
  __shared__ unsigned short As[128][40];
  __shared__ unsigned short Bs[128][40];
  int t = threadIdx.x;
  int wid = t>>6, lane = t&63;
  int wr = wid>>1, wc = wid&1;
  f32x4 acc[4][4];
  #pragma unroll
  for(int a=0;a<4;a++)
    #pragma unroll
    for(int c=0;c<4;c++) acc[a][c]=(f32x4){0.f,0.f,0.f,0.f};
  const unsigned short* Ag = A + (size_t)l*640*768;
  const unsigned short* Bg = B + (size_t)l*1536*768;
  int row_a = wr*64 + (lane&15);
  int row_b = wc*64 + (lane&15);
  int ko = (lane>>4)*8;
  for(int kt=0; kt<768; kt+=32){
    #pragma unroll
    for(int it=0; it<2; it++){
      int q = t + 256*it;
      int r = q>>2, c8 = (q&3)*8;
      *(uint4*)&As[r][c8] = *(const uint4*)&Ag[(size_t)(m0+r)*768 + kt + c8];
      *(uint4*)&Bs[r][c8] = *(const uint4*)&Bg[(size_t)(n0+r)*768 + kt + c8];
    }
    __syncthreads();
    short8v af[4], bfv[4];
    #pragma unroll
    for(int f=0; f<4; f++){
      af[f]  = *(const short8v*)&As[row_a + f*16][ko];
      bfv[f] = *(const short8v*)&Bs[row_b + f*16][ko];
    }
    #pragma unroll
    for(int fm=0;fm<4;fm++)
      #pragma unroll
      for(int fn=0;fn<4;fn++)
        acc[fm][fn] = __builtin_amdgcn_mfma_f32_16x16x32_bf16(af[fm], bfv[fn], acc[fm][fn], 0,0,0);
    __syncthreads();
  }
  #pragma unroll
  for(int fm=0;fm<4;fm++){
    int mb = m0 + wr*64 + fm*16 + ((lane>>4)*4);
    #pragma unroll
    for(int fn=0;fn<4;fn++){
      int n = n0 + wc*64 + fn*16 + (lane&15);
      if(n<1520){
        #pragma unroll
        for(int r=0;r<4;r++){
          int m = mb + r;
          if(m<608) Cf[((size_t)(l*608)+m)*1520 + n] = acc[fm][fn][r];
        }
      }
    }
  }
}

// conv2 inverse, MFMA batched over j (no j-loop); packed bf16 D2I
__global__ __launch_bounds__(512) void k6(const float2* __restrict__ Z,
                                          const unsigned int* __restrict__ D2IP,
                                          const float2* __restrict__ I2g,
                                          const float* __restrict__ b2,
                                          unsigned short* __restrict__ h2){
  int o=blockIdx.x, b=blockIdx.y;
  __shared__ __align__(16) unsigned short U[29952];   // An[384][72] / Tl[416][72]
  __shared__ __align__(16) unsigned short I2A[48][72];
  __shared__ __align__(16) unsigned short I2C[32][72];
  int t=threadIdx.x;
  for(int q=t;q<14976;q+=512) ((unsigned int*)U)[q]=0u;
  for(int q=t;q<48*72;q+=512){
    int R=q/72, kd=q%72; float v=0.f;
    if(kd<38){
      int mm = (kd<19)? kd : kd-19; int hi = (kd>=19);
      if(R<20){ float2 e=I2g[R*19+mm]; v = hi ? -e.y : e.x; }
      else if(R<40){ float2 e=I2g[(R-20)*19+mm]; v = hi ? e.x : e.y; }
    }
    I2A[R][kd]=f2bf(v);
  }
  for(int q=t;q<32*72;q+=512){
    int Qr=q/72, kd=q%72; float v=0.f;
    if(Qr<20 && kd<38){
      int kk2 = (kd<19)? kd : kd-19; int hi = (kd>=19);
      float2 e=I2g[Qr*19+kk2]; v = hi ? -e.y : e.x;
    }
    I2C[Qr][kd]=f2bf(v);
  }
  float zr[10], zi[10];
  int m=t/19, kk=t%19;   // valid t<361
  if(t<361){
    #pragma unroll
    for(int l=0;l<10;l++){
      float2 z=Z[(size_t)(l*608 + b*19+m)*760 + o*19+kk];
      zr[l]=z.x; zi[l]=z.y;
    }
  }
  __syncthreads();
  if(t<361){
    for(int j=0;j<20;j++){
      const unsigned int* dp = D2IP + (size_t)j*1805 + t;
      float ar=0.f, ai=0.f;
      #pragma unroll
      for(int p=0;p<5;p++){
        unsigned int v=dp[p*361];
        float f0=__uint_as_float(v<<16);
        float f1=__uint_as_float(v&0xFFFF0000u);
        ar += zr[2*p]*f0 + zr[2*p+1]*f1;
        ai += zi[2*p]*f0 + zi[2*p+1]*f1;
      }
      U[(j*19+kk)*72 + m]      = f2bf(ar);
      U[(j*19+kk)*72 + 19 + m] = f2bf(ai);
    }
  }
  __syncthreads();
  int wid=t>>6, lane=t&63, fr=lane&15, ko=(lane>>4)*8;
  f32x4 acc1[9];
  #pragma unroll
  for(int u=0;u<9;u++){
    int tile=wid+8*u;           // 0..71
    int mt=tile/24, nt=tile%24;
    short8v a0=*(const short8v*)&I2A[16*mt+fr][ko];
    short8v a1=*(const short8v*)&I2A[16*mt+fr][32+ko];
    short8v bb0=*(const short8v*)&U[(16*nt+fr)*72+ko];
    short8v bb1=*(const short8v*)&U[(16*nt+fr)*72+32+ko];
    f32x4 ac={0.f,0.f,0.f,0.f};
    ac=__builtin_amdgcn_mfma_f32_16x16x32_bf16(a0,bb0,ac,0,0,0);
    ac=__builtin_amdgcn_mfma_f32_16x16x32_bf16(a1,bb1,ac,0,0,0);
    acc1[u]=ac;
  }
  __syncthreads();   // all An reads done before Tl overlay writes
  #pragma unroll
  for(int u=0;u<9;u++){
    int tile=wid+8*u; int mt=tile/24, nt=tile%24;
    #pragma unroll
    for(int r=0;r<4;r++){
      int R=16*mt+(lane>>4)*4+r;
      int n=16*nt+fr;
      if(R<40 && n<380){
        int j=n/19, kq=n%19;
        U[(j*20 + (R%20))*72 + (R/20)*19 + kq] = f2bf(acc1[u][r]);
      }
    }
  }
  __syncthreads();
  float bias=b2[o];
  size_t obase=((size_t)b*40+o)*8000;
  #pragma unroll
  for(int u=0;u<7;u++){
    int tile=wid+8*u;
    if(tile<52){
      int mt=tile>>1, nt=tile&1;
      short8v a0=*(const short8v*)&U[(16*mt+fr)*72+ko];
      short8v a1=*(const short8v*)&U[(16*mt+fr)*72+32+ko];
      short8v bb0=*(const short8v*)&I2C[16*nt+fr][ko];
      short8v bb1=*(const short8v*)&I2C[16*nt+fr][32+ko];
      f32x4 ac={0.f,0.f,0.f,0.f};
      ac=__builtin_amdgcn_mfma_f32_16x16x32_bf16(a0,bb0,ac,0,0,0);
      ac=__builtin_amdgcn_mfma_f32_16x16x32_bf16(a1,bb1,ac,0,0,0);
      #pragma unroll
      for(int r=0;r<4;r++){
        int row=16*mt+(lane>>4)*4+r;
        int q=16*nt+fr;
        if(row<400 && q<20){
          float v=fmaxf(ac[r]+bias,0.f);
          h2[obase + row*20 + q]=f2bf(v);
        }
      }
    }
  }
}

// g[b,f] = (2pi/20)^2 * sum_{j,p,q} h2 * W_INT[j]   (h2 bf16, paired reads)
__global__ __launch_bounds__(256) void k7a(const unsigned int* __restrict__ h2p,
                                           const float* __restrict__ WI,
                                           float* __restrict__ g){
  int bf=blockIdx.x;
  const unsigned int* base=h2p + (size_t)bf*4000;
  int t=threadIdx.x; float s=0.f;
  for(int q=t;q<4000;q+=256){
    unsigned int v=base[q];
    float w=WI[q/200];
    s += (bf2f((unsigned short)(v&0xFFFF))+bf2f((unsigned short)(v>>16)))*w;
  }
  __shared__ float red[256];
  red[t]=s; __syncthreads();
  for(int off=128;off>0;off>>=1){ if(t<off) red[t]+=red[t+off]; __syncthreads(); }
  if(t==0){
    const float c=(float)((2.0*M_PI/20.0)*(2.0*M_PI/20.0));
    g[bf]=red[0]*c;
  }
}

__global__ __launch_bounds__(64) void k7b(const float* __restrict__ g,
                                          const float* __restrict__ wlin,
                                          const float* __restrict__ bl,
                                          float* __restrict__ out){
  int idx=blockIdx.x*64+threadIdx.x;
  if(idx>=320) return;
  int b=idx/10, c=idx%10;
  float s=bl[c];
  for(int f=0;f<40;f++) s += g[b*40+f]*wlin[c*40+f];
  out[b*10+c]=s;
}

extern "C" void kernel_launch(void* const* d_in, const int* in_sizes, int n_in,
                              void* d_out, int out_size, void* d_ws, size_t ws_size,
                              hipStream_t stream){
  (void)in_sizes; (void)n_in; (void)out_size;
  const float* x    = (const float*)d_in[0];
  const float* w1   = (const float*)d_in[1];
  const float* b1   = (const float*)d_in[2];
  const float* w2   = (const float*)d_in[3];
  const float* b2   = (const float*)d_in[4];
  const float* wlin = (const float*)d_in[5];
  const float* bl   = (const float*)d_in[6];
  float* out = (float*)d_out;
  char*  ws  = (char*)d_ws;

  if(ws_size < WS_NEED){
    fprintf(stderr, "kernel_launch: ws too small: have %zu need %lu\n", ws_size, WS_NEED);
  }

  float* C = (float*)(ws + WOFF_CONST);
  const float*  D1F = C + OFF_D1F;
  const unsigned int* D1IP = (const unsigned int*)C + OFF_D1IP;
  const unsigned int* D2FP = (const unsigned int*)C + OFF_D2FP;
  const unsigned int* D2IP = (const unsigned int*)C + OFF_D2IP;
  const float2* Y1  = (const float2*)(C + OFF_Y1);
  const float*  WI  = C + OFF_WI;
  const float2* E1  = (const float2*)(C + OFF_E1);
  const float2* I1  = (const float2*)(C + OFF_I1);
  const float2* E2  = (const float2*)(C + OFF_E2);
  const float2* I2  = (const float2*)(C + OFF_I2);

  float2* xf1   = (float2*)(ws + WOFF_XF1);
  float2* X1    = (float2*)(ws + WOFF_X1);
  float2* psi1c = (float2*)(ws + WOFF_PSI1);
  unsigned short* h1   = (unsigned short*)(ws + WOFF_H1);
  unsigned short* Y2bf = (unsigned short*)(ws + WOFF_Y2BF);
  unsigned short* w2bf = (unsigned short*)(ws + WOFF_W2BF);
  float*  Cpsi  = (float*)(ws + WOFF_CPSI);
  unsigned short* Aaug = (unsigned short*)(ws + WOFF_AAUG);
  unsigned short* Bt   = (unsigned short*)(ws + WOFF_BT);
  float*  Zf    = (float*)(ws + WOFF_Z);
  unsigned short* h2 = (unsigned short*)(ws + WOFF_H2);
  float*  g     = (float*)(ws + WOFF_G);

  hipLaunchKernelGGL(kconst0, dim3(16), dim3(256), 0, stream, C);
  hipLaunchKernelGGL(kconst, dim3(2048), dim3(256), 0, stream, C, (unsigned int*)Y2bf);
  hipLaunchKernelGGL(kfill, dim3(2048), dim3(256), 0, stream,
                     (uint4*)(ws + WOFF_AAUG), (long)(33423360ul/16ul));
  // zero 512B tail pad after h1 (k4's S1 A-fragments overread up to ~256B)
  hipLaunchKernelGGL(kfill, dim3(1), dim3(256), 0, stream,
                     (uint4*)(ws + WOFF_H1 + 34560000ul), 32L);
  hipLaunchKernelGGL(kw2, dim3((896*96+255)/256), dim3(256), 0, stream, w2, (unsigned int*)w2bf);

  hipLaunchKernelGGL(k1a, dim3((32*60*29+255)/256), dim3(256), 0, stream, x, E1, xf1);
  hipLaunchKernelGGL(k1b, dim3((32*15*29+255)/256), dim3(256), 0, stream, xf1, D1F, X1);
  hipLaunchKernelGGL(kpsi1, dim3((15*29*20+255)/256), dim3(256), 0, stream, w1, Y1, psi1c);
  hipLaunchKernelGGL(k2, dim3(20,32,5), dim3(512), 0, stream, X1, psi1c, D1IP, I1, b1, h1);
  hipLaunchKernelGGL(k4, dim3(20,32), dim3(512), 0, stream, h1, D2FP, E2, Aaug);
  hipLaunchKernelGGL(k3g, dim3(6,7,10), dim3(256), 0, stream, w2bf, Y2bf, Cpsi);
  hipLaunchKernelGGL(kBt, dim3(760,10), dim3(384), 0, stream, Cpsi, Bt);
  hipLaunchKernelGGL(k5, dim3(12,5,10), dim3(256), 0, stream, Aaug, Bt, Zf);
  hipLaunchKernelGGL(k6, dim3(40,32), dim3(512), 0, stream, (const float2*)Zf, D2IP, I2, b2, h2);
  hipLaunchKernelGGL(k7a, dim3(1280), dim3(256), 0, stream, (const unsigned int*)h2, WI, g);
  hipLaunchKernelGGL(k7b, dim3(5), dim3(64), 0, stream, g, wlin, bl, out);
}